// Round 3
// baseline (5209.135 us; speedup 1.0000x reference)
//
#include <hip/hip_runtime.h>
#include <hip/hip_bf16.h>
#include <math.h>

#define N_   512
#define B_   32
#define T_   12
#define H_   64
#define ED_  10
#define HOR_ 12

typedef __hip_bfloat16 bf16;

__device__ __forceinline__ float sigmoidf_(float x){ return 1.f/(1.f+expf(-x)); }
__device__ __forceinline__ float w2f(float w){ return w; }
__device__ __forceinline__ float w2f(short w){ return (float)w; }

// ---------- Laplacian construction ----------
__global__ __launch_bounds__(512) void k_norm(const float* __restrict__ emb, float* __restrict__ nrm){
  int n = threadIdx.x;
  if (n < N_){
    float s = 0.f;
    #pragma unroll
    for (int d=0; d<ED_; ++d){ float v = emb[n*ED_+d]; s += v*v; }
    nrm[n] = sqrtf(s);
  }
}

__global__ __launch_bounds__(256) void k_adj(const float* __restrict__ emb, const float* __restrict__ nrm,
                      const float* __restrict__ gn, float* __restrict__ adj, float* __restrict__ dvec){
  __shared__ float ei[ED_];
  __shared__ float red[256];
  int i = blockIdx.x;
  if (threadIdx.x < ED_) ei[threadIdx.x] = emb[i*ED_+threadIdx.x];
  __syncthreads();
  float ni = nrm[i];
  float part = 0.f;
  for (int j = threadIdx.x; j < N_; j += 256){
    float dot = 0.f;
    #pragma unroll
    for (int d=0; d<ED_; ++d) dot += ei[d]*emb[j*ED_+d];
    float lg = (dot/(ni*nrm[j]) + 1.f)*0.5f;
    size_t gi = ((size_t)i*N_ + j)*2;
    float y0 = lg + gn[gi];
    float y1 = (1.f - lg) + gn[gi+1];
    float a = (j != i && y0 >= y1) ? 1.f : 0.f;   // argmax picks idx 0 on tie
    adj[(size_t)i*N_ + j] = a;
    part += a;
  }
  red[threadIdx.x] = part;
  __syncthreads();
  for (int s=128; s>0; s>>=1){
    if (threadIdx.x < s) red[threadIdx.x] += red[threadIdx.x+s];
    __syncthreads();
  }
  if (threadIdx.x==0) dvec[i] = red[0];
}

__global__ __launch_bounds__(512) void k_lam(const float* __restrict__ dvec, float* __restrict__ lam){
  __shared__ float red[512];
  red[threadIdx.x] = dvec[threadIdx.x];
  __syncthreads();
  for (int s=256; s>0; s>>=1){
    if (threadIdx.x < s) red[threadIdx.x] = fmaxf(red[threadIdx.x], red[threadIdx.x+s]);
    __syncthreads();
  }
  if (threadIdx.x==0){
    float maxd = red[0];
    lam[0] = maxd + (maxd > 0.f ? 1.f : 0.f);
  }
}

__global__ __launch_bounds__(256) void k_tilde(float* __restrict__ adj, const float* __restrict__ dvec,
                        const float* __restrict__ lam){
  int idx = blockIdx.x*256 + threadIdx.x;
  int i = idx >> 9, j = idx & (N_-1);
  float a = adj[idx];
  float L = (i==j) ? dvec[i] : -a;
  float eye = (i==j) ? 1.f : 0.f;
  adj[idx] = 2.f*L/lam[0] - eye;
}

// ---------- f32 GEMM: Y[row][col] = sum_m S[row][m]*X[m][col]; M=K=512.
__global__ __launch_bounds__(256) void k_gemm(const float* __restrict__ S0, const float* __restrict__ S1,
                       const float* __restrict__ X, float* __restrict__ Y0, float* __restrict__ Y1v,
                       int BC, int mode){
  const float* S = blockIdx.z ? S1 : S0;
  float* Y = blockIdx.z ? Y1v : Y0;
  __shared__ float St[16][68];
  __shared__ float Xt[16][68];
  int tid = threadIdx.x;
  int tx = tid & 15, ty = tid >> 4;
  int rowBase = blockIdx.y*64, colBase = blockIdx.x*64;
  int lr  = tid >> 2;
  int lk4 = (tid & 3) * 4;
  int xk  = tid >> 4;
  int xc4 = (tid & 15) * 4;
  float acc[4][4] = {};
  for (int kk = 0; kk < N_; kk += 16){
    float4 sv = *(const float4*)&S[(size_t)(rowBase+lr)*N_ + kk + lk4];
    int col = colBase + xc4;
    float4 xv = make_float4(0.f,0.f,0.f,0.f);
    if (col < BC) xv = *(const float4*)&X[(size_t)(kk+xk)*BC + col];
    St[lk4+0][lr] = sv.x; St[lk4+1][lr] = sv.y; St[lk4+2][lr] = sv.z; St[lk4+3][lr] = sv.w;
    *(float4*)&Xt[xk][xc4] = xv;
    __syncthreads();
    #pragma unroll
    for (int k=0;k<16;++k){
      float4 a = *(const float4*)&St[k][ty*4];
      float4 b = *(const float4*)&Xt[k][tx*4];
      acc[0][0] += a.x*b.x; acc[0][1] += a.x*b.y; acc[0][2] += a.x*b.z; acc[0][3] += a.x*b.w;
      acc[1][0] += a.y*b.x; acc[1][1] += a.y*b.y; acc[1][2] += a.y*b.z; acc[1][3] += a.y*b.w;
      acc[2][0] += a.z*b.x; acc[2][1] += a.z*b.y; acc[2][2] += a.z*b.z; acc[2][3] += a.z*b.w;
      acc[3][0] += a.w*b.x; acc[3][1] += a.w*b.y; acc[3][2] += a.w*b.z; acc[3][3] += a.w*b.w;
    }
    __syncthreads();
  }
  int col = colBase + tx*4;
  if (col < BC){
    #pragma unroll
    for (int i=0;i<4;++i){
      int row = rowBase + ty*4 + i;
      float4 v = make_float4(acc[i][0], acc[i][1], acc[i][2], acc[i][3]);
      if (mode==1){
        v.x = 2.f*v.x - (row==col+0 ? 1.f:0.f);
        v.y = 2.f*v.y - (row==col+1 ? 1.f:0.f);
        v.z = 2.f*v.z - (row==col+2 ? 1.f:0.f);
        v.w = 2.f*v.w - (row==col+3 ? 1.f:0.f);
      }
      *(float4*)&Y[(size_t)row*BC + col] = v;
    }
  }
}

// ---------- per-node weights ----------
// f32 path: W[n][kio] = sum_d emb[n][d]*wp[d][kio]
__global__ __launch_bounds__(256) void k_wprep_f32(const float* __restrict__ wp, const float* __restrict__ emb,
                        float* __restrict__ W, int KIO){
  __shared__ float es[N_*ED_];
  for (int e = threadIdx.x; e < N_*ED_; e += 256) es[e] = emb[e];
  __syncthreads();
  int e = blockIdx.x*256 + threadIdx.x;
  if (e >= KIO) return;
  float wv[ED_];
  #pragma unroll
  for (int d=0; d<ED_; ++d) wv[d] = wp[(size_t)d*KIO + e];
  for (int n=0; n<N_; ++n){
    float a = 0.f;
    #pragma unroll
    for (int d=0; d<ED_; ++d) a += es[n*ED_+d]*wv[d];
    W[(size_t)n*KIO + e] = a;
  }
}

// int16 path pass 1: per-output-column max |W| -> sb[o] (float bits in uint, atomicMax)
__global__ __launch_bounds__(256) void k_wmax(const float* __restrict__ wp, const float* __restrict__ emb,
                       unsigned int* __restrict__ sb, int KIO, int O){
  __shared__ float es[N_*ED_];
  for (int e = threadIdx.x; e < N_*ED_; e += 256) es[e] = emb[e];
  __syncthreads();
  int e = blockIdx.x*256 + threadIdx.x;
  if (e >= KIO) return;
  int o = e % O;
  float wv[ED_];
  #pragma unroll
  for (int d=0; d<ED_; ++d) wv[d] = wp[(size_t)d*KIO + e];
  float m = 0.f;
  for (int n=0; n<N_; ++n){
    float a = 0.f;
    #pragma unroll
    for (int d=0; d<ED_; ++d) a += es[n*ED_+d]*wv[d];
    m = fmaxf(m, fabsf(a));
  }
  atomicMax(&sb[o], __float_as_uint(m));  // non-negative floats: uint order == float order
}

// int16 path pass 2: quantize q = round(a * 32767 / M[o])
__global__ __launch_bounds__(256) void k_wquant(const float* __restrict__ wp, const float* __restrict__ emb,
                         const unsigned int* __restrict__ sb, short* __restrict__ W, int KIO, int O){
  __shared__ float es[N_*ED_];
  for (int e = threadIdx.x; e < N_*ED_; e += 256) es[e] = emb[e];
  __syncthreads();
  int e = blockIdx.x*256 + threadIdx.x;
  if (e >= KIO) return;
  int o = e % O;
  float M = __uint_as_float(sb[o]);
  float inv = (M > 0.f) ? 32767.f/M : 0.f;
  float wv[ED_];
  #pragma unroll
  for (int d=0; d<ED_; ++d) wv[d] = wp[(size_t)d*KIO + e];
  for (int n=0; n<N_; ++n){
    float a = 0.f;
    #pragma unroll
    for (int d=0; d<ED_; ++d) a += es[n*ED_+d]*wv[d];
    W[(size_t)n*KIO + e] = (short)__float2int_rn(a*inv);
  }
}

__global__ __launch_bounds__(256) void k_bias(const float* __restrict__ bp, const float* __restrict__ emb,
                       float* __restrict__ Bo, int O){
  int idx = blockIdx.x*256 + threadIdx.x;
  int o = idx % O, n = idx / O;
  float a = 0.f;
  #pragma unroll
  for (int d=0; d<ED_; ++d) a += emb[n*ED_+d]*bp[d*O+o];
  Bo[idx] = a;
}

__global__ void k_fill0(float* __restrict__ p, size_t n){
  size_t i = (size_t)blockIdx.x*blockDim.x + threadIdx.x;
  size_t stride = (size_t)gridDim.x*blockDim.x;
  for (; i<n; i+=stride) p[i] = 0.f;
}

// ---------- xs assembly ----------
__global__ __launch_bounds__(256) void k_buildX0(float* __restrict__ Xm, const float* __restrict__ src,
                          const float* __restrict__ h, int t){
  int idx = blockIdx.x*256 + threadIdx.x;
  if (idx >= N_*B_*65) return;
  int c = idx % 65; int nb = idx / 65;
  int b = nb % B_;  int m = nb / B_;
  Xm[idx] = (c==0) ? src[((size_t)(b*T_+t))*N_ + m] : h[(size_t)nb*H_ + (c-1)];
}
__global__ __launch_bounds__(256) void k_buildX1(float* __restrict__ Xm, const float* __restrict__ hA,
                          const float* __restrict__ hB){
  int idx = blockIdx.x*256 + threadIdx.x;
  int c = idx & 127; int nb = idx >> 7;
  Xm[idx] = (c < H_) ? hA[(size_t)nb*H_ + c] : hB[(size_t)nb*H_ + (c-H_)];
}

// ---------- per-node gate contraction (O=128) ----------
template<int CIN, int CAND_OFF, typename WT>
__global__ __launch_bounds__(256) void k_gate(const float* __restrict__ Xm, const float* __restrict__ Y1,
                       const float* __restrict__ Y2, const WT* __restrict__ W,
                       const float* __restrict__ Wsc, const float* __restrict__ Bb,
                       const float* __restrict__ h,
                       float* __restrict__ XmOut, float* __restrict__ rbuf){
  constexpr int O = 2*H_;        // 128
  constexpr int G = 256/O;       // 2
  constexpr int NB = B_/G;       // 16
  __shared__ float A[3*B_*CIN];
  int n = blockIdx.x;
  size_t base = (size_t)n*B_*CIN;
  for (int e = threadIdx.x; e < B_*CIN; e += 256){
    A[e]            = Xm[base+e];
    A[B_*CIN+e]     = Y1[base+e];
    A[2*B_*CIN+e]   = Y2[base+e];
  }
  __syncthreads();
  int o = threadIdx.x % O;
  int g = threadIdx.x / O;
  float acc[NB];
  #pragma unroll
  for (int i=0;i<NB;++i) acc[i] = 0.f;
  const WT* Wn = W + (size_t)n*(3*CIN)*O + o;
  for (int k=0;k<3;++k){
    const float* Ak = A + k*B_*CIN;
    for (int i=0;i<CIN;++i){
      float w = w2f(Wn[(size_t)(k*CIN+i)*O]);
      #pragma unroll
      for (int bi=0;bi<NB;++bi) acc[bi] += Ak[(g+bi*G)*CIN + i]*w;
    }
  }
  float sc = 1.f;
  if constexpr (sizeof(WT)==2) sc = Wsc[o] * (1.f/32767.f);
  float bias = Bb[n*O+o];
  if (o < H_){
    #pragma unroll
    for (int bi=0;bi<NB;++bi){
      int b = g + bi*G;
      float z = sigmoidf_(acc[bi]*sc+bias);
      float hv = h[((size_t)n*B_+b)*H_ + o];
      XmOut[((size_t)n*B_+b)*CIN + CAND_OFF + o] = z*hv;
    }
  } else {
    int oo = o - H_;
    #pragma unroll
    for (int bi=0;bi<NB;++bi){
      int b = g + bi*G;
      rbuf[((size_t)n*B_+b)*H_ + oo] = sigmoidf_(acc[bi]*sc+bias);
    }
  }
}

// ---------- per-node update contraction (O=64) + GRU state update ----------
template<int CIN, typename WT>
__global__ __launch_bounds__(256) void k_update(const float* __restrict__ Xm, const float* __restrict__ Y1,
                         const float* __restrict__ Y2, const WT* __restrict__ W,
                         const float* __restrict__ Wsc, const float* __restrict__ Bb,
                         const float* __restrict__ rbuf, float* __restrict__ h){
  constexpr int O = H_;          // 64
  constexpr int G = 256/O;       // 4
  constexpr int NB = B_/G;       // 8
  __shared__ float A[3*B_*CIN];
  int n = blockIdx.x;
  size_t base = (size_t)n*B_*CIN;
  for (int e = threadIdx.x; e < B_*CIN; e += 256){
    A[e]            = Xm[base+e];
    A[B_*CIN+e]     = Y1[base+e];
    A[2*B_*CIN+e]   = Y2[base+e];
  }
  __syncthreads();
  int o = threadIdx.x % O;
  int g = threadIdx.x / O;
  float acc[NB];
  #pragma unroll
  for (int i=0;i<NB;++i) acc[i] = 0.f;
  const WT* Wn = W + (size_t)n*(3*CIN)*O + o;
  for (int k=0;k<3;++k){
    const float* Ak = A + k*B_*CIN;
    for (int i=0;i<CIN;++i){
      float w = w2f(Wn[(size_t)(k*CIN+i)*O]);
      #pragma unroll
      for (int bi=0;bi<NB;++bi) acc[bi] += Ak[(g+bi*G)*CIN + i]*w;
    }
  }
  float sc = 1.f;
  if constexpr (sizeof(WT)==2) sc = Wsc[o] * (1.f/32767.f);
  float bias = Bb[n*O+o];
  #pragma unroll
  for (int bi=0;bi<NB;++bi){
    int b = g + bi*G;
    float hc = tanhf(acc[bi]*sc+bias);
    size_t hidx = ((size_t)n*B_+b)*H_ + o;
    float r = rbuf[hidx];
    h[hidx] = r*h[hidx] + (1.f-r)*hc;
  }
}

// ---------- readout ----------
__global__ __launch_bounds__(256) void k_readout(const float* __restrict__ hB, const float* __restrict__ cw,
                          const float* __restrict__ cb, float* __restrict__ out){
  int idx = blockIdx.x*256 + threadIdx.x;
  int n = idx & (N_-1);
  int bo = idx >> 9;
  int o = bo % HOR_, b = bo / HOR_;
  float a = cb[o];
  #pragma unroll
  for (int j=0;j<H_;++j) a += hB[((size_t)n*B_+b)*H_ + j]*cw[o*H_+j];
  out[idx] = a;
}

template<typename WT>
static void run_all(void* const* d_in, void* d_out, void* d_ws, hipStream_t stream){
  const float* src  = (const float*)d_in[0];
  const float* gn   = (const float*)d_in[2];
  const float* emb  = (const float*)d_in[3];
  const float* gw0  = (const float*)d_in[4];
  const float* gb0  = (const float*)d_in[5];
  const float* uw0  = (const float*)d_in[6];
  const float* ub0  = (const float*)d_in[7];
  const float* gw1  = (const float*)d_in[8];
  const float* gb1  = (const float*)d_in[9];
  const float* uw1  = (const float*)d_in[10];
  const float* ub1  = (const float*)d_in[11];
  const float* cw   = (const float*)d_in[12];
  const float* cb   = (const float*)d_in[13];
  float* out = (float*)d_out;

  char* ws = (char*)d_ws;
  size_t off = 0;
  auto alloc = [&](size_t bytes)->char*{
    char* p = ws + off; off = (off + bytes + 255) & ~(size_t)255; return p;
  };
  float* tilde = (float*)alloc((size_t)N_*N_*4);
  float* sup2  = (float*)alloc((size_t)N_*N_*4);
  float* dvec  = (float*)alloc(N_*4);
  float* lam   = (float*)alloc(256);
  float* nrm   = (float*)alloc(N_*4);
  WT* Wg0 = (WT*)alloc((size_t)N_*195*128*sizeof(WT));
  WT* Wu0 = (WT*)alloc((size_t)N_*195*64*sizeof(WT));
  WT* Wg1 = (WT*)alloc((size_t)N_*384*128*sizeof(WT));
  WT* Wu1 = (WT*)alloc((size_t)N_*384*64*sizeof(WT));
  unsigned int* Sg0 = (unsigned int*)alloc(128*4);
  unsigned int* Su0 = (unsigned int*)alloc(64*4);
  unsigned int* Sg1 = (unsigned int*)alloc(128*4);
  unsigned int* Su1 = (unsigned int*)alloc(64*4);
  float* Bg0 = (float*)alloc((size_t)N_*128*4);
  float* Bu0 = (float*)alloc((size_t)N_*64*4);
  float* Bg1 = (float*)alloc((size_t)N_*128*4);
  float* Bu1 = (float*)alloc((size_t)N_*64*4);
  float* hA  = (float*)alloc((size_t)N_*B_*H_*4);
  float* hB  = (float*)alloc((size_t)N_*B_*H_*4);
  float* rbuf= (float*)alloc((size_t)N_*B_*H_*4);
  float* Xm  = (float*)alloc((size_t)N_*B_*128*4);
  float* Y1  = (float*)alloc((size_t)N_*B_*128*4);
  float* Y2  = (float*)alloc((size_t)N_*B_*128*4);

  // graph structure
  k_norm<<<1,512,0,stream>>>(emb, nrm);
  k_adj<<<N_,256,0,stream>>>(emb, nrm, gn, tilde, dvec);
  k_lam<<<1,512,0,stream>>>(dvec, lam);
  k_tilde<<<(N_*N_)/256,256,0,stream>>>(tilde, dvec, lam);
  k_gemm<<<dim3(8,8,1),256,0,stream>>>(tilde, tilde, tilde, sup2, sup2, N_, 1);

  // per-node weights
  if constexpr (sizeof(WT)==2){
    k_fill0<<<1,256,0,stream>>>((float*)Sg0, 128+64+128+64+/*padding slack*/0);
    k_wmax<<<(195*128+255)/256,256,0,stream>>>(gw0, emb, Sg0, 195*128, 128);
    k_wmax<<<(195*64+255)/256,256,0,stream>>>(uw0, emb, Su0, 195*64, 64);
    k_wmax<<<(384*128)/256,256,0,stream>>>(gw1, emb, Sg1, 384*128, 128);
    k_wmax<<<(384*64)/256,256,0,stream>>>(uw1, emb, Su1, 384*64, 64);
    k_wquant<<<(195*128+255)/256,256,0,stream>>>(gw0, emb, Sg0, (short*)Wg0, 195*128, 128);
    k_wquant<<<(195*64+255)/256,256,0,stream>>>(uw0, emb, Su0, (short*)Wu0, 195*64, 64);
    k_wquant<<<(384*128)/256,256,0,stream>>>(gw1, emb, Sg1, (short*)Wg1, 384*128, 128);
    k_wquant<<<(384*64)/256,256,0,stream>>>(uw1, emb, Su1, (short*)Wu1, 384*64, 64);
  } else {
    k_wprep_f32<<<(195*128+255)/256,256,0,stream>>>(gw0, emb, (float*)Wg0, 195*128);
    k_wprep_f32<<<(195*64+255)/256,256,0,stream>>>(uw0, emb, (float*)Wu0, 195*64);
    k_wprep_f32<<<(384*128)/256,256,0,stream>>>(gw1, emb, (float*)Wg1, 384*128);
    k_wprep_f32<<<(384*64)/256,256,0,stream>>>(uw1, emb, (float*)Wu1, 384*64);
  }
  k_bias<<<(N_*128)/256,256,0,stream>>>(gb0, emb, Bg0, 128);
  k_bias<<<(N_*64)/256,256,0,stream>>>(ub0, emb, Bu0, 64);
  k_bias<<<(N_*128)/256,256,0,stream>>>(gb1, emb, Bg1, 128);
  k_bias<<<(N_*64)/256,256,0,stream>>>(ub1, emb, Bu1, 64);

  k_fill0<<<2048,256,0,stream>>>(hA, (size_t)N_*B_*H_);
  k_fill0<<<2048,256,0,stream>>>(hB, (size_t)N_*B_*H_);

  const float* fSg0 = (const float*)Sg0;
  const float* fSu0 = (const float*)Su0;
  const float* fSg1 = (const float*)Sg1;
  const float* fSu1 = (const float*)Su1;

  for (int t=0; t<T_; ++t){
    // ---- layer 0 (CIN=65) ----
    k_buildX0<<<(N_*B_*65+255)/256,256,0,stream>>>(Xm, src, hA, t);
    k_gemm<<<dim3(33,8,2),256,0,stream>>>(tilde, sup2, Xm, Y1, Y2, B_*65, 0);
    k_gate<65,1,WT><<<N_,256,0,stream>>>(Xm, Y1, Y2, Wg0, fSg0, Bg0, hA, Xm, rbuf);
    k_gemm<<<dim3(33,8,2),256,0,stream>>>(tilde, sup2, Xm, Y1, Y2, B_*65, 0);
    k_update<65,WT><<<N_,256,0,stream>>>(Xm, Y1, Y2, Wu0, fSu0, Bu0, rbuf, hA);
    // ---- layer 1 (CIN=128) ----
    k_buildX1<<<(N_*B_*128)/256,256,0,stream>>>(Xm, hA, hB);
    k_gemm<<<dim3(64,8,2),256,0,stream>>>(tilde, sup2, Xm, Y1, Y2, B_*128, 0);
    k_gate<128,64,WT><<<N_,256,0,stream>>>(Xm, Y1, Y2, Wg1, fSg1, Bg1, hB, Xm, rbuf);
    k_gemm<<<dim3(64,8,2),256,0,stream>>>(tilde, sup2, Xm, Y1, Y2, B_*128, 0);
    k_update<128,WT><<<N_,256,0,stream>>>(Xm, Y1, Y2, Wu1, fSu1, Bu1, rbuf, hB);
  }

  k_readout<<<(B_*HOR_*N_)/256,256,0,stream>>>(hB, cw, cb, out);
}

extern "C" void kernel_launch(void* const* d_in, const int* in_sizes, int n_in,
                              void* d_out, int out_size, void* d_ws, size_t ws_size,
                              hipStream_t stream){
  (void)in_sizes; (void)n_in; (void)out_size;
  // f32 per-node weights need ~268MB total; int16 path needs ~156MB (R1 proved ws >= ~155MB).
  if (ws_size >= ((size_t)280 << 20)) run_all<float>(d_in, d_out, d_ws, stream);
  else                                run_all<short>(d_in, d_out, d_ws, stream);
}

// Round 5
// 4041.760 us; speedup vs baseline: 1.2888x; 1.2888x over previous
//
#include <hip/hip_runtime.h>
#include <math.h>

#define N_    512
#define B_    32
#define T_    12
#define H_    64
#define ED_   10
#define HOR_  12
#define OUTS_ 4096

typedef unsigned short ushort_t;
typedef __attribute__((ext_vector_type(4))) float f32x4;
typedef __attribute__((ext_vector_type(8))) __bf16 bf16x8;

__device__ __forceinline__ float sigmoidf_(float x){ return 1.f/(1.f+expf(-x)); }
__device__ __forceinline__ float b2f(ushort_t u){ return __uint_as_float(((unsigned)u)<<16); }
__device__ __forceinline__ ushort_t f2b(float f){
  unsigned x = __float_as_uint(f);
  unsigned r = x + 0x7FFFu + ((x>>16)&1u);
  return (ushort_t)(r>>16);
}
__device__ __forceinline__ void stage16(const void* g, void* l){
  __builtin_amdgcn_global_load_lds(
    (const __attribute__((address_space(1))) unsigned int*)g,
    (__attribute__((address_space(3))) unsigned int*)l, 16, 0, 0);
}

// ---------- graph structure ----------
__global__ __launch_bounds__(512) void k_norm(const float* __restrict__ emb, float* __restrict__ nrm){
  int n = threadIdx.x;
  if (n < N_){
    float s = 0.f;
    #pragma unroll
    for (int d=0; d<ED_; ++d){ float v = emb[n*ED_+d]; s += v*v; }
    nrm[n] = sqrtf(s);
  }
}

__global__ __launch_bounds__(256) void k_adj(const float* __restrict__ emb, const float* __restrict__ nrm,
                      const float* __restrict__ gn, ushort_t* __restrict__ Abf, float* __restrict__ dvec){
  __shared__ float ei[ED_];
  __shared__ float red[256];
  int i = blockIdx.x;
  if (threadIdx.x < ED_) ei[threadIdx.x] = emb[i*ED_+threadIdx.x];
  __syncthreads();
  float ni = nrm[i];
  float part = 0.f;
  for (int j = threadIdx.x; j < N_; j += 256){
    float dot = 0.f;
    #pragma unroll
    for (int d=0; d<ED_; ++d) dot += ei[d]*emb[j*ED_+d];
    float lg = (dot/(ni*nrm[j]) + 1.f)*0.5f;
    size_t gi = ((size_t)i*N_ + j)*2;
    float y0 = lg + gn[gi];
    float y1 = (1.f - lg) + gn[gi+1];
    bool a = (j != i && y0 >= y1);
    Abf[(size_t)i*N_ + j] = a ? (ushort_t)0x3F80 : (ushort_t)0;
    part += a ? 1.f : 0.f;
  }
  red[threadIdx.x] = part;
  __syncthreads();
  for (int s=128; s>0; s>>=1){
    if (threadIdx.x < s) red[threadIdx.x] += red[threadIdx.x+s];
    __syncthreads();
  }
  if (threadIdx.x==0) dvec[i] = red[0];
}

__global__ __launch_bounds__(512) void k_lam(const float* __restrict__ dvec, float* __restrict__ lam){
  __shared__ float red[512];
  red[threadIdx.x] = dvec[threadIdx.x];
  __syncthreads();
  for (int s=256; s>0; s>>=1){
    if (threadIdx.x < s) red[threadIdx.x] = fmaxf(red[threadIdx.x], red[threadIdx.x+s]);
    __syncthreads();
  }
  if (threadIdx.x==0){
    float maxd = red[0];
    lam[0] = maxd + (maxd > 0.f ? 1.f : 0.f);
  }
}

// A2[n][m] = sum_p A[n][p]*A[p][m] (integer counts <~200, exact in bf16)
__global__ __launch_bounds__(256) void k_a2(const ushort_t* __restrict__ Abf, ushort_t* __restrict__ A2bf){
  __shared__ float ar[N_];
  int n = blockIdx.x;
  for (int p = threadIdx.x; p < N_; p += 256) ar[p] = b2f(Abf[(size_t)n*N_ + p]);
  __syncthreads();
  int m0 = threadIdx.x, m1 = threadIdx.x + 256;
  float a0 = 0.f, a1 = 0.f;
  for (int p=0; p<N_; ++p){
    float ap = ar[p];
    a0 += ap * b2f(Abf[(size_t)p*N_ + m0]);
    a1 += ap * b2f(Abf[(size_t)p*N_ + m1]);
  }
  A2bf[(size_t)n*N_ + m0] = f2b(a0);
  A2bf[(size_t)n*N_ + m1] = f2b(a1);
}

// AD[n][m] = A[n][m] * delta_m, delta_m = 2*d_m/lam - 1
__global__ __launch_bounds__(256) void k_admats(const ushort_t* __restrict__ Abf, const float* __restrict__ dvec,
                        const float* __restrict__ lam, ushort_t* __restrict__ ADh){
  int idx = blockIdx.x*256 + threadIdx.x;
  int m = idx & (N_-1);
  float dm = 2.f*dvec[m]/lam[0] - 1.f;
  ADh[idx] = Abf[idx] ? f2b(dm) : (ushort_t)0;
}

// ---------- MFMA apply: OUT[n][c] = sum_m (XH+XL)[c][m] * M[n][m]  (f32 out)
// z=0: M=A -> P ; z=1: M=A2 -> R ; z=2: M=AD -> Q
#define TILE_USH 8192   // 128 rows x 64 k (bf16) = 16KB
__global__ __launch_bounds__(256) void k_apply(
    const ushort_t* __restrict__ XH, const ushort_t* __restrict__ XL,
    const ushort_t* __restrict__ Abf, const ushort_t* __restrict__ A2bf, const ushort_t* __restrict__ ADh,
    float* __restrict__ P, float* __restrict__ Rm, float* __restrict__ Qm)
{
  __shared__ ushort_t lds[3*TILE_USH];
  const int z = blockIdx.z;
  const ushort_t* M = (z==0)? Abf : (z==1)? A2bf : ADh;
  float* OUT = (z==0)? P : (z==1)? Rm : Qm;
  const int cBase = blockIdx.x<<7, nBase = blockIdx.y<<7;
  const int tid = threadIdx.x, lane = tid&63, w = tid>>6;
  const int wr = w>>1, wc = w&1;
  const int lrow = lane>>3, lslot = lane&7;
  const int srck = lslot ^ (lrow&7);          // XOR-swizzled source k-chunk
  const char* g0 = (const char*)XH;
  const char* g1 = (const char*)XL;
  const char* g2 = (const char*)M;
  f32x4 acc[4][4];
  #pragma unroll
  for (int i=0;i<4;++i)
    #pragma unroll
    for (int j=0;j<4;++j) acc[i][j] = f32x4{0.f,0.f,0.f,0.f};
  const int fl = lane&15, kq = lane>>4;

  for (int kk=0; kk<512; kk+=64){
    #pragma unroll
    for (int s=0; s<12; ++s){
      int instId = w + s*4;
      int tile = instId>>4, inst = instId&15;
      const char* g = (tile==0? g0 : (tile==1? g1 : g2));
      int rb = (tile<2? cBase : nBase) + inst*8 + lrow;
      stage16(g + (size_t)rb*(N_*2) + kk*2 + srck*16,
              (char*)lds + tile*16384 + inst*1024);
    }
    __syncthreads();
    #pragma unroll
    for (int kh=0; kh<2; ++kh){
      bf16x8 ah[4], alo[4], bm[4];
      #pragma unroll
      for (int fi=0; fi<4; ++fi){
        int row = (wr<<6) + (fi<<4) + fl;
        int off = (row<<6) + (((kq + (kh<<2)) ^ (row&7))<<3);
        ah[fi]  = *(const bf16x8*)&lds[off];
        alo[fi] = *(const bf16x8*)&lds[TILE_USH + off];
      }
      #pragma unroll
      for (int fj=0; fj<4; ++fj){
        int row = (wc<<6) + (fj<<4) + fl;
        int off = (row<<6) + (((kq + (kh<<2)) ^ (row&7))<<3);
        bm[fj] = *(const bf16x8*)&lds[2*TILE_USH + off];
      }
      #pragma unroll
      for (int fi=0; fi<4; ++fi)
        #pragma unroll
        for (int fj=0; fj<4; ++fj){
          acc[fi][fj] = __builtin_amdgcn_mfma_f32_16x16x32_bf16(ah[fi],  bm[fj], acc[fi][fj], 0,0,0);
          acc[fi][fj] = __builtin_amdgcn_mfma_f32_16x16x32_bf16(alo[fi], bm[fj], acc[fi][fj], 0,0,0);
        }
    }
    __syncthreads();
  }
  #pragma unroll
  for (int fi=0; fi<4; ++fi){
    int cg = cBase + (wr<<6) + (fi<<4) + (kq<<2);
    #pragma unroll
    for (int fj=0; fj<4; ++fj){
      int ng = nBase + (wc<<6) + (fj<<4) + fl;
      float4 v = make_float4(acc[fi][fj][0], acc[fi][fj][1], acc[fi][fj][2], acc[fi][fj][3]);
      *(float4*)&OUT[(size_t)ng*OUTS_ + cg] = v;
    }
  }
}

// ---------- weight prep (int16 per-o-column scaled) ----------
__global__ __launch_bounds__(256) void k_wmax(const float* __restrict__ wp, const float* __restrict__ emb,
                       unsigned int* __restrict__ sb, int KIO, int O){
  __shared__ float es[N_*ED_];
  for (int e = threadIdx.x; e < N_*ED_; e += 256) es[e] = emb[e];
  __syncthreads();
  int e = blockIdx.x*256 + threadIdx.x;
  if (e >= KIO) return;
  int o = e % O;
  float wv[ED_];
  #pragma unroll
  for (int d=0; d<ED_; ++d) wv[d] = wp[(size_t)d*KIO + e];
  float m = 0.f;
  for (int n=0; n<N_; ++n){
    float a = 0.f;
    #pragma unroll
    for (int d=0; d<ED_; ++d) a += es[n*ED_+d]*wv[d];
    m = fmaxf(m, fabsf(a));
  }
  atomicMax(&sb[o], __float_as_uint(m));
}

__global__ __launch_bounds__(256) void k_wquant(const float* __restrict__ wp, const float* __restrict__ emb,
                         const unsigned int* __restrict__ sb, short* __restrict__ W, int KIO, int O){
  __shared__ float es[N_*ED_];
  for (int e = threadIdx.x; e < N_*ED_; e += 256) es[e] = emb[e];
  __syncthreads();
  int e = blockIdx.x*256 + threadIdx.x;
  if (e >= KIO) return;
  int o = e % O;
  float M = __uint_as_float(sb[o]);
  float inv = (M > 0.f) ? 32767.f/M : 0.f;
  float wv[ED_];
  #pragma unroll
  for (int d=0; d<ED_; ++d) wv[d] = wp[(size_t)d*KIO + e];
  for (int n=0; n<N_; ++n){
    float a = 0.f;
    #pragma unroll
    for (int d=0; d<ED_; ++d) a += es[n*ED_+d]*wv[d];
    W[(size_t)n*KIO + e] = (short)__float2int_rn(a*inv);
  }
}

__global__ __launch_bounds__(256) void k_bias(const float* __restrict__ bp, const float* __restrict__ emb,
                       float* __restrict__ Bo, int O){
  int idx = blockIdx.x*256 + threadIdx.x;
  int o = idx % O, n = idx / O;
  float a = 0.f;
  #pragma unroll
  for (int d=0; d<ED_; ++d) a += emb[n*ED_+d]*bp[d*O+o];
  Bo[idx] = a;
}

__global__ void k_fill0(float* __restrict__ p, size_t n){
  size_t i = (size_t)blockIdx.x*blockDim.x + threadIdx.x;
  size_t stride = (size_t)gridDim.x*blockDim.x;
  for (; i<n; i+=stride) p[i] = 0.f;
}

// ---------- plane builders (col-major world: plane[col][m], col = b*CIN+c) ----------
__global__ __launch_bounds__(256) void k_bx0(const float* __restrict__ src, const float* __restrict__ hA,
                      ushort_t* __restrict__ XH, ushort_t* __restrict__ XL, int t){
  int idx = blockIdx.x*256 + threadIdx.x;   // < 2080*512 ; idx = col*512 + m
  int m = idx & (N_-1), col = idx >> 9;
  int b = col/65, c = col%65;
  float x = (c==0) ? src[((size_t)(b*T_+t))*N_ + m] : hA[(size_t)m*(B_*H_) + b*H_ + (c-1)];
  ushort_t xh = f2b(x);
  XH[idx] = xh; XL[idx] = f2b(x - b2f(xh));
}
__global__ __launch_bounds__(256) void k_bx1(const float* __restrict__ hA, const float* __restrict__ hB,
                      ushort_t* __restrict__ XH, ushort_t* __restrict__ XL){
  int idx = blockIdx.x*256 + threadIdx.x;   // < 4096*512
  int m = idx & (N_-1), col = idx >> 9;
  int c = col & 127, b = col >> 7;
  float x = (c<H_) ? hA[(size_t)m*(B_*H_) + b*H_ + c] : hB[(size_t)m*(B_*H_) + b*H_ + (c-H_)];
  ushort_t xh = f2b(x);
  XH[idx] = xh; XL[idx] = f2b(x - b2f(xh));
}

// ---------- per-node gate (O=128) ----------
template<int CIN>
__global__ __launch_bounds__(256) void k_gate(
    const float* __restrict__ src, int t,
    const float* __restrict__ hx, const float* __restrict__ hy,
    const float* __restrict__ P, const float* __restrict__ Rm, const float* __restrict__ Qm,
    const float* __restrict__ dvec, const float* __restrict__ lam,
    const short* __restrict__ W, const float* __restrict__ Wsc, const float* __restrict__ Bb,
    const float* __restrict__ hstate,
    float* __restrict__ cand, float* __restrict__ rbuf,
    ushort_t* __restrict__ XH, ushort_t* __restrict__ XL)
{
  constexpr int O = 2*H_;        // 128
  constexpr int G = 256/O;       // 2
  constexpr int NB = B_/G;       // 16
  constexpr int COFF = (CIN==65) ? 1 : H_;
  __shared__ float A[3*B_*CIN];
  int n = blockIdx.x;
  float lm = lam[0];
  float al = -2.f/lm;
  float dn = 2.f*dvec[n]/lm - 1.f;
  float c_r = 2.f*al*al, c_q = 2.f*al, c_p = 2.f*al*dn, c_x = 2.f*dn*dn - 1.f;
  for (int e = threadIdx.x; e < B_*CIN; e += 256){
    int b = e/CIN, c = e%CIN;
    float x;
    if (CIN==65) x = (c==0) ? src[((size_t)(b*T_+t))*N_ + n] : hx[(size_t)n*(B_*H_) + b*H_ + (c-1)];
    else         x = (c<H_) ? hx[(size_t)n*(B_*H_) + b*H_ + c] : hy[(size_t)n*(B_*H_) + b*H_ + (c-H_)];
    size_t pi = (size_t)n*OUTS_ + e;
    float pe = P[pi], re = Rm[pi], qe = Qm[pi];
    A[e]           = x;
    A[B_*CIN+e]    = al*pe + dn*x;
    A[2*B_*CIN+e]  = c_r*re + c_q*qe + c_p*pe + c_x*x;
  }
  __syncthreads();
  int o = threadIdx.x % O;
  int g = threadIdx.x / O;
  float acc[NB];
  #pragma unroll
  for (int i=0;i<NB;++i) acc[i] = 0.f;
  const short* Wn = W + (size_t)n*(3*CIN)*O + o;
  for (int k=0;k<3;++k){
    const float* Ak = A + k*B_*CIN;
    for (int i=0;i<CIN;++i){
      float wv = (float)Wn[(size_t)(k*CIN+i)*O];
      #pragma unroll
      for (int bi=0;bi<NB;++bi) acc[bi] += Ak[(g+bi*G)*CIN + i]*wv;
    }
  }
  float sc = Wsc[o]*(1.f/32767.f);
  float bias = Bb[n*O+o];
  if (o < H_){
    #pragma unroll
    for (int bi=0;bi<NB;++bi){
      int b = g + bi*G;
      float z = sigmoidf_(acc[bi]*sc + bias);
      float hv = hstate[(size_t)n*(B_*H_) + b*H_ + o];
      float v = z*hv;
      cand[(size_t)n*(B_*H_) + b*H_ + o] = v;
      int col = b*CIN + COFF + o;
      ushort_t vh = f2b(v);
      XH[(size_t)col*N_ + n] = vh;
      XL[(size_t)col*N_ + n] = f2b(v - b2f(vh));
    }
  } else {
    int oo = o - H_;
    #pragma unroll
    for (int bi=0;bi<NB;++bi){
      int b = g + bi*G;
      rbuf[(size_t)n*(B_*H_) + b*H_ + oo] = sigmoidf_(acc[bi]*sc + bias);
    }
  }
}

// ---------- per-node update (O=64) + GRU state ----------
template<int CIN>
__global__ __launch_bounds__(256) void k_update(
    const float* __restrict__ src, int t,
    const float* __restrict__ hx, const float* __restrict__ cand,
    const float* __restrict__ P, const float* __restrict__ Rm, const float* __restrict__ Qm,
    const float* __restrict__ dvec, const float* __restrict__ lam,
    const short* __restrict__ W, const float* __restrict__ Wsc, const float* __restrict__ Bb,
    const float* __restrict__ rbuf, float* __restrict__ h)
{
  constexpr int O = H_;          // 64
  constexpr int G = 256/O;       // 4
  constexpr int NB = B_/G;       // 8
  __shared__ float A[3*B_*CIN];
  int n = blockIdx.x;
  float lm = lam[0];
  float al = -2.f/lm;
  float dn = 2.f*dvec[n]/lm - 1.f;
  float c_r = 2.f*al*al, c_q = 2.f*al, c_p = 2.f*al*dn, c_x = 2.f*dn*dn - 1.f;
  for (int e = threadIdx.x; e < B_*CIN; e += 256){
    int b = e/CIN, c = e%CIN;
    float x;
    if (CIN==65) x = (c==0) ? src[((size_t)(b*T_+t))*N_ + n] : cand[(size_t)n*(B_*H_) + b*H_ + (c-1)];
    else         x = (c<H_) ? hx[(size_t)n*(B_*H_) + b*H_ + c] : cand[(size_t)n*(B_*H_) + b*H_ + (c-H_)];
    size_t pi = (size_t)n*OUTS_ + e;
    float pe = P[pi], re = Rm[pi], qe = Qm[pi];
    A[e]           = x;
    A[B_*CIN+e]    = al*pe + dn*x;
    A[2*B_*CIN+e]  = c_r*re + c_q*qe + c_p*pe + c_x*x;
  }
  __syncthreads();
  int o = threadIdx.x % O;
  int g = threadIdx.x / O;
  float acc[NB];
  #pragma unroll
  for (int i=0;i<NB;++i) acc[i] = 0.f;
  const short* Wn = W + (size_t)n*(3*CIN)*O + o;
  for (int k=0;k<3;++k){
    const float* Ak = A + k*B_*CIN;
    for (int i=0;i<CIN;++i){
      float wv = (float)Wn[(size_t)(k*CIN+i)*O];
      #pragma unroll
      for (int bi=0;bi<NB;++bi) acc[bi] += Ak[(g+bi*G)*CIN + i]*wv;
    }
  }
  float sc = Wsc[o]*(1.f/32767.f);
  float bias = Bb[n*O+o];
  #pragma unroll
  for (int bi=0;bi<NB;++bi){
    int b = g + bi*G;
    float hc = tanhf(acc[bi]*sc + bias);
    size_t hidx = (size_t)n*(B_*H_) + b*H_ + o;
    float r = rbuf[hidx];
    h[hidx] = r*h[hidx] + (1.f-r)*hc;
  }
}

// ---------- readout ----------
__global__ __launch_bounds__(256) void k_readout(const float* __restrict__ hB, const float* __restrict__ cw,
                          const float* __restrict__ cb, float* __restrict__ out){
  int idx = blockIdx.x*256 + threadIdx.x;
  int n = idx & (N_-1);
  int bo = idx >> 9;
  int o = bo % HOR_, b = bo / HOR_;
  float a = cb[o];
  #pragma unroll
  for (int j=0;j<H_;++j) a += hB[(size_t)n*(B_*H_) + b*H_ + j]*cw[o*H_+j];
  out[idx] = a;
}

extern "C" void kernel_launch(void* const* d_in, const int* in_sizes, int n_in,
                              void* d_out, int out_size, void* d_ws, size_t ws_size,
                              hipStream_t stream){
  (void)in_sizes; (void)n_in; (void)out_size; (void)ws_size;
  const float* src  = (const float*)d_in[0];
  const float* gn   = (const float*)d_in[2];
  const float* emb  = (const float*)d_in[3];
  const float* gw0  = (const float*)d_in[4];
  const float* gb0  = (const float*)d_in[5];
  const float* uw0  = (const float*)d_in[6];
  const float* ub0  = (const float*)d_in[7];
  const float* gw1  = (const float*)d_in[8];
  const float* gb1  = (const float*)d_in[9];
  const float* uw1  = (const float*)d_in[10];
  const float* ub1  = (const float*)d_in[11];
  const float* cw   = (const float*)d_in[12];
  const float* cb   = (const float*)d_in[13];
  float* out = (float*)d_out;

  char* ws = (char*)d_ws;
  size_t off = 0;
  auto alloc = [&](size_t bytes)->char*{
    char* p = ws + off; off = (off + bytes + 255) & ~(size_t)255; return p;
  };
  short* Wg0 = (short*)alloc((size_t)N_*195*128*2);
  short* Wu0 = (short*)alloc((size_t)N_*195*64*2);
  short* Wg1 = (short*)alloc((size_t)N_*384*128*2);
  short* Wu1 = (short*)alloc((size_t)N_*384*64*2);
  unsigned int* Sg0 = (unsigned int*)alloc(128*4);
  unsigned int* Su0 = (unsigned int*)alloc(64*4);
  unsigned int* Sg1 = (unsigned int*)alloc(128*4);
  unsigned int* Su1 = (unsigned int*)alloc(64*4);
  float* Bg0 = (float*)alloc((size_t)N_*128*4);
  float* Bu0 = (float*)alloc((size_t)N_*64*4);
  float* Bg1 = (float*)alloc((size_t)N_*128*4);
  float* Bu1 = (float*)alloc((size_t)N_*64*4);
  ushort_t* Abf  = (ushort_t*)alloc((size_t)N_*N_*2);
  ushort_t* A2bf = (ushort_t*)alloc((size_t)N_*N_*2);
  ushort_t* ADh  = (ushort_t*)alloc((size_t)N_*N_*2);
  float* dvec = (float*)alloc(N_*4);
  float* lam  = (float*)alloc(256);
  float* nrm  = (float*)alloc(N_*4);
  float* hA   = (float*)alloc((size_t)N_*B_*H_*4);
  float* hB   = (float*)alloc((size_t)N_*B_*H_*4);
  float* rbuf = (float*)alloc((size_t)N_*B_*H_*4);
  float* cand = (float*)alloc((size_t)N_*B_*H_*4);
  ushort_t* XH = (ushort_t*)alloc((size_t)4096*N_*2);
  ushort_t* XL = (ushort_t*)alloc((size_t)4096*N_*2);
  float* P  = (float*)alloc((size_t)N_*OUTS_*4);
  float* R  = (float*)alloc((size_t)N_*OUTS_*4);
  float* Q  = (float*)alloc((size_t)N_*OUTS_*4);

  const float* fSg0 = (const float*)Sg0;
  const float* fSu0 = (const float*)Su0;
  const float* fSg1 = (const float*)Sg1;
  const float* fSu1 = (const float*)Su1;

  // graph structure
  k_norm<<<1,512,0,stream>>>(emb, nrm);
  k_adj<<<N_,256,0,stream>>>(emb, nrm, gn, Abf, dvec);
  k_lam<<<1,512,0,stream>>>(dvec, lam);
  k_a2<<<N_,256,0,stream>>>(Abf, A2bf);
  k_admats<<<(N_*N_)/256,256,0,stream>>>(Abf, dvec, lam, ADh);

  // weights (int16 per-o-column scale) + biases (f32)
  k_fill0<<<1,256,0,stream>>>((float*)Sg0, 384);
  k_wmax<<<(195*128+255)/256,256,0,stream>>>(gw0, emb, Sg0, 195*128, 128);
  k_wmax<<<(195*64+255)/256,256,0,stream>>>(uw0, emb, Su0, 195*64, 64);
  k_wmax<<<(384*128)/256,256,0,stream>>>(gw1, emb, Sg1, 384*128, 128);
  k_wmax<<<(384*64)/256,256,0,stream>>>(uw1, emb, Su1, 384*64, 64);
  k_wquant<<<(195*128+255)/256,256,0,stream>>>(gw0, emb, Sg0, Wg0, 195*128, 128);
  k_wquant<<<(195*64+255)/256,256,0,stream>>>(uw0, emb, Su0, Wu0, 195*64, 64);
  k_wquant<<<(384*128)/256,256,0,stream>>>(gw1, emb, Sg1, Wg1, 384*128, 128);
  k_wquant<<<(384*64)/256,256,0,stream>>>(uw1, emb, Su1, Wu1, 384*64, 64);
  k_bias<<<(N_*128)/256,256,0,stream>>>(gb0, emb, Bg0, 128);
  k_bias<<<(N_*64)/256,256,0,stream>>>(ub0, emb, Bu0, 64);
  k_bias<<<(N_*128)/256,256,0,stream>>>(gb1, emb, Bg1, 128);
  k_bias<<<(N_*64)/256,256,0,stream>>>(ub1, emb, Bu1, 64);

  k_fill0<<<2048,256,0,stream>>>(hA, (size_t)N_*B_*H_);
  k_fill0<<<2048,256,0,stream>>>(hB, (size_t)N_*B_*H_);

  for (int t=0; t<T_; ++t){
    // ---- layer 0 (CIN=65, cols padded to 2176 = 17*128) ----
    k_bx0<<<(2080*512)/256,256,0,stream>>>(src, hA, XH, XL, t);
    k_apply<<<dim3(17,4,3),256,0,stream>>>(XH, XL, Abf, A2bf, ADh, P, R, Q);
    k_gate<65><<<N_,256,0,stream>>>(src, t, hA, hA, P, R, Q, dvec, lam,
                                    Wg0, fSg0, Bg0, hA, cand, rbuf, XH, XL);
    k_apply<<<dim3(17,4,3),256,0,stream>>>(XH, XL, Abf, A2bf, ADh, P, R, Q);
    k_update<65><<<N_,256,0,stream>>>(src, t, hA, cand, P, R, Q, dvec, lam,
                                      Wu0, fSu0, Bu0, rbuf, hA);
    // ---- layer 1 (CIN=128, cols = 4096 = 32*128) ----
    k_bx1<<<(4096*512)/256,256,0,stream>>>(hA, hB, XH, XL);
    k_apply<<<dim3(32,4,3),256,0,stream>>>(XH, XL, Abf, A2bf, ADh, P, R, Q);
    k_gate<128><<<N_,256,0,stream>>>(nullptr, 0, hA, hB, P, R, Q, dvec, lam,
                                     Wg1, fSg1, Bg1, hB, cand, rbuf, XH, XL);
    k_apply<<<dim3(32,4,3),256,0,stream>>>(XH, XL, Abf, A2bf, ADh, P, R, Q);
    k_update<128><<<N_,256,0,stream>>>(nullptr, 0, hA, cand, P, R, Q, dvec, lam,
                                       Wu1, fSu1, Bu1, rbuf, hB);
  }

  k_readout<<<(B_*HOR_*N_)/256,256,0,stream>>>(hB, cw, cb, out);
}

// Round 7
// 3540.840 us; speedup vs baseline: 1.4712x; 1.1415x over previous
//
#include <hip/hip_runtime.h>
#include <math.h>

#define N_    512
#define B_    32
#define T_    12
#define H_    64
#define ED_   10
#define HOR_  12
#define OUTS_ 4096

typedef unsigned short ushort_t;
typedef __attribute__((ext_vector_type(4))) float f32x4;
typedef __attribute__((ext_vector_type(8))) __bf16 bf16x8;
typedef __attribute__((ext_vector_type(8))) short short8;

__device__ __forceinline__ float sigmoidf_(float x){ return 1.f/(1.f+expf(-x)); }
__device__ __forceinline__ float b2f(ushort_t u){ return __uint_as_float(((unsigned)u)<<16); }
__device__ __forceinline__ ushort_t f2b(float f){
  unsigned x = __float_as_uint(f);
  unsigned r = x + 0x7FFFu + ((x>>16)&1u);
  return (ushort_t)(r>>16);
}
__device__ __forceinline__ void stage16(const void* g, void* l){
  __builtin_amdgcn_global_load_lds(
    (const __attribute__((address_space(1))) unsigned int*)g,
    (__attribute__((address_space(3))) unsigned int*)l, 16, 0, 0);
}

// ---------- graph structure ----------
__global__ __launch_bounds__(512) void k_norm(const float* __restrict__ emb, float* __restrict__ nrm){
  int n = threadIdx.x;
  if (n < N_){
    float s = 0.f;
    #pragma unroll
    for (int d=0; d<ED_; ++d){ float v = emb[n*ED_+d]; s += v*v; }
    nrm[n] = sqrtf(s);
  }
}

__global__ __launch_bounds__(256) void k_adj(const float* __restrict__ emb, const float* __restrict__ nrm,
                      const float* __restrict__ gn, ushort_t* __restrict__ Abf, float* __restrict__ dvec){
  __shared__ float ei[ED_];
  __shared__ float red[256];
  int i = blockIdx.x;
  if (threadIdx.x < ED_) ei[threadIdx.x] = emb[i*ED_+threadIdx.x];
  __syncthreads();
  float ni = nrm[i];
  float part = 0.f;
  for (int j = threadIdx.x; j < N_; j += 256){
    float dot = 0.f;
    #pragma unroll
    for (int d=0; d<ED_; ++d) dot += ei[d]*emb[j*ED_+d];
    float lg = (dot/(ni*nrm[j]) + 1.f)*0.5f;
    size_t gi = ((size_t)i*N_ + j)*2;
    float y0 = lg + gn[gi];
    float y1 = (1.f - lg) + gn[gi+1];
    bool a = (j != i && y0 >= y1);
    Abf[(size_t)i*N_ + j] = a ? (ushort_t)0x3F80 : (ushort_t)0;
    part += a ? 1.f : 0.f;
  }
  red[threadIdx.x] = part;
  __syncthreads();
  for (int s=128; s>0; s>>=1){
    if (threadIdx.x < s) red[threadIdx.x] += red[threadIdx.x+s];
    __syncthreads();
  }
  if (threadIdx.x==0) dvec[i] = red[0];
}

__global__ __launch_bounds__(512) void k_lam(const float* __restrict__ dvec, float* __restrict__ lam){
  __shared__ float red[512];
  red[threadIdx.x] = dvec[threadIdx.x];
  __syncthreads();
  for (int s=256; s>0; s>>=1){
    if (threadIdx.x < s) red[threadIdx.x] = fmaxf(red[threadIdx.x], red[threadIdx.x+s]);
    __syncthreads();
  }
  if (threadIdx.x==0){
    float maxd = red[0];
    lam[0] = maxd + (maxd > 0.f ? 1.f : 0.f);
  }
}

__global__ __launch_bounds__(256) void k_a2(const ushort_t* __restrict__ Abf, ushort_t* __restrict__ A2bf){
  __shared__ float ar[N_];
  int n = blockIdx.x;
  for (int p = threadIdx.x; p < N_; p += 256) ar[p] = b2f(Abf[(size_t)n*N_ + p]);
  __syncthreads();
  int m0 = threadIdx.x, m1 = threadIdx.x + 256;
  float a0 = 0.f, a1 = 0.f;
  for (int p=0; p<N_; ++p){
    float ap = ar[p];
    a0 += ap * b2f(Abf[(size_t)p*N_ + m0]);
    a1 += ap * b2f(Abf[(size_t)p*N_ + m1]);
  }
  A2bf[(size_t)n*N_ + m0] = f2b(a0);
  A2bf[(size_t)n*N_ + m1] = f2b(a1);
}

__global__ __launch_bounds__(256) void k_admats(const ushort_t* __restrict__ Abf, const float* __restrict__ dvec,
                        const float* __restrict__ lam, ushort_t* __restrict__ ADh){
  int idx = blockIdx.x*256 + threadIdx.x;
  int m = idx & (N_-1);
  float dm = 2.f*dvec[m]/lam[0] - 1.f;
  ADh[idx] = Abf[idx] ? f2b(dm) : (ushort_t)0;
}

// ---------- MFMA apply ----------
#define TILE_USH 8192
__global__ __launch_bounds__(256) void k_apply(
    const ushort_t* __restrict__ XH, const ushort_t* __restrict__ XL,
    const ushort_t* __restrict__ Abf, const ushort_t* __restrict__ A2bf, const ushort_t* __restrict__ ADh,
    float* __restrict__ P, float* __restrict__ Rm, float* __restrict__ Qm)
{
  __shared__ ushort_t lds[3*TILE_USH];
  const int z = blockIdx.z;
  const ushort_t* M = (z==0)? Abf : (z==1)? A2bf : ADh;
  float* OUT = (z==0)? P : (z==1)? Rm : Qm;
  const int cBase = blockIdx.x<<7, nBase = blockIdx.y<<7;
  const int tid = threadIdx.x, lane = tid&63, w = tid>>6;
  const int wr = w>>1, wc = w&1;
  const int lrow = lane>>3, lslot = lane&7;
  const int srck = lslot ^ (lrow&7);
  const char* g0 = (const char*)XH;
  const char* g1 = (const char*)XL;
  const char* g2 = (const char*)M;
  f32x4 acc[4][4];
  #pragma unroll
  for (int i=0;i<4;++i)
    #pragma unroll
    for (int j=0;j<4;++j) acc[i][j] = f32x4{0.f,0.f,0.f,0.f};
  const int fl = lane&15, kq = lane>>4;

  for (int kk=0; kk<512; kk+=64){
    #pragma unroll
    for (int s=0; s<12; ++s){
      int instId = w + s*4;
      int tile = instId>>4, inst = instId&15;
      const char* g = (tile==0? g0 : (tile==1? g1 : g2));
      int rb = (tile<2? cBase : nBase) + inst*8 + lrow;
      stage16(g + (size_t)rb*(N_*2) + kk*2 + srck*16,
              (char*)lds + tile*16384 + inst*1024);
    }
    __syncthreads();
    #pragma unroll
    for (int kh=0; kh<2; ++kh){
      bf16x8 ah[4], alo[4], bm[4];
      #pragma unroll
      for (int fi=0; fi<4; ++fi){
        int row = (wr<<6) + (fi<<4) + fl;
        int off = (row<<6) + (((kq + (kh<<2)) ^ (row&7))<<3);
        ah[fi]  = *(const bf16x8*)&lds[off];
        alo[fi] = *(const bf16x8*)&lds[TILE_USH + off];
      }
      #pragma unroll
      for (int fj=0; fj<4; ++fj){
        int row = (wc<<6) + (fj<<4) + fl;
        int off = (row<<6) + (((kq + (kh<<2)) ^ (row&7))<<3);
        bm[fj] = *(const bf16x8*)&lds[2*TILE_USH + off];
      }
      #pragma unroll
      for (int fi=0; fi<4; ++fi)
        #pragma unroll
        for (int fj=0; fj<4; ++fj){
          acc[fi][fj] = __builtin_amdgcn_mfma_f32_16x16x32_bf16(ah[fi],  bm[fj], acc[fi][fj], 0,0,0);
          acc[fi][fj] = __builtin_amdgcn_mfma_f32_16x16x32_bf16(alo[fi], bm[fj], acc[fi][fj], 0,0,0);
        }
    }
    __syncthreads();
  }
  #pragma unroll
  for (int fi=0; fi<4; ++fi){
    int cg = cBase + (wr<<6) + (fi<<4) + (kq<<2);
    #pragma unroll
    for (int fj=0; fj<4; ++fj){
      int ng = nBase + (wc<<6) + (fj<<4) + fl;
      float4 v = make_float4(acc[fi][fj][0], acc[fi][fj][1], acc[fi][fj][2], acc[fi][fj][3]);
      *(float4*)&OUT[(size_t)ng*OUTS_ + cg] = v;
    }
  }
}

// ---------- weight prep: int16, per-o-column scale, TRANSPOSED padded layout W[n][o][RS] ----------
__global__ __launch_bounds__(256) void k_wmax(const float* __restrict__ wp, const float* __restrict__ emb,
                       unsigned int* __restrict__ sb, int KIO, int O){
  __shared__ float es[N_*ED_];
  for (int e = threadIdx.x; e < N_*ED_; e += 256) es[e] = emb[e];
  __syncthreads();
  int e = blockIdx.x*256 + threadIdx.x;
  if (e >= KIO) return;
  int o = e % O;
  float wv[ED_];
  #pragma unroll
  for (int d=0; d<ED_; ++d) wv[d] = wp[(size_t)d*KIO + e];
  float m = 0.f;
  for (int n=0; n<N_; ++n){
    float a = 0.f;
    #pragma unroll
    for (int d=0; d<ED_; ++d) a += es[n*ED_+d]*wv[d];
    m = fmaxf(m, fabsf(a));
  }
  atomicMax(&sb[o], __float_as_uint(m));
}

__global__ __launch_bounds__(256) void k_wquant(const float* __restrict__ wp, const float* __restrict__ emb,
                         const unsigned int* __restrict__ sb, short* __restrict__ W,
                         int KI, int O, int RS){
  __shared__ float es[N_*ED_];
  for (int e = threadIdx.x; e < N_*ED_; e += 256) es[e] = emb[e];
  __syncthreads();
  int e = blockIdx.x*256 + threadIdx.x;
  if (e >= O*RS) return;
  int o = e / RS, ki = e % RS;
  if (ki >= KI){
    for (int n=0; n<N_; ++n) W[((size_t)n*O + o)*RS + ki] = 0;
    return;
  }
  int KIO = KI*O;
  float M = __uint_as_float(sb[o]);
  float inv = (M > 0.f) ? 32767.f/M : 0.f;
  float wv[ED_];
  #pragma unroll
  for (int d=0; d<ED_; ++d) wv[d] = wp[(size_t)d*KIO + ki*O + o];
  for (int n=0; n<N_; ++n){
    float a = 0.f;
    #pragma unroll
    for (int d=0; d<ED_; ++d) a += es[n*ED_+d]*wv[d];
    W[((size_t)n*O + o)*RS + ki] = (short)__float2int_rn(a*inv);
  }
}

__global__ __launch_bounds__(256) void k_bias(const float* __restrict__ bp, const float* __restrict__ emb,
                       float* __restrict__ Bo, int O){
  int idx = blockIdx.x*256 + threadIdx.x;
  int o = idx % O, n = idx / O;
  float a = 0.f;
  #pragma unroll
  for (int d=0; d<ED_; ++d) a += emb[n*ED_+d]*bp[d*O+o];
  Bo[idx] = a;
}

__global__ void k_fill0(float* __restrict__ p, size_t n){
  size_t i = (size_t)blockIdx.x*blockDim.x + threadIdx.x;
  size_t stride = (size_t)gridDim.x*blockDim.x;
  for (; i<n; i+=stride) p[i] = 0.f;
}

// ---------- plane builders (LDS-tiled transpose, coalesced both sides) ----------
// S[m][b][j] (f32, [N][B][H]) -> XH/XL[(b*CIN+coff+j)*512 + m]; grid (8, 32, nz)
__global__ __launch_bounds__(256) void k_btr(const float* __restrict__ S0, const float* __restrict__ S1,
        ushort_t* __restrict__ XH, ushort_t* __restrict__ XL, int CIN, int coff0, int coff1){
  __shared__ float Tt[64][65];
  const float* S = blockIdx.z ? S1 : S0;
  int coff = blockIdx.z ? coff1 : coff0;
  int mt = blockIdx.x, b = blockIdx.y;
  int r = threadIdx.x >> 6;   // 0..3
  int j = threadIdx.x & 63;
  #pragma unroll
  for (int rr=0; rr<16; ++rr){
    int m = mt*64 + rr*4 + r;
    Tt[rr*4+r][j] = S[((size_t)m*B_ + b)*H_ + j];
  }
  __syncthreads();
  int mr = threadIdx.x & 63;
  int jq = threadIdx.x >> 6;
  #pragma unroll
  for (int jj=0; jj<16; ++jj){
    int jcol = jj*4 + jq;
    float x = Tt[mr][jcol];   // FIXED (R6 bug: was Tt[jcol][mr])
    size_t idx = ((size_t)(b*CIN + coff + jcol))*N_ + mt*64 + mr;
    ushort_t xh = f2b(x);
    XH[idx] = xh;
    XL[idx] = f2b(x - b2f(xh));
  }
}

// src column for layer0 (col b*65), coalesced
__global__ __launch_bounds__(256) void k_bsrc(const float* __restrict__ src,
        ushort_t* __restrict__ XH, ushort_t* __restrict__ XL, int t){
  int idx = blockIdx.x*256 + threadIdx.x;   // 32*512
  int m = idx & (N_-1), b = idx >> 9;
  float x = src[((size_t)(b*T_+t))*N_ + m];
  size_t o = ((size_t)(b*65))*N_ + m;
  ushort_t xh = f2b(x);
  XH[o] = xh; XL[o] = f2b(x - b2f(xh));
}

// ---------- per-node gate (O=128), register-blocked 4o x 4b, short8 weight streams ----------
template<int CIN>
__global__ __launch_bounds__(256) void k_gate(
    const float* __restrict__ src, int t,
    const float* __restrict__ hx, const float* __restrict__ hy,
    const float* __restrict__ P, const float* __restrict__ Rm, const float* __restrict__ Qm,
    const float* __restrict__ dvec, const float* __restrict__ lam,
    const short* __restrict__ W, const float* __restrict__ Wsc, const float* __restrict__ Bb,
    const float* __restrict__ hstate,
    float* __restrict__ cand, float* __restrict__ rbuf)
{
  constexpr int O  = 128;
  constexpr int RS = (3*CIN + 7) & ~7;
  constexpr int AS = RS + 4;
  __shared__ float A[B_*AS];
  int n = blockIdx.x;
  float lm = lam[0];
  float al = -2.f/lm;
  float dn = 2.f*dvec[n]/lm - 1.f;
  float c_r = 2.f*al*al, c_q = 2.f*al, c_p = 2.f*al*dn, c_x = 2.f*dn*dn - 1.f;
  for (int e = threadIdx.x; e < B_*CIN; e += 256){
    int b = e/CIN, c = e%CIN;
    float x;
    if (CIN==65) x = (c==0) ? src[((size_t)(b*T_+t))*N_ + n] : hx[(size_t)n*(B_*H_) + b*H_ + (c-1)];
    else         x = (c<H_) ? hx[(size_t)n*(B_*H_) + b*H_ + c] : hy[(size_t)n*(B_*H_) + b*H_ + (c-H_)];
    size_t pi = (size_t)n*OUTS_ + e;
    float pe = P[pi], re = Rm[pi], qe = Qm[pi];
    float* Ab = A + b*AS;
    Ab[c]         = x;
    Ab[CIN+c]     = al*pe + dn*x;
    Ab[2*CIN+c]   = c_r*re + c_q*qe + c_p*pe + c_x*x;
  }
  for (int e = threadIdx.x; e < B_*(AS-3*CIN); e += 256){
    int b = e/(AS-3*CIN), c = e%(AS-3*CIN);
    A[b*AS + 3*CIN + c] = 0.f;
  }
  __syncthreads();
  int ow = threadIdx.x & 31;   // o = ow*4 + oj
  int bq = threadIdx.x >> 5;   // b = bq*4 + bj
  float acc[4][4] = {};        // [oj][bj]
  const short* W0 = W + ((size_t)n*O + ow*4)*RS;
  const float* A0 = A + (bq*4)*AS;
  for (int kc=0; kc<RS; kc+=8){
    short8 w0 = *(const short8*)&W0[kc];
    short8 w1 = *(const short8*)&W0[RS + kc];
    short8 w2 = *(const short8*)&W0[2*RS + kc];
    short8 w3 = *(const short8*)&W0[3*RS + kc];
    #pragma unroll
    for (int kh=0; kh<2; ++kh){
      f32x4 a0 = *(const f32x4*)&A0[kc + kh*4];
      f32x4 a1 = *(const f32x4*)&A0[AS + kc + kh*4];
      f32x4 a2 = *(const f32x4*)&A0[2*AS + kc + kh*4];
      f32x4 a3 = *(const f32x4*)&A0[3*AS + kc + kh*4];
      #pragma unroll
      for (int u=0; u<4; ++u){
        float wv0 = (float)w0[kh*4+u];
        float wv1 = (float)w1[kh*4+u];
        float wv2 = (float)w2[kh*4+u];
        float wv3 = (float)w3[kh*4+u];
        acc[0][0] += a0[u]*wv0; acc[0][1] += a1[u]*wv0; acc[0][2] += a2[u]*wv0; acc[0][3] += a3[u]*wv0;
        acc[1][0] += a0[u]*wv1; acc[1][1] += a1[u]*wv1; acc[1][2] += a2[u]*wv1; acc[1][3] += a3[u]*wv1;
        acc[2][0] += a0[u]*wv2; acc[2][1] += a1[u]*wv2; acc[2][2] += a2[u]*wv2; acc[2][3] += a3[u]*wv2;
        acc[3][0] += a0[u]*wv3; acc[3][1] += a1[u]*wv3; acc[3][2] += a2[u]*wv3; acc[3][3] += a3[u]*wv3;
      }
    }
  }
  #pragma unroll
  for (int oj=0; oj<4; ++oj){
    int o = ow*4 + oj;
    float sc = Wsc[o]*(1.f/32767.f);
    float bias = Bb[n*O+o];
    if (o < H_){
      #pragma unroll
      for (int bj=0; bj<4; ++bj){
        int b = bq*4 + bj;
        float z = sigmoidf_(acc[oj][bj]*sc + bias);
        size_t hi = (size_t)n*(B_*H_) + b*H_ + o;
        float v = z*hstate[hi];
        cand[hi] = v;
      }
    } else {
      int oo = o - H_;
      #pragma unroll
      for (int bj=0; bj<4; ++bj){
        int b = bq*4 + bj;
        rbuf[(size_t)n*(B_*H_) + b*H_ + oo] = sigmoidf_(acc[oj][bj]*sc + bias);
      }
    }
  }
}

// ---------- per-node update (O=64), 4o x 2b per thread ----------
template<int CIN>
__global__ __launch_bounds__(256) void k_update(
    const float* __restrict__ src, int t,
    const float* __restrict__ hx, const float* __restrict__ cand,
    const float* __restrict__ P, const float* __restrict__ Rm, const float* __restrict__ Qm,
    const float* __restrict__ dvec, const float* __restrict__ lam,
    const short* __restrict__ W, const float* __restrict__ Wsc, const float* __restrict__ Bb,
    const float* __restrict__ rbuf, float* __restrict__ h)
{
  constexpr int O  = 64;
  constexpr int RS = (3*CIN + 7) & ~7;
  constexpr int AS = RS + 4;
  __shared__ float A[B_*AS];
  int n = blockIdx.x;
  float lm = lam[0];
  float al = -2.f/lm;
  float dn = 2.f*dvec[n]/lm - 1.f;
  float c_r = 2.f*al*al, c_q = 2.f*al, c_p = 2.f*al*dn, c_x = 2.f*dn*dn - 1.f;
  for (int e = threadIdx.x; e < B_*CIN; e += 256){
    int b = e/CIN, c = e%CIN;
    float x;
    if (CIN==65) x = (c==0) ? src[((size_t)(b*T_+t))*N_ + n] : cand[(size_t)n*(B_*H_) + b*H_ + (c-1)];
    else         x = (c<H_) ? hx[(size_t)n*(B_*H_) + b*H_ + c] : cand[(size_t)n*(B_*H_) + b*H_ + (c-H_)];
    size_t pi = (size_t)n*OUTS_ + e;
    float pe = P[pi], re = Rm[pi], qe = Qm[pi];
    float* Ab = A + b*AS;
    Ab[c]         = x;
    Ab[CIN+c]     = al*pe + dn*x;
    Ab[2*CIN+c]   = c_r*re + c_q*qe + c_p*pe + c_x*x;
  }
  for (int e = threadIdx.x; e < B_*(AS-3*CIN); e += 256){
    int b = e/(AS-3*CIN), c = e%(AS-3*CIN);
    A[b*AS + 3*CIN + c] = 0.f;
  }
  __syncthreads();
  int ow = threadIdx.x & 15;   // o = ow*4 + oj
  int bq = threadIdx.x >> 4;   // b = bq*2 + bj
  float acc[4][2] = {};
  const short* W0 = W + ((size_t)n*O + ow*4)*RS;
  const float* A0 = A + (bq*2)*AS;
  for (int kc=0; kc<RS; kc+=8){
    short8 w0 = *(const short8*)&W0[kc];
    short8 w1 = *(const short8*)&W0[RS + kc];
    short8 w2 = *(const short8*)&W0[2*RS + kc];
    short8 w3 = *(const short8*)&W0[3*RS + kc];
    #pragma unroll
    for (int kh=0; kh<2; ++kh){
      f32x4 a0 = *(const f32x4*)&A0[kc + kh*4];
      f32x4 a1 = *(const f32x4*)&A0[AS + kc + kh*4];
      #pragma unroll
      for (int u=0; u<4; ++u){
        float wv0 = (float)w0[kh*4+u];
        float wv1 = (float)w1[kh*4+u];
        float wv2 = (float)w2[kh*4+u];
        float wv3 = (float)w3[kh*4+u];
        acc[0][0] += a0[u]*wv0; acc[0][1] += a1[u]*wv0;
        acc[1][0] += a0[u]*wv1; acc[1][1] += a1[u]*wv1;
        acc[2][0] += a0[u]*wv2; acc[2][1] += a1[u]*wv2;
        acc[3][0] += a0[u]*wv3; acc[3][1] += a1[u]*wv3;
      }
    }
  }
  #pragma unroll
  for (int oj=0; oj<4; ++oj){
    int o = ow*4 + oj;
    float sc = Wsc[o]*(1.f/32767.f);
    float bias = Bb[n*O+o];
    #pragma unroll
    for (int bj=0; bj<2; ++bj){
      int b = bq*2 + bj;
      float hc = tanhf(acc[oj][bj]*sc + bias);
      size_t hidx = (size_t)n*(B_*H_) + b*H_ + o;
      float r = rbuf[hidx];
      h[hidx] = r*h[hidx] + (1.f-r)*hc;
    }
  }
}

// ---------- readout ----------
__global__ __launch_bounds__(256) void k_readout(const float* __restrict__ hB, const float* __restrict__ cw,
                          const float* __restrict__ cb, float* __restrict__ out){
  int idx = blockIdx.x*256 + threadIdx.x;
  int n = idx & (N_-1);
  int bo = idx >> 9;
  int o = bo % HOR_, b = bo / HOR_;
  float a = cb[o];
  #pragma unroll
  for (int j=0;j<H_;++j) a += hB[(size_t)n*(B_*H_) + b*H_ + j]*cw[o*H_+j];
  out[idx] = a;
}

extern "C" void kernel_launch(void* const* d_in, const int* in_sizes, int n_in,
                              void* d_out, int out_size, void* d_ws, size_t ws_size,
                              hipStream_t stream){
  (void)in_sizes; (void)n_in; (void)out_size; (void)ws_size;
  const float* src  = (const float*)d_in[0];
  const float* gn   = (const float*)d_in[2];
  const float* emb  = (const float*)d_in[3];
  const float* gw0  = (const float*)d_in[4];
  const float* gb0  = (const float*)d_in[5];
  const float* uw0  = (const float*)d_in[6];
  const float* ub0  = (const float*)d_in[7];
  const float* gw1  = (const float*)d_in[8];
  const float* gb1  = (const float*)d_in[9];
  const float* uw1  = (const float*)d_in[10];
  const float* ub1  = (const float*)d_in[11];
  const float* cw   = (const float*)d_in[12];
  const float* cb   = (const float*)d_in[13];
  float* out = (float*)d_out;

  const int RS0 = 200;  // (3*65+7)&~7
  const int RS1 = 384;  // 3*128

  char* ws = (char*)d_ws;
  size_t off = 0;
  auto alloc = [&](size_t bytes)->char*{
    char* p = ws + off; off = (off + bytes + 255) & ~(size_t)255; return p;
  };
  short* Wg0 = (short*)alloc((size_t)N_*128*RS0*2);
  short* Wu0 = (short*)alloc((size_t)N_*64*RS0*2);
  short* Wg1 = (short*)alloc((size_t)N_*128*RS1*2);
  short* Wu1 = (short*)alloc((size_t)N_*64*RS1*2);
  unsigned int* Sg0 = (unsigned int*)alloc(128*4);
  unsigned int* Su0 = (unsigned int*)alloc(64*4);
  unsigned int* Sg1 = (unsigned int*)alloc(128*4);
  unsigned int* Su1 = (unsigned int*)alloc(64*4);
  float* Bg0 = (float*)alloc((size_t)N_*128*4);
  float* Bu0 = (float*)alloc((size_t)N_*64*4);
  float* Bg1 = (float*)alloc((size_t)N_*128*4);
  float* Bu1 = (float*)alloc((size_t)N_*64*4);
  ushort_t* Abf  = (ushort_t*)alloc((size_t)N_*N_*2);
  ushort_t* A2bf = (ushort_t*)alloc((size_t)N_*N_*2);
  ushort_t* ADh  = (ushort_t*)alloc((size_t)N_*N_*2);
  float* dvec = (float*)alloc(N_*4);
  float* lam  = (float*)alloc(256);
  float* nrm  = (float*)alloc(N_*4);
  float* hA   = (float*)alloc((size_t)N_*B_*H_*4);
  float* hB   = (float*)alloc((size_t)N_*B_*H_*4);
  float* rbuf = (float*)alloc((size_t)N_*B_*H_*4);
  float* cand = (float*)alloc((size_t)N_*B_*H_*4);
  ushort_t* XH = (ushort_t*)alloc((size_t)4096*N_*2);
  ushort_t* XL = (ushort_t*)alloc((size_t)4096*N_*2);
  float* P  = (float*)alloc((size_t)N_*OUTS_*4);
  float* R  = (float*)alloc((size_t)N_*OUTS_*4);
  float* Q  = (float*)alloc((size_t)N_*OUTS_*4);

  const float* fSg0 = (const float*)Sg0;
  const float* fSu0 = (const float*)Su0;
  const float* fSg1 = (const float*)Sg1;
  const float* fSu1 = (const float*)Su1;

  // graph structure
  k_norm<<<1,512,0,stream>>>(emb, nrm);
  k_adj<<<N_,256,0,stream>>>(emb, nrm, gn, Abf, dvec);
  k_lam<<<1,512,0,stream>>>(dvec, lam);
  k_a2<<<N_,256,0,stream>>>(Abf, A2bf);
  k_admats<<<(N_*N_)/256,256,0,stream>>>(Abf, dvec, lam, ADh);

  // weights (int16 per-o-column scale, transposed+padded) + biases (f32)
  k_fill0<<<1,256,0,stream>>>((float*)Sg0, 384);
  k_wmax<<<(195*128+255)/256,256,0,stream>>>(gw0, emb, Sg0, 195*128, 128);
  k_wmax<<<(195*64+255)/256,256,0,stream>>>(uw0, emb, Su0, 195*64, 64);
  k_wmax<<<(384*128)/256,256,0,stream>>>(gw1, emb, Sg1, 384*128, 128);
  k_wmax<<<(384*64)/256,256,0,stream>>>(uw1, emb, Su1, 384*64, 64);
  k_wquant<<<(128*RS0+255)/256,256,0,stream>>>(gw0, emb, Sg0, Wg0, 195, 128, RS0);
  k_wquant<<<(64*RS0+255)/256,256,0,stream>>>(uw0, emb, Su0, Wu0, 195, 64, RS0);
  k_wquant<<<(128*RS1)/256,256,0,stream>>>(gw1, emb, Sg1, Wg1, 384, 128, RS1);
  k_wquant<<<(64*RS1)/256,256,0,stream>>>(uw1, emb, Su1, Wu1, 384, 64, RS1);
  k_bias<<<(N_*128)/256,256,0,stream>>>(gb0, emb, Bg0, 128);
  k_bias<<<(N_*64)/256,256,0,stream>>>(ub0, emb, Bu0, 64);
  k_bias<<<(N_*128)/256,256,0,stream>>>(gb1, emb, Bg1, 128);
  k_bias<<<(N_*64)/256,256,0,stream>>>(ub1, emb, Bu1, 64);

  k_fill0<<<2048,256,0,stream>>>(hA, (size_t)N_*B_*H_);
  k_fill0<<<2048,256,0,stream>>>(hB, (size_t)N_*B_*H_);

  for (int t=0; t<T_; ++t){
    // ---- layer 0 (CIN=65) ----
    k_bsrc<<<(B_*N_)/256,256,0,stream>>>(src, XH, XL, t);
    k_btr<<<dim3(8,32,1),256,0,stream>>>(hA, hA, XH, XL, 65, 1, 1);
    k_apply<<<dim3(17,4,3),256,0,stream>>>(XH, XL, Abf, A2bf, ADh, P, R, Q);
    k_gate<65><<<N_,256,0,stream>>>(src, t, hA, hA, P, R, Q, dvec, lam,
                                    Wg0, fSg0, Bg0, hA, cand, rbuf);
    k_btr<<<dim3(8,32,1),256,0,stream>>>(cand, cand, XH, XL, 65, 1, 1);
    k_apply<<<dim3(17,4,3),256,0,stream>>>(XH, XL, Abf, A2bf, ADh, P, R, Q);
    k_update<65><<<N_,256,0,stream>>>(src, t, hA, cand, P, R, Q, dvec, lam,
                                      Wu0, fSu0, Bu0, rbuf, hA);
    // ---- layer 1 (CIN=128) ----
    k_btr<<<dim3(8,32,2),256,0,stream>>>(hA, hB, XH, XL, 128, 0, 64);
    k_apply<<<dim3(32,4,3),256,0,stream>>>(XH, XL, Abf, A2bf, ADh, P, R, Q);
    k_gate<128><<<N_,256,0,stream>>>(nullptr, 0, hA, hB, P, R, Q, dvec, lam,
                                     Wg1, fSg1, Bg1, hB, cand, rbuf);
    k_btr<<<dim3(8,32,1),256,0,stream>>>(cand, cand, XH, XL, 128, 64, 64);
    k_apply<<<dim3(32,4,3),256,0,stream>>>(XH, XL, Abf, A2bf, ADh, P, R, Q);
    k_update<128><<<N_,256,0,stream>>>(nullptr, 0, hA, cand, P, R, Q, dvec, lam,
                                       Wu1, fSu1, Bu1, rbuf, hB);
  }

  k_readout<<<(B_*HOR_*N_)/256,256,0,stream>>>(hB, cw, cb, out);
}

// Round 8
// 3426.608 us; speedup vs baseline: 1.5202x; 1.0333x over previous
//
#include <hip/hip_runtime.h>
#include <math.h>

#define N_    512
#define B_    32
#define T_    12
#define H_    64
#define ED_   10
#define HOR_  12
#define OUTS_ 4096

typedef unsigned short ushort_t;
typedef __attribute__((ext_vector_type(4))) float f32x4;
typedef __attribute__((ext_vector_type(8))) __bf16 bf16x8;
typedef __attribute__((ext_vector_type(8))) short short8;

__device__ __forceinline__ float sigmoidf_(float x){ return 1.f/(1.f+expf(-x)); }
__device__ __forceinline__ float b2f(ushort_t u){ return __uint_as_float(((unsigned)u)<<16); }
__device__ __forceinline__ ushort_t f2b(float f){
  unsigned x = __float_as_uint(f);
  unsigned r = x + 0x7FFFu + ((x>>16)&1u);
  return (ushort_t)(r>>16);
}
__device__ __forceinline__ void stage16(const void* g, void* l){
  __builtin_amdgcn_global_load_lds(
    (const __attribute__((address_space(1))) unsigned int*)g,
    (__attribute__((address_space(3))) unsigned int*)l, 16, 0, 0);
}

// ---------- graph structure ----------
__global__ __launch_bounds__(512) void k_norm(const float* __restrict__ emb, float* __restrict__ nrm){
  int n = threadIdx.x;
  if (n < N_){
    float s = 0.f;
    #pragma unroll
    for (int d=0; d<ED_; ++d){ float v = emb[n*ED_+d]; s += v*v; }
    nrm[n] = sqrtf(s);
  }
}

__global__ __launch_bounds__(256) void k_adj(const float* __restrict__ emb, const float* __restrict__ nrm,
                      const float* __restrict__ gn, ushort_t* __restrict__ Abf, float* __restrict__ dvec){
  __shared__ float ei[ED_];
  __shared__ float red[256];
  int i = blockIdx.x;
  if (threadIdx.x < ED_) ei[threadIdx.x] = emb[i*ED_+threadIdx.x];
  __syncthreads();
  float ni = nrm[i];
  float part = 0.f;
  for (int j = threadIdx.x; j < N_; j += 256){
    float dot = 0.f;
    #pragma unroll
    for (int d=0; d<ED_; ++d) dot += ei[d]*emb[j*ED_+d];
    float lg = (dot/(ni*nrm[j]) + 1.f)*0.5f;
    size_t gi = ((size_t)i*N_ + j)*2;
    float y0 = lg + gn[gi];
    float y1 = (1.f - lg) + gn[gi+1];
    bool a = (j != i && y0 >= y1);
    Abf[(size_t)i*N_ + j] = a ? (ushort_t)0x3F80 : (ushort_t)0;
    part += a ? 1.f : 0.f;
  }
  red[threadIdx.x] = part;
  __syncthreads();
  for (int s=128; s>0; s>>=1){
    if (threadIdx.x < s) red[threadIdx.x] += red[threadIdx.x+s];
    __syncthreads();
  }
  if (threadIdx.x==0) dvec[i] = red[0];
}

__global__ __launch_bounds__(512) void k_lam(const float* __restrict__ dvec, float* __restrict__ lam){
  __shared__ float red[512];
  red[threadIdx.x] = dvec[threadIdx.x];
  __syncthreads();
  for (int s=256; s>0; s>>=1){
    if (threadIdx.x < s) red[threadIdx.x] = fmaxf(red[threadIdx.x], red[threadIdx.x+s]);
    __syncthreads();
  }
  if (threadIdx.x==0){
    float maxd = red[0];
    lam[0] = maxd + (maxd > 0.f ? 1.f : 0.f);
  }
}

__global__ __launch_bounds__(256) void k_a2(const ushort_t* __restrict__ Abf, ushort_t* __restrict__ A2bf){
  __shared__ float ar[N_];
  int n = blockIdx.x;
  for (int p = threadIdx.x; p < N_; p += 256) ar[p] = b2f(Abf[(size_t)n*N_ + p]);
  __syncthreads();
  int m0 = threadIdx.x, m1 = threadIdx.x + 256;
  float a0 = 0.f, a1 = 0.f;
  for (int p=0; p<N_; ++p){
    float ap = ar[p];
    a0 += ap * b2f(Abf[(size_t)p*N_ + m0]);
    a1 += ap * b2f(Abf[(size_t)p*N_ + m1]);
  }
  A2bf[(size_t)n*N_ + m0] = f2b(a0);
  A2bf[(size_t)n*N_ + m1] = f2b(a1);
}

__global__ __launch_bounds__(256) void k_admats(const ushort_t* __restrict__ Abf, const float* __restrict__ dvec,
                        const float* __restrict__ lam, ushort_t* __restrict__ ADh){
  int idx = blockIdx.x*256 + threadIdx.x;
  int m = idx & (N_-1);
  float dm = 2.f*dvec[m]/lam[0] - 1.f;
  ADh[idx] = Abf[idx] ? f2b(dm) : (ushort_t)0;
}

// ---------- MFMA apply ----------
#define TILE_USH 8192
__global__ __launch_bounds__(256) void k_apply(
    const ushort_t* __restrict__ XH, const ushort_t* __restrict__ XL,
    const ushort_t* __restrict__ Abf, const ushort_t* __restrict__ A2bf, const ushort_t* __restrict__ ADh,
    float* __restrict__ P, float* __restrict__ Rm, float* __restrict__ Qm)
{
  __shared__ ushort_t lds[3*TILE_USH];
  const int z = blockIdx.z;
  const ushort_t* M = (z==0)? Abf : (z==1)? A2bf : ADh;
  float* OUT = (z==0)? P : (z==1)? Rm : Qm;
  const int cBase = blockIdx.x<<7, nBase = blockIdx.y<<7;
  const int tid = threadIdx.x, lane = tid&63, w = tid>>6;
  const int wr = w>>1, wc = w&1;
  const int lrow = lane>>3, lslot = lane&7;
  const int srck = lslot ^ (lrow&7);
  const char* g0 = (const char*)XH;
  const char* g1 = (const char*)XL;
  const char* g2 = (const char*)M;
  f32x4 acc[4][4];
  #pragma unroll
  for (int i=0;i<4;++i)
    #pragma unroll
    for (int j=0;j<4;++j) acc[i][j] = f32x4{0.f,0.f,0.f,0.f};
  const int fl = lane&15, kq = lane>>4;

  for (int kk=0; kk<512; kk+=64){
    #pragma unroll
    for (int s=0; s<12; ++s){
      int instId = w + s*4;
      int tile = instId>>4, inst = instId&15;
      const char* g = (tile==0? g0 : (tile==1? g1 : g2));
      int rb = (tile<2? cBase : nBase) + inst*8 + lrow;
      stage16(g + (size_t)rb*(N_*2) + kk*2 + srck*16,
              (char*)lds + tile*16384 + inst*1024);
    }
    __syncthreads();
    #pragma unroll
    for (int kh=0; kh<2; ++kh){
      bf16x8 ah[4], alo[4], bm[4];
      #pragma unroll
      for (int fi=0; fi<4; ++fi){
        int row = (wr<<6) + (fi<<4) + fl;
        int off = (row<<6) + (((kq + (kh<<2)) ^ (row&7))<<3);
        ah[fi]  = *(const bf16x8*)&lds[off];
        alo[fi] = *(const bf16x8*)&lds[TILE_USH + off];
      }
      #pragma unroll
      for (int fj=0; fj<4; ++fj){
        int row = (wc<<6) + (fj<<4) + fl;
        int off = (row<<6) + (((kq + (kh<<2)) ^ (row&7))<<3);
        bm[fj] = *(const bf16x8*)&lds[2*TILE_USH + off];
      }
      #pragma unroll
      for (int fi=0; fi<4; ++fi)
        #pragma unroll
        for (int fj=0; fj<4; ++fj){
          acc[fi][fj] = __builtin_amdgcn_mfma_f32_16x16x32_bf16(ah[fi],  bm[fj], acc[fi][fj], 0,0,0);
          acc[fi][fj] = __builtin_amdgcn_mfma_f32_16x16x32_bf16(alo[fi], bm[fj], acc[fi][fj], 0,0,0);
        }
    }
    __syncthreads();
  }
  #pragma unroll
  for (int fi=0; fi<4; ++fi){
    int cg = cBase + (wr<<6) + (fi<<4) + (kq<<2);
    #pragma unroll
    for (int fj=0; fj<4; ++fj){
      int ng = nBase + (wc<<6) + (fj<<4) + fl;
      float4 v = make_float4(acc[fi][fj][0], acc[fi][fj][1], acc[fi][fj][2], acc[fi][fj][3]);
      *(float4*)&OUT[(size_t)ng*OUTS_ + cg] = v;
    }
  }
}

// ---------- weight prep: int16, per-o-column scale, packed layout W[n][kc][o][8] ----------
__global__ __launch_bounds__(256) void k_wmax(const float* __restrict__ wp, const float* __restrict__ emb,
                       unsigned int* __restrict__ sb, int KIO, int O){
  __shared__ float es[N_*ED_];
  for (int e = threadIdx.x; e < N_*ED_; e += 256) es[e] = emb[e];
  __syncthreads();
  int e = blockIdx.x*256 + threadIdx.x;
  if (e >= KIO) return;
  int o = e % O;
  float wv[ED_];
  #pragma unroll
  for (int d=0; d<ED_; ++d) wv[d] = wp[(size_t)d*KIO + e];
  float m = 0.f;
  int n0 = blockIdx.y*64;
  for (int n=n0; n<n0+64; ++n){
    float a = 0.f;
    #pragma unroll
    for (int d=0; d<ED_; ++d) a += es[n*ED_+d]*wv[d];
    m = fmaxf(m, fabsf(a));
  }
  atomicMax(&sb[o], __float_as_uint(m));
}

// thread -> (kc,o); writes contiguous short8 per n
__global__ __launch_bounds__(256) void k_wquant(const float* __restrict__ wp, const float* __restrict__ emb,
                         const unsigned int* __restrict__ sb, short* __restrict__ W,
                         int KI, int O, int RS){
  __shared__ float es[N_*ED_];
  for (int e = threadIdx.x; e < N_*ED_; e += 256) es[e] = emb[e];
  __syncthreads();
  int KC = RS/8;
  int e = blockIdx.x*256 + threadIdx.x;
  if (e >= KC*O) return;
  int o = e % O, kc = e / O;
  int KIO = KI*O;
  float M = __uint_as_float(sb[o]);
  float inv = (M > 0.f) ? 32767.f/M : 0.f;
  float wv[8][ED_];
  #pragma unroll
  for (int km=0; km<8; ++km){
    int ki = kc*8 + km;
    #pragma unroll
    for (int d=0; d<ED_; ++d)
      wv[km][d] = (ki < KI) ? wp[(size_t)d*KIO + (size_t)ki*O + o] : 0.f;
  }
  int n0 = blockIdx.y*32;
  for (int n=n0; n<n0+32; ++n){
    short8 q;
    #pragma unroll
    for (int km=0; km<8; ++km){
      float a = 0.f;
      #pragma unroll
      for (int d=0; d<ED_; ++d) a += es[n*ED_+d]*wv[km][d];
      q[km] = (short)__float2int_rn(a*inv);
    }
    *(short8*)&W[(((size_t)n*KC + kc)*O + o)*8] = q;
  }
}

__global__ __launch_bounds__(256) void k_bias(const float* __restrict__ bp, const float* __restrict__ emb,
                       float* __restrict__ Bo, int O){
  int idx = blockIdx.x*256 + threadIdx.x;
  int o = idx % O, n = idx / O;
  float a = 0.f;
  #pragma unroll
  for (int d=0; d<ED_; ++d) a += emb[n*ED_+d]*bp[d*O+o];
  Bo[idx] = a;
}

__global__ void k_fill0(float* __restrict__ p, size_t n){
  size_t i = (size_t)blockIdx.x*blockDim.x + threadIdx.x;
  size_t stride = (size_t)gridDim.x*blockDim.x;
  for (; i<n; i+=stride) p[i] = 0.f;
}

// ---------- plane builders ----------
__global__ __launch_bounds__(256) void k_btr(const float* __restrict__ S0, const float* __restrict__ S1,
        ushort_t* __restrict__ XH, ushort_t* __restrict__ XL, int CIN, int coff0, int coff1){
  __shared__ float Tt[64][65];
  const float* S = blockIdx.z ? S1 : S0;
  int coff = blockIdx.z ? coff1 : coff0;
  int mt = blockIdx.x, b = blockIdx.y;
  int r = threadIdx.x >> 6;
  int j = threadIdx.x & 63;
  #pragma unroll
  for (int rr=0; rr<16; ++rr){
    int m = mt*64 + rr*4 + r;
    Tt[rr*4+r][j] = S[((size_t)m*B_ + b)*H_ + j];
  }
  __syncthreads();
  int mr = threadIdx.x & 63;
  int jq = threadIdx.x >> 6;
  #pragma unroll
  for (int jj=0; jj<16; ++jj){
    int jcol = jj*4 + jq;
    float x = Tt[mr][jcol];
    size_t idx = ((size_t)(b*CIN + coff + jcol))*N_ + mt*64 + mr;
    ushort_t xh = f2b(x);
    XH[idx] = xh;
    XL[idx] = f2b(x - b2f(xh));
  }
}

__global__ __launch_bounds__(256) void k_bsrc(const float* __restrict__ src,
        ushort_t* __restrict__ XH, ushort_t* __restrict__ XL, int t){
  int idx = blockIdx.x*256 + threadIdx.x;
  int m = idx & (N_-1), b = idx >> 9;
  float x = src[((size_t)(b*T_+t))*N_ + m];
  size_t o = ((size_t)(b*65))*N_ + m;
  ushort_t xh = f2b(x);
  XH[o] = xh; XL[o] = f2b(x - b2f(xh));
}

// ---------- per-node gate (O=128) ----------
// CIN=65: 1 block/node, 32ow x 8bq, 4o x 4b per thread.
// CIN=128: gridDim.y=2 (o-halves), 16ow x 16bq, 4o x 2b per thread.
template<int CIN>
__global__ __launch_bounds__(256) void k_gate(
    const float* __restrict__ src, int t,
    const float* __restrict__ hx, const float* __restrict__ hy,
    const float* __restrict__ P, const float* __restrict__ Rm, const float* __restrict__ Qm,
    const float* __restrict__ dvec, const float* __restrict__ lam,
    const short* __restrict__ W, const float* __restrict__ Wsc, const float* __restrict__ Bb,
    const float* __restrict__ hstate,
    float* __restrict__ cand, float* __restrict__ rbuf)
{
  constexpr int O  = 128;
  constexpr int RS = (3*CIN + 7) & ~7;
  constexpr int KC = RS/8;
  constexpr int AS = RS + 4;
  constexpr int OW  = (CIN==65) ? 32 : 16;
  constexpr int NBJ = (CIN==65) ? 4 : 2;
  __shared__ float A[B_*AS];
  int n = blockIdx.x;
  float lm = lam[0];
  float al = -2.f/lm;
  float dn = 2.f*dvec[n]/lm - 1.f;
  float c_r = 2.f*al*al, c_q = 2.f*al, c_p = 2.f*al*dn, c_x = 2.f*dn*dn - 1.f;
  for (int e = threadIdx.x; e < B_*CIN; e += 256){
    int b = e/CIN, c = e%CIN;
    float x;
    if (CIN==65) x = (c==0) ? src[((size_t)(b*T_+t))*N_ + n] : hx[(size_t)n*(B_*H_) + b*H_ + (c-1)];
    else         x = (c<H_) ? hx[(size_t)n*(B_*H_) + b*H_ + c] : hy[(size_t)n*(B_*H_) + b*H_ + (c-H_)];
    size_t pi = (size_t)n*OUTS_ + e;
    float pe = P[pi], re = Rm[pi], qe = Qm[pi];
    float* Ab = A + b*AS;
    Ab[c]         = x;
    Ab[CIN+c]     = al*pe + dn*x;
    Ab[2*CIN+c]   = c_r*re + c_q*qe + c_p*pe + c_x*x;
  }
  for (int e = threadIdx.x; e < B_*(AS-3*CIN); e += 256){
    int b = e/(AS-3*CIN), c = e%(AS-3*CIN);
    A[b*AS + 3*CIN + c] = 0.f;
  }
  __syncthreads();
  int ow = threadIdx.x & (OW-1);
  int bq = threadIdx.x / OW;
  int o0 = (blockIdx.y*OW + ow)*4;
  float acc[4][NBJ] = {};
  const short* Wb = W + ((size_t)n*KC*O + o0)*8;
  const float* A0 = A + (bq*NBJ)*AS;
  for (int kc=0; kc<KC; ++kc){
    const short8* wp8 = (const short8*)(Wb + (size_t)kc*(O*8));
    short8 w0 = wp8[0], w1 = wp8[1], w2 = wp8[2], w3 = wp8[3];
    #pragma unroll
    for (int kh=0; kh<2; ++kh){
      f32x4 av[NBJ];
      #pragma unroll
      for (int bj=0; bj<NBJ; ++bj) av[bj] = *(const f32x4*)&A0[bj*AS + kc*8 + kh*4];
      #pragma unroll
      for (int u=0; u<4; ++u){
        float wv0 = (float)w0[kh*4+u];
        float wv1 = (float)w1[kh*4+u];
        float wv2 = (float)w2[kh*4+u];
        float wv3 = (float)w3[kh*4+u];
        #pragma unroll
        for (int bj=0; bj<NBJ; ++bj){
          acc[0][bj] += av[bj][u]*wv0;
          acc[1][bj] += av[bj][u]*wv1;
          acc[2][bj] += av[bj][u]*wv2;
          acc[3][bj] += av[bj][u]*wv3;
        }
      }
    }
  }
  #pragma unroll
  for (int oj=0; oj<4; ++oj){
    int o = o0 + oj;
    float sc = Wsc[o]*(1.f/32767.f);
    float bias = Bb[n*O+o];
    if (o < H_){
      #pragma unroll
      for (int bj=0; bj<NBJ; ++bj){
        int b = bq*NBJ + bj;
        float z = sigmoidf_(acc[oj][bj]*sc + bias);
        size_t hi = (size_t)n*(B_*H_) + b*H_ + o;
        cand[hi] = z*hstate[hi];
      }
    } else {
      int oo = o - H_;
      #pragma unroll
      for (int bj=0; bj<NBJ; ++bj){
        int b = bq*NBJ + bj;
        rbuf[(size_t)n*(B_*H_) + b*H_ + oo] = sigmoidf_(acc[oj][bj]*sc + bias);
      }
    }
  }
}

// ---------- per-node update (O=64): 16ow x 16bq, 4o x 2b ----------
template<int CIN>
__global__ __launch_bounds__(256) void k_update(
    const float* __restrict__ src, int t,
    const float* __restrict__ hx, const float* __restrict__ cand,
    const float* __restrict__ P, const float* __restrict__ Rm, const float* __restrict__ Qm,
    const float* __restrict__ dvec, const float* __restrict__ lam,
    const short* __restrict__ W, const float* __restrict__ Wsc, const float* __restrict__ Bb,
    const float* __restrict__ rbuf, float* __restrict__ h)
{
  constexpr int O  = 64;
  constexpr int RS = (3*CIN + 7) & ~7;
  constexpr int KC = RS/8;
  constexpr int AS = RS + 4;
  __shared__ float A[B_*AS];
  int n = blockIdx.x;
  float lm = lam[0];
  float al = -2.f/lm;
  float dn = 2.f*dvec[n]/lm - 1.f;
  float c_r = 2.f*al*al, c_q = 2.f*al, c_p = 2.f*al*dn, c_x = 2.f*dn*dn - 1.f;
  for (int e = threadIdx.x; e < B_*CIN; e += 256){
    int b = e/CIN, c = e%CIN;
    float x;
    if (CIN==65) x = (c==0) ? src[((size_t)(b*T_+t))*N_ + n] : cand[(size_t)n*(B_*H_) + b*H_ + (c-1)];
    else         x = (c<H_) ? hx[(size_t)n*(B_*H_) + b*H_ + c] : cand[(size_t)n*(B_*H_) + b*H_ + (c-H_)];
    size_t pi = (size_t)n*OUTS_ + e;
    float pe = P[pi], re = Rm[pi], qe = Qm[pi];
    float* Ab = A + b*AS;
    Ab[c]         = x;
    Ab[CIN+c]     = al*pe + dn*x;
    Ab[2*CIN+c]   = c_r*re + c_q*qe + c_p*pe + c_x*x;
  }
  for (int e = threadIdx.x; e < B_*(AS-3*CIN); e += 256){
    int b = e/(AS-3*CIN), c = e%(AS-3*CIN);
    A[b*AS + 3*CIN + c] = 0.f;
  }
  __syncthreads();
  int ow = threadIdx.x & 15;
  int bq = threadIdx.x >> 4;
  int o0 = ow*4;
  float acc[4][2] = {};
  const short* Wb = W + ((size_t)n*KC*O + o0)*8;
  const float* A0 = A + (bq*2)*AS;
  for (int kc=0; kc<KC; ++kc){
    const short8* wp8 = (const short8*)(Wb + (size_t)kc*(O*8));
    short8 w0 = wp8[0], w1 = wp8[1], w2 = wp8[2], w3 = wp8[3];
    #pragma unroll
    for (int kh=0; kh<2; ++kh){
      f32x4 a0 = *(const f32x4*)&A0[kc*8 + kh*4];
      f32x4 a1 = *(const f32x4*)&A0[AS + kc*8 + kh*4];
      #pragma unroll
      for (int u=0; u<4; ++u){
        float wv0 = (float)w0[kh*4+u];
        float wv1 = (float)w1[kh*4+u];
        float wv2 = (float)w2[kh*4+u];
        float wv3 = (float)w3[kh*4+u];
        acc[0][0] += a0[u]*wv0; acc[0][1] += a1[u]*wv0;
        acc[1][0] += a0[u]*wv1; acc[1][1] += a1[u]*wv1;
        acc[2][0] += a0[u]*wv2; acc[2][1] += a1[u]*wv2;
        acc[3][0] += a0[u]*wv3; acc[3][1] += a1[u]*wv3;
      }
    }
  }
  #pragma unroll
  for (int oj=0; oj<4; ++oj){
    int o = o0 + oj;
    float sc = Wsc[o]*(1.f/32767.f);
    float bias = Bb[n*O+o];
    #pragma unroll
    for (int bj=0; bj<2; ++bj){
      int b = bq*2 + bj;
      float hc = tanhf(acc[oj][bj]*sc + bias);
      size_t hidx = (size_t)n*(B_*H_) + b*H_ + o;
      float r = rbuf[hidx];
      h[hidx] = r*h[hidx] + (1.f-r)*hc;
    }
  }
}

// ---------- readout ----------
__global__ __launch_bounds__(256) void k_readout(const float* __restrict__ hB, const float* __restrict__ cw,
                          const float* __restrict__ cb, float* __restrict__ out){
  int idx = blockIdx.x*256 + threadIdx.x;
  int n = idx & (N_-1);
  int bo = idx >> 9;
  int o = bo % HOR_, b = bo / HOR_;
  float a = cb[o];
  #pragma unroll
  for (int j=0;j<H_;++j) a += hB[(size_t)n*(B_*H_) + b*H_ + j]*cw[o*H_+j];
  out[idx] = a;
}

extern "C" void kernel_launch(void* const* d_in, const int* in_sizes, int n_in,
                              void* d_out, int out_size, void* d_ws, size_t ws_size,
                              hipStream_t stream){
  (void)in_sizes; (void)n_in; (void)out_size; (void)ws_size;
  const float* src  = (const float*)d_in[0];
  const float* gn   = (const float*)d_in[2];
  const float* emb  = (const float*)d_in[3];
  const float* gw0  = (const float*)d_in[4];
  const float* gb0  = (const float*)d_in[5];
  const float* uw0  = (const float*)d_in[6];
  const float* ub0  = (const float*)d_in[7];
  const float* gw1  = (const float*)d_in[8];
  const float* gb1  = (const float*)d_in[9];
  const float* uw1  = (const float*)d_in[10];
  const float* ub1  = (const float*)d_in[11];
  const float* cw   = (const float*)d_in[12];
  const float* cb   = (const float*)d_in[13];
  float* out = (float*)d_out;

  const int RS0 = 200;  // (3*65+7)&~7
  const int RS1 = 384;  // 3*128

  char* ws = (char*)d_ws;
  size_t off = 0;
  auto alloc = [&](size_t bytes)->char*{
    char* p = ws + off; off = (off + bytes + 255) & ~(size_t)255; return p;
  };
  short* Wg0 = (short*)alloc((size_t)N_*128*RS0*2);
  short* Wu0 = (short*)alloc((size_t)N_*64*RS0*2);
  short* Wg1 = (short*)alloc((size_t)N_*128*RS1*2);
  short* Wu1 = (short*)alloc((size_t)N_*64*RS1*2);
  unsigned int* Sg0 = (unsigned int*)alloc(128*4);
  unsigned int* Su0 = (unsigned int*)alloc(64*4);
  unsigned int* Sg1 = (unsigned int*)alloc(128*4);
  unsigned int* Su1 = (unsigned int*)alloc(64*4);
  float* Bg0 = (float*)alloc((size_t)N_*128*4);
  float* Bu0 = (float*)alloc((size_t)N_*64*4);
  float* Bg1 = (float*)alloc((size_t)N_*128*4);
  float* Bu1 = (float*)alloc((size_t)N_*64*4);
  ushort_t* Abf  = (ushort_t*)alloc((size_t)N_*N_*2);
  ushort_t* A2bf = (ushort_t*)alloc((size_t)N_*N_*2);
  ushort_t* ADh  = (ushort_t*)alloc((size_t)N_*N_*2);
  float* dvec = (float*)alloc(N_*4);
  float* lam  = (float*)alloc(256);
  float* nrm  = (float*)alloc(N_*4);
  float* hA   = (float*)alloc((size_t)N_*B_*H_*4);
  float* hB   = (float*)alloc((size_t)N_*B_*H_*4);
  float* rbuf = (float*)alloc((size_t)N_*B_*H_*4);
  float* cand = (float*)alloc((size_t)N_*B_*H_*4);
  ushort_t* XH = (ushort_t*)alloc((size_t)4096*N_*2);
  ushort_t* XL = (ushort_t*)alloc((size_t)4096*N_*2);
  float* P  = (float*)alloc((size_t)N_*OUTS_*4);
  float* R  = (float*)alloc((size_t)N_*OUTS_*4);
  float* Q  = (float*)alloc((size_t)N_*OUTS_*4);

  const float* fSg0 = (const float*)Sg0;
  const float* fSu0 = (const float*)Su0;
  const float* fSg1 = (const float*)Sg1;
  const float* fSu1 = (const float*)Su1;

  // graph structure
  k_norm<<<1,512,0,stream>>>(emb, nrm);
  k_adj<<<N_,256,0,stream>>>(emb, nrm, gn, Abf, dvec);
  k_lam<<<1,512,0,stream>>>(dvec, lam);
  k_a2<<<N_,256,0,stream>>>(Abf, A2bf);
  k_admats<<<(N_*N_)/256,256,0,stream>>>(Abf, dvec, lam, ADh);

  // weights (int16 per-o-column scale, packed [n][kc][o][8]) + biases (f32)
  k_fill0<<<1,256,0,stream>>>((float*)Sg0, 384);
  k_wmax<<<dim3((195*128+255)/256,8),256,0,stream>>>(gw0, emb, Sg0, 195*128, 128);
  k_wmax<<<dim3((195*64+255)/256,8),256,0,stream>>>(uw0, emb, Su0, 195*64, 64);
  k_wmax<<<dim3((384*128)/256,8),256,0,stream>>>(gw1, emb, Sg1, 384*128, 128);
  k_wmax<<<dim3((384*64)/256,8),256,0,stream>>>(uw1, emb, Su1, 384*64, 64);
  k_wquant<<<dim3((25*128+255)/256,16),256,0,stream>>>(gw0, emb, Sg0, Wg0, 195, 128, RS0);
  k_wquant<<<dim3((25*64+255)/256,16),256,0,stream>>>(uw0, emb, Su0, Wu0, 195, 64, RS0);
  k_wquant<<<dim3((48*128)/256,16),256,0,stream>>>(gw1, emb, Sg1, Wg1, 384, 128, RS1);
  k_wquant<<<dim3((48*64)/256,16),256,0,stream>>>(uw1, emb, Su1, Wu1, 384, 64, RS1);
  k_bias<<<(N_*128)/256,256,0,stream>>>(gb0, emb, Bg0, 128);
  k_bias<<<(N_*64)/256,256,0,stream>>>(ub0, emb, Bu0, 64);
  k_bias<<<(N_*128)/256,256,0,stream>>>(gb1, emb, Bg1, 128);
  k_bias<<<(N_*64)/256,256,0,stream>>>(ub1, emb, Bu1, 64);

  k_fill0<<<2048,256,0,stream>>>(hA, (size_t)N_*B_*H_);
  k_fill0<<<2048,256,0,stream>>>(hB, (size_t)N_*B_*H_);

  for (int t=0; t<T_; ++t){
    // ---- layer 0 (CIN=65) ----
    k_bsrc<<<(B_*N_)/256,256,0,stream>>>(src, XH, XL, t);
    k_btr<<<dim3(8,32,1),256,0,stream>>>(hA, hA, XH, XL, 65, 1, 1);
    k_apply<<<dim3(17,4,3),256,0,stream>>>(XH, XL, Abf, A2bf, ADh, P, R, Q);
    k_gate<65><<<dim3(N_,1),256,0,stream>>>(src, t, hA, hA, P, R, Q, dvec, lam,
                                    Wg0, fSg0, Bg0, hA, cand, rbuf);
    k_btr<<<dim3(8,32,1),256,0,stream>>>(cand, cand, XH, XL, 65, 1, 1);
    k_apply<<<dim3(17,4,3),256,0,stream>>>(XH, XL, Abf, A2bf, ADh, P, R, Q);
    k_update<65><<<N_,256,0,stream>>>(src, t, hA, cand, P, R, Q, dvec, lam,
                                      Wu0, fSu0, Bu0, rbuf, hA);
    // ---- layer 1 (CIN=128) ----
    k_btr<<<dim3(8,32,2),256,0,stream>>>(hA, hB, XH, XL, 128, 0, 64);
    k_apply<<<dim3(32,4,3),256,0,stream>>>(XH, XL, Abf, A2bf, ADh, P, R, Q);
    k_gate<128><<<dim3(N_,2),256,0,stream>>>(nullptr, 0, hA, hB, P, R, Q, dvec, lam,
                                     Wg1, fSg1, Bg1, hB, cand, rbuf);
    k_btr<<<dim3(8,32,1),256,0,stream>>>(cand, cand, XH, XL, 128, 64, 64);
    k_apply<<<dim3(32,4,3),256,0,stream>>>(XH, XL, Abf, A2bf, ADh, P, R, Q);
    k_update<128><<<N_,256,0,stream>>>(nullptr, 0, hA, cand, P, R, Q, dvec, lam,
                                       Wu1, fSu1, Bu1, rbuf, hB);
  }

  k_readout<<<(B_*HOR_*N_)/256,256,0,stream>>>(hB, cw, cb, out);
}

// Round 9
// 2946.086 us; speedup vs baseline: 1.7682x; 1.1631x over previous
//
#include <hip/hip_runtime.h>
#include <math.h>

#define N_    512
#define B_    32
#define T_    12
#define H_    64
#define ED_   10
#define HOR_  12
#define OUTS_ 4096

typedef unsigned short ushort_t;
typedef __attribute__((ext_vector_type(4))) float f32x4;
typedef __attribute__((ext_vector_type(8))) __bf16 bf16x8;
typedef __attribute__((ext_vector_type(8))) short short8;

__device__ __forceinline__ float sigmoidf_(float x){ return 1.f/(1.f+expf(-x)); }
__device__ __forceinline__ float b2f(ushort_t u){ return __uint_as_float(((unsigned)u)<<16); }
__device__ __forceinline__ ushort_t f2b(float f){
  unsigned x = __float_as_uint(f);
  unsigned r = x + 0x7FFFu + ((x>>16)&1u);
  return (ushort_t)(r>>16);
}
__device__ __forceinline__ void stage16(const void* g, void* l){
  __builtin_amdgcn_global_load_lds(
    (const __attribute__((address_space(1))) unsigned int*)g,
    (__attribute__((address_space(3))) unsigned int*)l, 16, 0, 0);
}

// ---------- graph structure ----------
__global__ __launch_bounds__(512) void k_norm(const float* __restrict__ emb, float* __restrict__ nrm){
  int n = threadIdx.x;
  if (n < N_){
    float s = 0.f;
    #pragma unroll
    for (int d=0; d<ED_; ++d){ float v = emb[n*ED_+d]; s += v*v; }
    nrm[n] = sqrtf(s);
  }
}

__global__ __launch_bounds__(256) void k_adj(const float* __restrict__ emb, const float* __restrict__ nrm,
                      const float* __restrict__ gn, ushort_t* __restrict__ Abf, float* __restrict__ dvec){
  __shared__ float ei[ED_];
  __shared__ float red[256];
  int i = blockIdx.x;
  if (threadIdx.x < ED_) ei[threadIdx.x] = emb[i*ED_+threadIdx.x];
  __syncthreads();
  float ni = nrm[i];
  float part = 0.f;
  for (int j = threadIdx.x; j < N_; j += 256){
    float dot = 0.f;
    #pragma unroll
    for (int d=0; d<ED_; ++d) dot += ei[d]*emb[j*ED_+d];
    float lg = (dot/(ni*nrm[j]) + 1.f)*0.5f;
    size_t gi = ((size_t)i*N_ + j)*2;
    float y0 = lg + gn[gi];
    float y1 = (1.f - lg) + gn[gi+1];
    bool a = (j != i && y0 >= y1);
    Abf[(size_t)i*N_ + j] = a ? (ushort_t)0x3F80 : (ushort_t)0;
    part += a ? 1.f : 0.f;
  }
  red[threadIdx.x] = part;
  __syncthreads();
  for (int s=128; s>0; s>>=1){
    if (threadIdx.x < s) red[threadIdx.x] += red[threadIdx.x+s];
    __syncthreads();
  }
  if (threadIdx.x==0) dvec[i] = red[0];
}

__global__ __launch_bounds__(512) void k_lam(const float* __restrict__ dvec, float* __restrict__ lam){
  __shared__ float red[512];
  red[threadIdx.x] = dvec[threadIdx.x];
  __syncthreads();
  for (int s=256; s>0; s>>=1){
    if (threadIdx.x < s) red[threadIdx.x] = fmaxf(red[threadIdx.x], red[threadIdx.x+s]);
    __syncthreads();
  }
  if (threadIdx.x==0){
    float maxd = red[0];
    lam[0] = maxd + (maxd > 0.f ? 1.f : 0.f);
  }
}

__global__ __launch_bounds__(256) void k_a2(const ushort_t* __restrict__ Abf, ushort_t* __restrict__ A2bf){
  __shared__ float ar[N_];
  int n = blockIdx.x;
  for (int p = threadIdx.x; p < N_; p += 256) ar[p] = b2f(Abf[(size_t)n*N_ + p]);
  __syncthreads();
  int m0 = threadIdx.x, m1 = threadIdx.x + 256;
  float a0 = 0.f, a1 = 0.f;
  for (int p=0; p<N_; ++p){
    float ap = ar[p];
    a0 += ap * b2f(Abf[(size_t)p*N_ + m0]);
    a1 += ap * b2f(Abf[(size_t)p*N_ + m1]);
  }
  A2bf[(size_t)n*N_ + m0] = f2b(a0);
  A2bf[(size_t)n*N_ + m1] = f2b(a1);
}

__global__ __launch_bounds__(256) void k_admats(const ushort_t* __restrict__ Abf, const float* __restrict__ dvec,
                        const float* __restrict__ lam, ushort_t* __restrict__ ADh){
  int idx = blockIdx.x*256 + threadIdx.x;
  int m = idx & (N_-1);
  float dm = 2.f*dvec[m]/lam[0] - 1.f;
  ADh[idx] = Abf[idx] ? f2b(dm) : (ushort_t)0;
}

// ---------- MFMA apply ----------
#define TILE_USH 8192
__global__ __launch_bounds__(256) void k_apply(
    const ushort_t* __restrict__ XH, const ushort_t* __restrict__ XL,
    const ushort_t* __restrict__ Abf, const ushort_t* __restrict__ A2bf, const ushort_t* __restrict__ ADh,
    float* __restrict__ P, float* __restrict__ Rm, float* __restrict__ Qm)
{
  __shared__ ushort_t lds[3*TILE_USH];
  const int z = blockIdx.z;
  const ushort_t* M = (z==0)? Abf : (z==1)? A2bf : ADh;
  float* OUT = (z==0)? P : (z==1)? Rm : Qm;
  const int cBase = blockIdx.x<<7, nBase = blockIdx.y<<7;
  const int tid = threadIdx.x, lane = tid&63, w = tid>>6;
  const int wr = w>>1, wc = w&1;
  const int lrow = lane>>3, lslot = lane&7;
  const int srck = lslot ^ (lrow&7);
  const char* g0 = (const char*)XH;
  const char* g1 = (const char*)XL;
  const char* g2 = (const char*)M;
  f32x4 acc[4][4];
  #pragma unroll
  for (int i=0;i<4;++i)
    #pragma unroll
    for (int j=0;j<4;++j) acc[i][j] = f32x4{0.f,0.f,0.f,0.f};
  const int fl = lane&15, kq = lane>>4;

  for (int kk=0; kk<512; kk+=64){
    #pragma unroll
    for (int s=0; s<12; ++s){
      int instId = w + s*4;
      int tile = instId>>4, inst = instId&15;
      const char* g = (tile==0? g0 : (tile==1? g1 : g2));
      int rb = (tile<2? cBase : nBase) + inst*8 + lrow;
      stage16(g + (size_t)rb*(N_*2) + kk*2 + srck*16,
              (char*)lds + tile*16384 + inst*1024);
    }
    __syncthreads();
    #pragma unroll
    for (int kh=0; kh<2; ++kh){
      bf16x8 ah[4], alo[4], bm[4];
      #pragma unroll
      for (int fi=0; fi<4; ++fi){
        int row = (wr<<6) + (fi<<4) + fl;
        int off = (row<<6) + (((kq + (kh<<2)) ^ (row&7))<<3);
        ah[fi]  = *(const bf16x8*)&lds[off];
        alo[fi] = *(const bf16x8*)&lds[TILE_USH + off];
      }
      #pragma unroll
      for (int fj=0; fj<4; ++fj){
        int row = (wc<<6) + (fj<<4) + fl;
        int off = (row<<6) + (((kq + (kh<<2)) ^ (row&7))<<3);
        bm[fj] = *(const bf16x8*)&lds[2*TILE_USH + off];
      }
      #pragma unroll
      for (int fi=0; fi<4; ++fi)
        #pragma unroll
        for (int fj=0; fj<4; ++fj){
          acc[fi][fj] = __builtin_amdgcn_mfma_f32_16x16x32_bf16(ah[fi],  bm[fj], acc[fi][fj], 0,0,0);
          acc[fi][fj] = __builtin_amdgcn_mfma_f32_16x16x32_bf16(alo[fi], bm[fj], acc[fi][fj], 0,0,0);
        }
    }
    __syncthreads();
  }
  #pragma unroll
  for (int fi=0; fi<4; ++fi){
    int cg = cBase + (wr<<6) + (fi<<4) + (kq<<2);
    #pragma unroll
    for (int fj=0; fj<4; ++fj){
      int ng = nBase + (wc<<6) + (fj<<4) + fl;
      float4 v = make_float4(acc[fi][fj][0], acc[fi][fj][1], acc[fi][fj][2], acc[fi][fj][3]);
      *(float4*)&OUT[(size_t)ng*OUTS_ + cg] = v;
    }
  }
}

// ---------- weight prep: int16, per-o-column scale, packed layout W[n][kc][o][8] ----------
__global__ __launch_bounds__(256) void k_wmax(const float* __restrict__ wp, const float* __restrict__ emb,
                       unsigned int* __restrict__ sb, int KIO, int O){
  __shared__ float es[N_*ED_];
  for (int e = threadIdx.x; e < N_*ED_; e += 256) es[e] = emb[e];
  __syncthreads();
  int e = blockIdx.x*256 + threadIdx.x;
  if (e >= KIO) return;
  int o = e % O;
  float wv[ED_];
  #pragma unroll
  for (int d=0; d<ED_; ++d) wv[d] = wp[(size_t)d*KIO + e];
  float m = 0.f;
  int n0 = blockIdx.y*64;
  for (int n=n0; n<n0+64; ++n){
    float a = 0.f;
    #pragma unroll
    for (int d=0; d<ED_; ++d) a += es[n*ED_+d]*wv[d];
    m = fmaxf(m, fabsf(a));
  }
  atomicMax(&sb[o], __float_as_uint(m));
}

__global__ __launch_bounds__(256) void k_wquant(const float* __restrict__ wp, const float* __restrict__ emb,
                         const unsigned int* __restrict__ sb, short* __restrict__ W,
                         int KI, int O, int RS){
  __shared__ float es[N_*ED_];
  for (int e = threadIdx.x; e < N_*ED_; e += 256) es[e] = emb[e];
  __syncthreads();
  int KC = RS/8;
  int e = blockIdx.x*256 + threadIdx.x;
  if (e >= KC*O) return;
  int o = e % O, kc = e / O;
  int KIO = KI*O;
  float M = __uint_as_float(sb[o]);
  float inv = (M > 0.f) ? 32767.f/M : 0.f;
  float wv[8][ED_];
  #pragma unroll
  for (int km=0; km<8; ++km){
    int ki = kc*8 + km;
    #pragma unroll
    for (int d=0; d<ED_; ++d)
      wv[km][d] = (ki < KI) ? wp[(size_t)d*KIO + (size_t)ki*O + o] : 0.f;
  }
  int n0 = blockIdx.y*32;
  for (int n=n0; n<n0+32; ++n){
    short8 q;
    #pragma unroll
    for (int km=0; km<8; ++km){
      float a = 0.f;
      #pragma unroll
      for (int d=0; d<ED_; ++d) a += es[n*ED_+d]*wv[km][d];
      q[km] = (short)__float2int_rn(a*inv);
    }
    *(short8*)&W[(((size_t)n*KC + kc)*O + o)*8] = q;
  }
}

__global__ __launch_bounds__(256) void k_bias(const float* __restrict__ bp, const float* __restrict__ emb,
                       float* __restrict__ Bo, int O){
  int idx = blockIdx.x*256 + threadIdx.x;
  int o = idx % O, n = idx / O;
  float a = 0.f;
  #pragma unroll
  for (int d=0; d<ED_; ++d) a += emb[n*ED_+d]*bp[d*O+o];
  Bo[idx] = a;
}

__global__ void k_fill0(float* __restrict__ p, size_t n){
  size_t i = (size_t)blockIdx.x*blockDim.x + threadIdx.x;
  size_t stride = (size_t)gridDim.x*blockDim.x;
  for (; i<n; i+=stride) p[i] = 0.f;
}

// ---------- plane builders (LDS-tiled transpose; optional fused src column) ----------
__global__ __launch_bounds__(256) void k_btr(const float* __restrict__ S0, const float* __restrict__ S1,
        ushort_t* __restrict__ XH, ushort_t* __restrict__ XL, int CIN, int coff0, int coff1,
        const float* __restrict__ src, int t, int doSrc){
  __shared__ float Tt[64][65];
  const float* S = blockIdx.z ? S1 : S0;
  int coff = blockIdx.z ? coff1 : coff0;
  int mt = blockIdx.x, b = blockIdx.y;
  int r = threadIdx.x >> 6;
  int j = threadIdx.x & 63;
  #pragma unroll
  for (int rr=0; rr<16; ++rr){
    int m = mt*64 + rr*4 + r;
    Tt[rr*4+r][j] = S[((size_t)m*B_ + b)*H_ + j];
  }
  if (doSrc && blockIdx.z==0 && threadIdx.x < 64){
    int m = mt*64 + threadIdx.x;
    float x = src[((size_t)(b*T_+t))*N_ + m];
    size_t o = ((size_t)(b*CIN))*N_ + m;
    ushort_t xh = f2b(x);
    XH[o] = xh; XL[o] = f2b(x - b2f(xh));
  }
  __syncthreads();
  int mr = threadIdx.x & 63;
  int jq = threadIdx.x >> 6;
  #pragma unroll
  for (int jj=0; jj<16; ++jj){
    int jcol = jj*4 + jq;
    float x = Tt[mr][jcol];
    size_t idx = ((size_t)(b*CIN + coff + jcol))*N_ + mt*64 + mr;
    ushort_t xh = f2b(x);
    XH[idx] = xh;
    XL[idx] = f2b(x - b2f(xh));
  }
}

// ---------- int16 contraction core: acc[4][NBJ] += A(f32,LDS) x W(int16, packed) ----------
// Sum order per (o,b): ki ascending (kc asc; kh 0..1; u 0..3) — identical to R7/R8.
template<int KC, int NBJ, int OSTR, int AS>
__device__ __forceinline__ void contract_i16(const short* __restrict__ Wb,
                                             const float* __restrict__ A0,
                                             float acc[4][NBJ]){
  short8 w0,w1,w2,w3, p0,p1,p2,p3, q0,q1,q2,q3;
  {
    const short8* wp8 = (const short8*)(Wb);
    w0=wp8[0]; w1=wp8[1]; w2=wp8[2]; w3=wp8[3];
    const short8* pp8 = (const short8*)(Wb + OSTR);
    p0=pp8[0]; p1=pp8[1]; p2=pp8[2]; p3=pp8[3];
    q0=p0; q1=p1; q2=p2; q3=p3;
  }
  for (int kc=0; kc<KC; ++kc){
    if (kc+2 < KC){
      const short8* np8 = (const short8*)(Wb + (size_t)(kc+2)*OSTR);
      q0=np8[0]; q1=np8[1]; q2=np8[2]; q3=np8[3];
    }
    #pragma unroll
    for (int kh=0; kh<2; ++kh){
      f32x4 av[NBJ];
      #pragma unroll
      for (int bj=0; bj<NBJ; ++bj) av[bj] = *(const f32x4*)&A0[bj*AS + kc*8 + kh*4];
      #pragma unroll
      for (int u=0; u<4; ++u){
        float f0=(float)w0[kh*4+u], f1=(float)w1[kh*4+u];
        float f2v=(float)w2[kh*4+u], f3=(float)w3[kh*4+u];
        #pragma unroll
        for (int bj=0; bj<NBJ; ++bj){
          acc[0][bj] += av[bj][u]*f0;
          acc[1][bj] += av[bj][u]*f1;
          acc[2][bj] += av[bj][u]*f2v;
          acc[3][bj] += av[bj][u]*f3;
        }
      }
    }
    w0=p0; w1=p1; w2=p2; w3=p3;
    p0=q0; p1=q1; p2=q2; p3=q3;
  }
}

// ---------- per-node gate (O=128): 32ow x 8bq, 4o x 4b per thread, prefetch-2 ----------
template<int CIN>
__global__ __launch_bounds__(256) void k_gate(
    const float* __restrict__ src, int t,
    const float* __restrict__ hx, const float* __restrict__ hy,
    const float* __restrict__ P, const float* __restrict__ Rm, const float* __restrict__ Qm,
    const float* __restrict__ dvec, const float* __restrict__ lam,
    const short* __restrict__ W, const float* __restrict__ Wsc, const float* __restrict__ Bb,
    const float* __restrict__ hstate,
    float* __restrict__ cand, float* __restrict__ rbuf)
{
  constexpr int O  = 128;
  constexpr int RS = (3*CIN + 7) & ~7;
  constexpr int KC = RS/8;
  constexpr int AS = RS + 4;
  __shared__ float A[B_*AS];
  int n = blockIdx.x;
  float lm = lam[0];
  float al = -2.f/lm;
  float dn = 2.f*dvec[n]/lm - 1.f;
  float c_r = 2.f*al*al, c_q = 2.f*al, c_p = 2.f*al*dn, c_x = 2.f*dn*dn - 1.f;
  for (int e = threadIdx.x; e < B_*CIN; e += 256){
    int b = e/CIN, c = e%CIN;
    float x;
    if (CIN==65) x = (c==0) ? src[((size_t)(b*T_+t))*N_ + n] : hx[(size_t)n*(B_*H_) + b*H_ + (c-1)];
    else         x = (c<H_) ? hx[(size_t)n*(B_*H_) + b*H_ + c] : hy[(size_t)n*(B_*H_) + b*H_ + (c-H_)];
    size_t pi = (size_t)n*OUTS_ + e;
    float pe = P[pi], re = Rm[pi], qe = Qm[pi];
    float* Ab = A + b*AS;
    Ab[c]         = x;
    Ab[CIN+c]     = al*pe + dn*x;
    Ab[2*CIN+c]   = c_r*re + c_q*qe + c_p*pe + c_x*x;
  }
  for (int e = threadIdx.x; e < B_*(AS-3*CIN); e += 256){
    int b = e/(AS-3*CIN), c = e%(AS-3*CIN);
    A[b*AS + 3*CIN + c] = 0.f;
  }
  __syncthreads();
  int ow = threadIdx.x & 31;   // o0 = ow*4
  int bq = threadIdx.x >> 5;   // b = bq*4 + bj
  int o0 = ow*4;
  float acc[4][4] = {};
  const short* Wb = W + ((size_t)n*KC*O + o0)*8;
  const float* A0 = A + (bq*4)*AS;
  contract_i16<KC,4,O*8,AS>(Wb, A0, acc);
  #pragma unroll
  for (int oj=0; oj<4; ++oj){
    int o = o0 + oj;
    float sc = Wsc[o]*(1.f/32767.f);
    float bias = Bb[n*O+o];
    if (o < H_){
      #pragma unroll
      for (int bj=0; bj<4; ++bj){
        int b = bq*4 + bj;
        float z = sigmoidf_(acc[oj][bj]*sc + bias);
        size_t hi = (size_t)n*(B_*H_) + b*H_ + o;
        cand[hi] = z*hstate[hi];
      }
    } else {
      int oo = o - H_;
      #pragma unroll
      for (int bj=0; bj<4; ++bj){
        int b = bq*4 + bj;
        rbuf[(size_t)n*(B_*H_) + b*H_ + oo] = sigmoidf_(acc[oj][bj]*sc + bias);
      }
    }
  }
}

// ---------- per-node update (O=64): 16ow x 16bq, 4o x 2b, prefetch-2 ----------
template<int CIN>
__global__ __launch_bounds__(256) void k_update(
    const float* __restrict__ src, int t,
    const float* __restrict__ hx, const float* __restrict__ cand,
    const float* __restrict__ P, const float* __restrict__ Rm, const float* __restrict__ Qm,
    const float* __restrict__ dvec, const float* __restrict__ lam,
    const short* __restrict__ W, const float* __restrict__ Wsc, const float* __restrict__ Bb,
    const float* __restrict__ rbuf, float* __restrict__ h)
{
  constexpr int O  = 64;
  constexpr int RS = (3*CIN + 7) & ~7;
  constexpr int KC = RS/8;
  constexpr int AS = RS + 4;
  __shared__ float A[B_*AS];
  int n = blockIdx.x;
  float lm = lam[0];
  float al = -2.f/lm;
  float dn = 2.f*dvec[n]/lm - 1.f;
  float c_r = 2.f*al*al, c_q = 2.f*al, c_p = 2.f*al*dn, c_x = 2.f*dn*dn - 1.f;
  for (int e = threadIdx.x; e < B_*CIN; e += 256){
    int b = e/CIN, c = e%CIN;
    float x;
    if (CIN==65) x = (c==0) ? src[((size_t)(b*T_+t))*N_ + n] : cand[(size_t)n*(B_*H_) + b*H_ + (c-1)];
    else         x = (c<H_) ? hx[(size_t)n*(B_*H_) + b*H_ + c] : cand[(size_t)n*(B_*H_) + b*H_ + (c-H_)];
    size_t pi = (size_t)n*OUTS_ + e;
    float pe = P[pi], re = Rm[pi], qe = Qm[pi];
    float* Ab = A + b*AS;
    Ab[c]         = x;
    Ab[CIN+c]     = al*pe + dn*x;
    Ab[2*CIN+c]   = c_r*re + c_q*qe + c_p*pe + c_x*x;
  }
  for (int e = threadIdx.x; e < B_*(AS-3*CIN); e += 256){
    int b = e/(AS-3*CIN), c = e%(AS-3*CIN);
    A[b*AS + 3*CIN + c] = 0.f;
  }
  __syncthreads();
  int ow = threadIdx.x & 15;
  int bq = threadIdx.x >> 4;
  int o0 = ow*4;
  float acc[4][2] = {};
  const short* Wb = W + ((size_t)n*KC*O + o0)*8;
  const float* A0 = A + (bq*2)*AS;
  contract_i16<KC,2,O*8,AS>(Wb, A0, acc);
  #pragma unroll
  for (int oj=0; oj<4; ++oj){
    int o = o0 + oj;
    float sc = Wsc[o]*(1.f/32767.f);
    float bias = Bb[n*O+o];
    #pragma unroll
    for (int bj=0; bj<2; ++bj){
      int b = bq*2 + bj;
      float hc = tanhf(acc[oj][bj]*sc + bias);
      size_t hidx = (size_t)n*(B_*H_) + b*H_ + o;
      float r = rbuf[hidx];
      h[hidx] = r*h[hidx] + (1.f-r)*hc;
    }
  }
}

// ---------- readout ----------
__global__ __launch_bounds__(256) void k_readout(const float* __restrict__ hB, const float* __restrict__ cw,
                          const float* __restrict__ cb, float* __restrict__ out){
  int idx = blockIdx.x*256 + threadIdx.x;
  int n = idx & (N_-1);
  int bo = idx >> 9;
  int o = bo % HOR_, b = bo / HOR_;
  float a = cb[o];
  #pragma unroll
  for (int j=0;j<H_;++j) a += hB[(size_t)n*(B_*H_) + b*H_ + j]*cw[o*H_+j];
  out[idx] = a;
}

extern "C" void kernel_launch(void* const* d_in, const int* in_sizes, int n_in,
                              void* d_out, int out_size, void* d_ws, size_t ws_size,
                              hipStream_t stream){
  (void)in_sizes; (void)n_in; (void)out_size; (void)ws_size;
  const float* src  = (const float*)d_in[0];
  const float* gn   = (const float*)d_in[2];
  const float* emb  = (const float*)d_in[3];
  const float* gw0  = (const float*)d_in[4];
  const float* gb0  = (const float*)d_in[5];
  const float* uw0  = (const float*)d_in[6];
  const float* ub0  = (const float*)d_in[7];
  const float* gw1  = (const float*)d_in[8];
  const float* gb1  = (const float*)d_in[9];
  const float* uw1  = (const float*)d_in[10];
  const float* ub1  = (const float*)d_in[11];
  const float* cw   = (const float*)d_in[12];
  const float* cb   = (const float*)d_in[13];
  float* out = (float*)d_out;

  const int RS0 = 200;  // (3*65+7)&~7
  const int RS1 = 384;  // 3*128

  char* ws = (char*)d_ws;
  size_t off = 0;
  auto alloc = [&](size_t bytes)->char*{
    char* p = ws + off; off = (off + bytes + 255) & ~(size_t)255; return p;
  };
  short* Wg0 = (short*)alloc((size_t)N_*128*RS0*2);
  short* Wu0 = (short*)alloc((size_t)N_*64*RS0*2);
  short* Wg1 = (short*)alloc((size_t)N_*128*RS1*2);
  short* Wu1 = (short*)alloc((size_t)N_*64*RS1*2);
  unsigned int* Sg0 = (unsigned int*)alloc(128*4);
  unsigned int* Su0 = (unsigned int*)alloc(64*4);
  unsigned int* Sg1 = (unsigned int*)alloc(128*4);
  unsigned int* Su1 = (unsigned int*)alloc(64*4);
  float* Bg0 = (float*)alloc((size_t)N_*128*4);
  float* Bu0 = (float*)alloc((size_t)N_*64*4);
  float* Bg1 = (float*)alloc((size_t)N_*128*4);
  float* Bu1 = (float*)alloc((size_t)N_*64*4);
  ushort_t* Abf  = (ushort_t*)alloc((size_t)N_*N_*2);
  ushort_t* A2bf = (ushort_t*)alloc((size_t)N_*N_*2);
  ushort_t* ADh  = (ushort_t*)alloc((size_t)N_*N_*2);
  float* dvec = (float*)alloc(N_*4);
  float* lam  = (float*)alloc(256);
  float* nrm  = (float*)alloc(N_*4);
  float* hA   = (float*)alloc((size_t)N_*B_*H_*4);
  float* hB   = (float*)alloc((size_t)N_*B_*H_*4);
  float* rbuf = (float*)alloc((size_t)N_*B_*H_*4);
  float* cand = (float*)alloc((size_t)N_*B_*H_*4);
  ushort_t* XH = (ushort_t*)alloc((size_t)4096*N_*2);
  ushort_t* XL = (ushort_t*)alloc((size_t)4096*N_*2);
  float* P  = (float*)alloc((size_t)N_*OUTS_*4);
  float* R  = (float*)alloc((size_t)N_*OUTS_*4);
  float* Q  = (float*)alloc((size_t)N_*OUTS_*4);

  const float* fSg0 = (const float*)Sg0;
  const float* fSu0 = (const float*)Su0;
  const float* fSg1 = (const float*)Sg1;
  const float* fSu1 = (const float*)Su1;

  // graph structure
  k_norm<<<1,512,0,stream>>>(emb, nrm);
  k_adj<<<N_,256,0,stream>>>(emb, nrm, gn, Abf, dvec);
  k_lam<<<1,512,0,stream>>>(dvec, lam);
  k_a2<<<N_,256,0,stream>>>(Abf, A2bf);
  k_admats<<<(N_*N_)/256,256,0,stream>>>(Abf, dvec, lam, ADh);

  // weights (int16 per-o-column scale, packed [n][kc][o][8]) + biases (f32)
  k_fill0<<<1,256,0,stream>>>((float*)Sg0, 384);
  k_wmax<<<dim3((195*128+255)/256,8),256,0,stream>>>(gw0, emb, Sg0, 195*128, 128);
  k_wmax<<<dim3((195*64+255)/256,8),256,0,stream>>>(uw0, emb, Su0, 195*64, 64);
  k_wmax<<<dim3((384*128)/256,8),256,0,stream>>>(gw1, emb, Sg1, 384*128, 128);
  k_wmax<<<dim3((384*64)/256,8),256,0,stream>>>(uw1, emb, Su1, 384*64, 64);
  k_wquant<<<dim3((25*128+255)/256,16),256,0,stream>>>(gw0, emb, Sg0, Wg0, 195, 128, RS0);
  k_wquant<<<dim3((25*64+255)/256,16),256,0,stream>>>(uw0, emb, Su0, Wu0, 195, 64, RS0);
  k_wquant<<<dim3((48*128)/256,16),256,0,stream>>>(gw1, emb, Sg1, Wg1, 384, 128, RS1);
  k_wquant<<<dim3((48*64)/256,16),256,0,stream>>>(uw1, emb, Su1, Wu1, 384, 64, RS1);
  k_bias<<<(N_*128)/256,256,0,stream>>>(gb0, emb, Bg0, 128);
  k_bias<<<(N_*64)/256,256,0,stream>>>(ub0, emb, Bu0, 64);
  k_bias<<<(N_*128)/256,256,0,stream>>>(gb1, emb, Bg1, 128);
  k_bias<<<(N_*64)/256,256,0,stream>>>(ub1, emb, Bu1, 64);

  k_fill0<<<2048,256,0,stream>>>(hA, (size_t)N_*B_*H_);
  k_fill0<<<2048,256,0,stream>>>(hB, (size_t)N_*B_*H_);

  for (int t=0; t<T_; ++t){
    // ---- layer 0 (CIN=65) ----
    k_btr<<<dim3(8,32,1),256,0,stream>>>(hA, hA, XH, XL, 65, 1, 1, src, t, 1);
    k_apply<<<dim3(17,4,3),256,0,stream>>>(XH, XL, Abf, A2bf, ADh, P, R, Q);
    k_gate<65><<<N_,256,0,stream>>>(src, t, hA, hA, P, R, Q, dvec, lam,
                                    Wg0, fSg0, Bg0, hA, cand, rbuf);
    k_btr<<<dim3(8,32,1),256,0,stream>>>(cand, cand, XH, XL, 65, 1, 1, nullptr, 0, 0);
    k_apply<<<dim3(17,4,3),256,0,stream>>>(XH, XL, Abf, A2bf, ADh, P, R, Q);
    k_update<65><<<N_,256,0,stream>>>(src, t, hA, cand, P, R, Q, dvec, lam,
                                      Wu0, fSu0, Bu0, rbuf, hA);
    // ---- layer 1 (CIN=128) ----
    k_btr<<<dim3(8,32,2),256,0,stream>>>(hA, hB, XH, XL, 128, 0, 64, nullptr, 0, 0);
    k_apply<<<dim3(32,4,3),256,0,stream>>>(XH, XL, Abf, A2bf, ADh, P, R, Q);
    k_gate<128><<<N_,256,0,stream>>>(nullptr, 0, hA, hB, P, R, Q, dvec, lam,
                                     Wg1, fSg1, Bg1, hB, cand, rbuf);
    k_btr<<<dim3(8,32,1),256,0,stream>>>(cand, cand, XH, XL, 128, 64, 64, nullptr, 0, 0);
    k_apply<<<dim3(32,4,3),256,0,stream>>>(XH, XL, Abf, A2bf, ADh, P, R, Q);
    k_update<128><<<N_,256,0,stream>>>(nullptr, 0, hA, cand, P, R, Q, dvec, lam,
                                       Wu1, fSu1, Bu1, rbuf, hB);
  }

  k_readout<<<(B_*HOR_*N_)/256,256,0,stream>>>(hB, cw, cb, out);
}

// Round 10
// 2929.212 us; speedup vs baseline: 1.7783x; 1.0058x over previous
//
#include <hip/hip_runtime.h>
#include <math.h>

#define N_    512
#define B_    32
#define T_    12
#define H_    64
#define ED_   10
#define HOR_  12
#define OUTS_ 4096

typedef unsigned short ushort_t;
typedef __attribute__((ext_vector_type(4))) float f32x4;
typedef __attribute__((ext_vector_type(8))) __bf16 bf16x8;
typedef __attribute__((ext_vector_type(8))) short short8;

__device__ __forceinline__ float sigmoidf_(float x){ return 1.f/(1.f+expf(-x)); }
__device__ __forceinline__ float b2f(ushort_t u){ return __uint_as_float(((unsigned)u)<<16); }
__device__ __forceinline__ ushort_t f2b(float f){
  unsigned x = __float_as_uint(f);
  unsigned r = x + 0x7FFFu + ((x>>16)&1u);
  return (ushort_t)(r>>16);
}
__device__ __forceinline__ void stage16(const void* g, void* l){
  __builtin_amdgcn_global_load_lds(
    (const __attribute__((address_space(1))) unsigned int*)g,
    (__attribute__((address_space(3))) unsigned int*)l, 16, 0, 0);
}

// ---------- graph structure ----------
__global__ __launch_bounds__(512) void k_norm(const float* __restrict__ emb, float* __restrict__ nrm){
  int n = threadIdx.x;
  if (n < N_){
    float s = 0.f;
    #pragma unroll
    for (int d=0; d<ED_; ++d){ float v = emb[n*ED_+d]; s += v*v; }
    nrm[n] = sqrtf(s);
  }
}

__global__ __launch_bounds__(256) void k_adj(const float* __restrict__ emb, const float* __restrict__ nrm,
                      const float* __restrict__ gn, ushort_t* __restrict__ Abf, float* __restrict__ dvec){
  __shared__ float ei[ED_];
  __shared__ float red[256];
  int i = blockIdx.x;
  if (threadIdx.x < ED_) ei[threadIdx.x] = emb[i*ED_+threadIdx.x];
  __syncthreads();
  float ni = nrm[i];
  float part = 0.f;
  for (int j = threadIdx.x; j < N_; j += 256){
    float dot = 0.f;
    #pragma unroll
    for (int d=0; d<ED_; ++d) dot += ei[d]*emb[j*ED_+d];
    float lg = (dot/(ni*nrm[j]) + 1.f)*0.5f;
    size_t gi = ((size_t)i*N_ + j)*2;
    float y0 = lg + gn[gi];
    float y1 = (1.f - lg) + gn[gi+1];
    bool a = (j != i && y0 >= y1);
    Abf[(size_t)i*N_ + j] = a ? (ushort_t)0x3F80 : (ushort_t)0;
    part += a ? 1.f : 0.f;
  }
  red[threadIdx.x] = part;
  __syncthreads();
  for (int s=128; s>0; s>>=1){
    if (threadIdx.x < s) red[threadIdx.x] += red[threadIdx.x+s];
    __syncthreads();
  }
  if (threadIdx.x==0) dvec[i] = red[0];
}

__global__ __launch_bounds__(512) void k_lam(const float* __restrict__ dvec, float* __restrict__ lam){
  __shared__ float red[512];
  red[threadIdx.x] = dvec[threadIdx.x];
  __syncthreads();
  for (int s=256; s>0; s>>=1){
    if (threadIdx.x < s) red[threadIdx.x] = fmaxf(red[threadIdx.x], red[threadIdx.x+s]);
    __syncthreads();
  }
  if (threadIdx.x==0){
    float maxd = red[0];
    lam[0] = maxd + (maxd > 0.f ? 1.f : 0.f);
  }
}

__global__ __launch_bounds__(256) void k_a2(const ushort_t* __restrict__ Abf, ushort_t* __restrict__ A2bf){
  __shared__ float ar[N_];
  int n = blockIdx.x;
  for (int p = threadIdx.x; p < N_; p += 256) ar[p] = b2f(Abf[(size_t)n*N_ + p]);
  __syncthreads();
  int m0 = threadIdx.x, m1 = threadIdx.x + 256;
  float a0 = 0.f, a1 = 0.f;
  for (int p=0; p<N_; ++p){
    float ap = ar[p];
    a0 += ap * b2f(Abf[(size_t)p*N_ + m0]);
    a1 += ap * b2f(Abf[(size_t)p*N_ + m1]);
  }
  A2bf[(size_t)n*N_ + m0] = f2b(a0);
  A2bf[(size_t)n*N_ + m1] = f2b(a1);
}

__global__ __launch_bounds__(256) void k_admats(const ushort_t* __restrict__ Abf, const float* __restrict__ dvec,
                        const float* __restrict__ lam, ushort_t* __restrict__ ADh){
  int idx = blockIdx.x*256 + threadIdx.x;
  int m = idx & (N_-1);
  float dm = 2.f*dvec[m]/lam[0] - 1.f;
  ADh[idx] = Abf[idx] ? f2b(dm) : (ushort_t)0;
}

// ---------- MFMA apply: 128 cols x 64 n-rows per block, 40KB LDS, 4 blocks/CU ----------
#define XTILE_USH 8192   // 128 rows x 64k bf16 = 16KB
__global__ __launch_bounds__(256) void k_apply(
    const ushort_t* __restrict__ XH, const ushort_t* __restrict__ XL,
    const ushort_t* __restrict__ Abf, const ushort_t* __restrict__ A2bf, const ushort_t* __restrict__ ADh,
    float* __restrict__ P, float* __restrict__ Rm, float* __restrict__ Qm)
{
  __shared__ ushort_t lds[2*XTILE_USH + 4096];   // XH(16K) + XL(16K) + M(8K)
  const int z = blockIdx.z;
  const ushort_t* M = (z==0)? Abf : (z==1)? A2bf : ADh;
  float* OUT = (z==0)? P : (z==1)? Rm : Qm;
  const int cBase = blockIdx.x<<7, nBase = blockIdx.y<<6;
  const int tid = threadIdx.x, lane = tid&63, w = tid>>6;
  const int lrow = lane>>3, lslot = lane&7;
  const int srck = lslot ^ (lrow&7);
  const char* g0 = (const char*)XH;
  const char* g1 = (const char*)XL;
  const char* g2 = (const char*)M;
  f32x4 acc[2][4];
  #pragma unroll
  for (int i=0;i<2;++i)
    #pragma unroll
    for (int j=0;j<4;++j) acc[i][j] = f32x4{0.f,0.f,0.f,0.f};
  const int fl = lane&15, kq = lane>>4;

  for (int kk=0; kk<512; kk+=64){
    // 40 stage16 units over 4 waves: tiles 0,1 = X (16 units each), tile 2 = M (8 units)
    #pragma unroll
    for (int s=0; s<10; ++s){
      int instId = w + s*4;
      int tile = instId>>4, inst = instId&15;
      const char* g = (tile==0? g0 : (tile==1? g1 : g2));
      int rb = (tile<2? cBase : nBase) + inst*8 + lrow;
      stage16(g + (size_t)rb*(N_*2) + kk*2 + srck*16,
              (char*)lds + tile*16384 + inst*1024);
    }
    __syncthreads();
    #pragma unroll
    for (int kh=0; kh<2; ++kh){
      bf16x8 ah[2], alo[2], bm[4];
      #pragma unroll
      for (int fi=0; fi<2; ++fi){
        int row = (w<<5) + (fi<<4) + fl;
        int off = (row<<6) + (((kq + (kh<<2)) ^ (row&7))<<3);
        ah[fi]  = *(const bf16x8*)&lds[off];
        alo[fi] = *(const bf16x8*)&lds[XTILE_USH + off];
      }
      #pragma unroll
      for (int fj=0; fj<4; ++fj){
        int row = (fj<<4) + fl;
        int off = (row<<6) + (((kq + (kh<<2)) ^ (row&7))<<3);
        bm[fj] = *(const bf16x8*)&lds[2*XTILE_USH + off];
      }
      #pragma unroll
      for (int fi=0; fi<2; ++fi)
        #pragma unroll
        for (int fj=0; fj<4; ++fj){
          acc[fi][fj] = __builtin_amdgcn_mfma_f32_16x16x32_bf16(ah[fi],  bm[fj], acc[fi][fj], 0,0,0);
          acc[fi][fj] = __builtin_amdgcn_mfma_f32_16x16x32_bf16(alo[fi], bm[fj], acc[fi][fj], 0,0,0);
        }
    }
    __syncthreads();
  }
  #pragma unroll
  for (int fi=0; fi<2; ++fi){
    int cg = cBase + (w<<5) + (fi<<4) + (kq<<2);
    #pragma unroll
    for (int fj=0; fj<4; ++fj){
      int ng = nBase + (fj<<4) + fl;
      float4 v = make_float4(acc[fi][fj][0], acc[fi][fj][1], acc[fi][fj][2], acc[fi][fj][3]);
      *(float4*)&OUT[(size_t)ng*OUTS_ + cg] = v;
    }
  }
}

// ---------- weight prep: per-o max with LDS tree-reduce (1 atomic per (block,o)) ----------
__global__ __launch_bounds__(256) void k_wmax(const float* __restrict__ wp, const float* __restrict__ emb,
                       unsigned int* __restrict__ sb, int KI, int O, int KB){
  __shared__ float es[N_*ED_];
  __shared__ float sm[256];
  for (int e = threadIdx.x; e < N_*ED_; e += 256) es[e] = emb[e];
  __syncthreads();
  int G = 256/O;
  int o = threadIdx.x % O;
  int g = threadIdx.x / O;
  int KIend = min(KI, (int)(blockIdx.x+1)*KB);
  int n0 = blockIdx.y*128;
  size_t KIO = (size_t)KI*O;
  float m = 0.f;
  for (int ki = blockIdx.x*KB + g; ki < KIend; ki += G){
    float wv[ED_];
    #pragma unroll
    for (int d=0; d<ED_; ++d) wv[d] = wp[(size_t)d*KIO + (size_t)ki*O + o];
    for (int n=n0; n<n0+128; ++n){
      float a = 0.f;
      #pragma unroll
      for (int d=0; d<ED_; ++d) a += es[n*ED_+d]*wv[d];
      m = fmaxf(m, fabsf(a));
    }
  }
  sm[threadIdx.x] = m;
  __syncthreads();
  for (int s=128; s>=O; s>>=1){
    if (threadIdx.x < s) sm[threadIdx.x] = fmaxf(sm[threadIdx.x], sm[threadIdx.x+s]);
    __syncthreads();
  }
  if (threadIdx.x < O) atomicMax(&sb[o], __float_as_uint(sm[threadIdx.x]));
}

__global__ __launch_bounds__(256) void k_wquant(const float* __restrict__ wp, const float* __restrict__ emb,
                         const unsigned int* __restrict__ sb, short* __restrict__ W,
                         int KI, int O, int RS){
  __shared__ float es[N_*ED_];
  for (int e = threadIdx.x; e < N_*ED_; e += 256) es[e] = emb[e];
  __syncthreads();
  int KC = RS/8;
  int e = blockIdx.x*256 + threadIdx.x;
  if (e >= KC*O) return;
  int o = e % O, kc = e / O;
  int KIO = KI*O;
  float M = __uint_as_float(sb[o]);
  float inv = (M > 0.f) ? 32767.f/M : 0.f;
  float wv[8][ED_];
  #pragma unroll
  for (int km=0; km<8; ++km){
    int ki = kc*8 + km;
    #pragma unroll
    for (int d=0; d<ED_; ++d)
      wv[km][d] = (ki < KI) ? wp[(size_t)d*KIO + (size_t)ki*O + o] : 0.f;
  }
  int n0 = blockIdx.y*32;
  for (int n=n0; n<n0+32; ++n){
    short8 q;
    #pragma unroll
    for (int km=0; km<8; ++km){
      float a = 0.f;
      #pragma unroll
      for (int d=0; d<ED_; ++d) a += es[n*ED_+d]*wv[km][d];
      q[km] = (short)__float2int_rn(a*inv);
    }
    *(short8*)&W[(((size_t)n*KC + kc)*O + o)*8] = q;
  }
}

__global__ __launch_bounds__(256) void k_bias(const float* __restrict__ bp, const float* __restrict__ emb,
                       float* __restrict__ Bo, int O){
  int idx = blockIdx.x*256 + threadIdx.x;
  int o = idx % O, n = idx / O;
  float a = 0.f;
  #pragma unroll
  for (int d=0; d<ED_; ++d) a += emb[n*ED_+d]*bp[d*O+o];
  Bo[idx] = a;
}

__global__ void k_fill0(float* __restrict__ p, size_t n){
  size_t i = (size_t)blockIdx.x*blockDim.x + threadIdx.x;
  size_t stride = (size_t)gridDim.x*blockDim.x;
  for (; i<n; i+=stride) p[i] = 0.f;
}

// ---------- plane builders ----------
__global__ __launch_bounds__(256) void k_btr(const float* __restrict__ S0, const float* __restrict__ S1,
        ushort_t* __restrict__ XH, ushort_t* __restrict__ XL, int CIN, int coff0, int coff1,
        const float* __restrict__ src, int t, int doSrc){
  __shared__ float Tt[64][65];
  const float* S = blockIdx.z ? S1 : S0;
  int coff = blockIdx.z ? coff1 : coff0;
  int mt = blockIdx.x, b = blockIdx.y;
  int r = threadIdx.x >> 6;
  int j = threadIdx.x & 63;
  #pragma unroll
  for (int rr=0; rr<16; ++rr){
    int m = mt*64 + rr*4 + r;
    Tt[rr*4+r][j] = S[((size_t)m*B_ + b)*H_ + j];
  }
  if (doSrc && blockIdx.z==0 && threadIdx.x < 64){
    int m = mt*64 + threadIdx.x;
    float x = src[((size_t)(b*T_+t))*N_ + m];
    size_t o = ((size_t)(b*CIN))*N_ + m;
    ushort_t xh = f2b(x);
    XH[o] = xh; XL[o] = f2b(x - b2f(xh));
  }
  __syncthreads();
  int mr = threadIdx.x & 63;
  int jq = threadIdx.x >> 6;
  #pragma unroll
  for (int jj=0; jj<16; ++jj){
    int jcol = jj*4 + jq;
    float x = Tt[mr][jcol];
    size_t idx = ((size_t)(b*CIN + coff + jcol))*N_ + mt*64 + mr;
    ushort_t xh = f2b(x);
    XH[idx] = xh;
    XL[idx] = f2b(x - b2f(xh));
  }
}

// ---------- int16 contraction core (prefetch-2), sum order ki ascending ----------
template<int KC, int NBJ, int OSTR, int AS>
__device__ __forceinline__ void contract_i16(const short* __restrict__ Wb,
                                             const float* __restrict__ A0,
                                             float acc[4][NBJ]){
  short8 w0,w1,w2,w3, p0,p1,p2,p3, q0,q1,q2,q3;
  {
    const short8* wp8 = (const short8*)(Wb);
    w0=wp8[0]; w1=wp8[1]; w2=wp8[2]; w3=wp8[3];
    const short8* pp8 = (const short8*)(Wb + OSTR);
    p0=pp8[0]; p1=pp8[1]; p2=pp8[2]; p3=pp8[3];
    q0=p0; q1=p1; q2=p2; q3=p3;
  }
  for (int kc=0; kc<KC; ++kc){
    if (kc+2 < KC){
      const short8* np8 = (const short8*)(Wb + (size_t)(kc+2)*OSTR);
      q0=np8[0]; q1=np8[1]; q2=np8[2]; q3=np8[3];
    }
    #pragma unroll
    for (int kh=0; kh<2; ++kh){
      f32x4 av[NBJ];
      #pragma unroll
      for (int bj=0; bj<NBJ; ++bj) av[bj] = *(const f32x4*)&A0[bj*AS + kc*8 + kh*4];
      #pragma unroll
      for (int u=0; u<4; ++u){
        float f0=(float)w0[kh*4+u], f1=(float)w1[kh*4+u];
        float f2v=(float)w2[kh*4+u], f3=(float)w3[kh*4+u];
        #pragma unroll
        for (int bj=0; bj<NBJ; ++bj){
          acc[0][bj] += av[bj][u]*f0;
          acc[1][bj] += av[bj][u]*f1;
          acc[2][bj] += av[bj][u]*f2v;
          acc[3][bj] += av[bj][u]*f3;
        }
      }
    }
    w0=p0; w1=p1; w2=p2; w3=p3;
    p0=q0; p1=q1; p2=q2; p3=q3;
  }
}

// ---------- per-node gate (O=128): 32ow x 8bq, 4o x 4b per thread ----------
template<int CIN>
__global__ __launch_bounds__(256) void k_gate(
    const float* __restrict__ src, int t,
    const float* __restrict__ hx, const float* __restrict__ hy,
    const float* __restrict__ P, const float* __restrict__ Rm, const float* __restrict__ Qm,
    const float* __restrict__ dvec, const float* __restrict__ lam,
    const short* __restrict__ W, const float* __restrict__ Wsc, const float* __restrict__ Bb,
    const float* __restrict__ hstate,
    float* __restrict__ cand, float* __restrict__ rbuf)
{
  constexpr int O  = 128;
  constexpr int RS = (3*CIN + 7) & ~7;
  constexpr int KC = RS/8;
  constexpr int AS = RS + 4;
  __shared__ float A[B_*AS];
  int n = blockIdx.x;
  float lm = lam[0];
  float al = -2.f/lm;
  float dn = 2.f*dvec[n]/lm - 1.f;
  float c_r = 2.f*al*al, c_q = 2.f*al, c_p = 2.f*al*dn, c_x = 2.f*dn*dn - 1.f;
  for (int e = threadIdx.x; e < B_*CIN; e += 256){
    int b = e/CIN, c = e%CIN;
    float x;
    if (CIN==65) x = (c==0) ? src[((size_t)(b*T_+t))*N_ + n] : hx[(size_t)n*(B_*H_) + b*H_ + (c-1)];
    else         x = (c<H_) ? hx[(size_t)n*(B_*H_) + b*H_ + c] : hy[(size_t)n*(B_*H_) + b*H_ + (c-H_)];
    size_t pi = (size_t)n*OUTS_ + e;
    float pe = P[pi], re = Rm[pi], qe = Qm[pi];
    float* Ab = A + b*AS;
    Ab[c]         = x;
    Ab[CIN+c]     = al*pe + dn*x;
    Ab[2*CIN+c]   = c_r*re + c_q*qe + c_p*pe + c_x*x;
  }
  for (int e = threadIdx.x; e < B_*(AS-3*CIN); e += 256){
    int b = e/(AS-3*CIN), c = e%(AS-3*CIN);
    A[b*AS + 3*CIN + c] = 0.f;
  }
  __syncthreads();
  int ow = threadIdx.x & 31;
  int bq = threadIdx.x >> 5;
  int o0 = ow*4;
  float acc[4][4] = {};
  const short* Wb = W + ((size_t)n*KC*O + o0)*8;
  const float* A0 = A + (bq*4)*AS;
  contract_i16<KC,4,O*8,AS>(Wb, A0, acc);
  #pragma unroll
  for (int oj=0; oj<4; ++oj){
    int o = o0 + oj;
    float sc = Wsc[o]*(1.f/32767.f);
    float bias = Bb[n*O+o];
    if (o < H_){
      #pragma unroll
      for (int bj=0; bj<4; ++bj){
        int b = bq*4 + bj;
        float z = sigmoidf_(acc[oj][bj]*sc + bias);
        size_t hi = (size_t)n*(B_*H_) + b*H_ + o;
        cand[hi] = z*hstate[hi];
      }
    } else {
      int oo = o - H_;
      #pragma unroll
      for (int bj=0; bj<4; ++bj){
        int b = bq*4 + bj;
        rbuf[(size_t)n*(B_*H_) + b*H_ + oo] = sigmoidf_(acc[oj][bj]*sc + bias);
      }
    }
  }
}

// ---------- per-node update (O=64): 16ow x 16bq, 4o x 2b ----------
template<int CIN>
__global__ __launch_bounds__(256) void k_update(
    const float* __restrict__ src, int t,
    const float* __restrict__ hx, const float* __restrict__ cand,
    const float* __restrict__ P, const float* __restrict__ Rm, const float* __restrict__ Qm,
    const float* __restrict__ dvec, const float* __restrict__ lam,
    const short* __restrict__ W, const float* __restrict__ Wsc, const float* __restrict__ Bb,
    const float* __restrict__ rbuf, float* __restrict__ h)
{
  constexpr int O  = 64;
  constexpr int RS = (3*CIN + 7) & ~7;
  constexpr int KC = RS/8;
  constexpr int AS = RS + 4;
  __shared__ float A[B_*AS];
  int n = blockIdx.x;
  float lm = lam[0];
  float al = -2.f/lm;
  float dn = 2.f*dvec[n]/lm - 1.f;
  float c_r = 2.f*al*al, c_q = 2.f*al, c_p = 2.f*al*dn, c_x = 2.f*dn*dn - 1.f;
  for (int e = threadIdx.x; e < B_*CIN; e += 256){
    int b = e/CIN, c = e%CIN;
    float x;
    if (CIN==65) x = (c==0) ? src[((size_t)(b*T_+t))*N_ + n] : cand[(size_t)n*(B_*H_) + b*H_ + (c-1)];
    else         x = (c<H_) ? hx[(size_t)n*(B_*H_) + b*H_ + c] : cand[(size_t)n*(B_*H_) + b*H_ + (c-H_)];
    size_t pi = (size_t)n*OUTS_ + e;
    float pe = P[pi], re = Rm[pi], qe = Qm[pi];
    float* Ab = A + b*AS;
    Ab[c]         = x;
    Ab[CIN+c]     = al*pe + dn*x;
    Ab[2*CIN+c]   = c_r*re + c_q*qe + c_p*pe + c_x*x;
  }
  for (int e = threadIdx.x; e < B_*(AS-3*CIN); e += 256){
    int b = e/(AS-3*CIN), c = e%(AS-3*CIN);
    A[b*AS + 3*CIN + c] = 0.f;
  }
  __syncthreads();
  int ow = threadIdx.x & 15;
  int bq = threadIdx.x >> 4;
  int o0 = ow*4;
  float acc[4][2] = {};
  const short* Wb = W + ((size_t)n*KC*O + o0)*8;
  const float* A0 = A + (bq*2)*AS;
  contract_i16<KC,2,O*8,AS>(Wb, A0, acc);
  #pragma unroll
  for (int oj=0; oj<4; ++oj){
    int o = o0 + oj;
    float sc = Wsc[o]*(1.f/32767.f);
    float bias = Bb[n*O+o];
    #pragma unroll
    for (int bj=0; bj<2; ++bj){
      int b = bq*2 + bj;
      float hc = tanhf(acc[oj][bj]*sc + bias);
      size_t hidx = (size_t)n*(B_*H_) + b*H_ + o;
      float r = rbuf[hidx];
      h[hidx] = r*h[hidx] + (1.f-r)*hc;
    }
  }
}

// ---------- readout ----------
__global__ __launch_bounds__(256) void k_readout(const float* __restrict__ hB, const float* __restrict__ cw,
                          const float* __restrict__ cb, float* __restrict__ out){
  int idx = blockIdx.x*256 + threadIdx.x;
  int n = idx & (N_-1);
  int bo = idx >> 9;
  int o = bo % HOR_, b = bo / HOR_;
  float a = cb[o];
  #pragma unroll
  for (int j=0;j<H_;++j) a += hB[(size_t)n*(B_*H_) + b*H_ + j]*cw[o*H_+j];
  out[idx] = a;
}

extern "C" void kernel_launch(void* const* d_in, const int* in_sizes, int n_in,
                              void* d_out, int out_size, void* d_ws, size_t ws_size,
                              hipStream_t stream){
  (void)in_sizes; (void)n_in; (void)out_size; (void)ws_size;
  const float* src  = (const float*)d_in[0];
  const float* gn   = (const float*)d_in[2];
  const float* emb  = (const float*)d_in[3];
  const float* gw0  = (const float*)d_in[4];
  const float* gb0  = (const float*)d_in[5];
  const float* uw0  = (const float*)d_in[6];
  const float* ub0  = (const float*)d_in[7];
  const float* gw1  = (const float*)d_in[8];
  const float* gb1  = (const float*)d_in[9];
  const float* uw1  = (const float*)d_in[10];
  const float* ub1  = (const float*)d_in[11];
  const float* cw   = (const float*)d_in[12];
  const float* cb   = (const float*)d_in[13];
  float* out = (float*)d_out;

  const int RS0 = 200;  // (3*65+7)&~7
  const int RS1 = 384;  // 3*128

  char* ws = (char*)d_ws;
  size_t off = 0;
  auto alloc = [&](size_t bytes)->char*{
    char* p = ws + off; off = (off + bytes + 255) & ~(size_t)255; return p;
  };
  short* Wg0 = (short*)alloc((size_t)N_*128*RS0*2);
  short* Wu0 = (short*)alloc((size_t)N_*64*RS0*2);
  short* Wg1 = (short*)alloc((size_t)N_*128*RS1*2);
  short* Wu1 = (short*)alloc((size_t)N_*64*RS1*2);
  unsigned int* Sg0 = (unsigned int*)alloc(128*4);
  unsigned int* Su0 = (unsigned int*)alloc(64*4);
  unsigned int* Sg1 = (unsigned int*)alloc(128*4);
  unsigned int* Su1 = (unsigned int*)alloc(64*4);
  float* Bg0 = (float*)alloc((size_t)N_*128*4);
  float* Bu0 = (float*)alloc((size_t)N_*64*4);
  float* Bg1 = (float*)alloc((size_t)N_*128*4);
  float* Bu1 = (float*)alloc((size_t)N_*64*4);
  ushort_t* Abf  = (ushort_t*)alloc((size_t)N_*N_*2);
  ushort_t* A2bf = (ushort_t*)alloc((size_t)N_*N_*2);
  ushort_t* ADh  = (ushort_t*)alloc((size_t)N_*N_*2);
  float* dvec = (float*)alloc(N_*4);
  float* lam  = (float*)alloc(256);
  float* nrm  = (float*)alloc(N_*4);
  float* hA   = (float*)alloc((size_t)N_*B_*H_*4);
  float* hB   = (float*)alloc((size_t)N_*B_*H_*4);
  float* rbuf = (float*)alloc((size_t)N_*B_*H_*4);
  float* cand = (float*)alloc((size_t)N_*B_*H_*4);
  ushort_t* XH = (ushort_t*)alloc((size_t)4096*N_*2);
  ushort_t* XL = (ushort_t*)alloc((size_t)4096*N_*2);
  float* P  = (float*)alloc((size_t)N_*OUTS_*4);
  float* R  = (float*)alloc((size_t)N_*OUTS_*4);
  float* Q  = (float*)alloc((size_t)N_*OUTS_*4);

  const float* fSg0 = (const float*)Sg0;
  const float* fSu0 = (const float*)Su0;
  const float* fSg1 = (const float*)Sg1;
  const float* fSu1 = (const float*)Su1;

  // graph structure
  k_norm<<<1,512,0,stream>>>(emb, nrm);
  k_adj<<<N_,256,0,stream>>>(emb, nrm, gn, Abf, dvec);
  k_lam<<<1,512,0,stream>>>(dvec, lam);
  k_a2<<<N_,256,0,stream>>>(Abf, A2bf);
  k_admats<<<(N_*N_)/256,256,0,stream>>>(Abf, dvec, lam, ADh);

  // weights (int16 per-o-column scale, packed [n][kc][o][8]) + biases (f32)
  k_fill0<<<1,256,0,stream>>>((float*)Sg0, 384);
  k_wmax<<<dim3(17,4),256,0,stream>>>(gw0, emb, Sg0, 195, 128, 12);
  k_wmax<<<dim3(13,4),256,0,stream>>>(uw0, emb, Su0, 195, 64, 16);
  k_wmax<<<dim3(32,4),256,0,stream>>>(gw1, emb, Sg1, 384, 128, 12);
  k_wmax<<<dim3(24,4),256,0,stream>>>(uw1, emb, Su1, 384, 64, 16);
  k_wquant<<<dim3((25*128+255)/256,16),256,0,stream>>>(gw0, emb, Sg0, Wg0, 195, 128, RS0);
  k_wquant<<<dim3((25*64+255)/256,16),256,0,stream>>>(uw0, emb, Su0, Wu0, 195, 64, RS0);
  k_wquant<<<dim3((48*128)/256,16),256,0,stream>>>(gw1, emb, Sg1, Wg1, 384, 128, RS1);
  k_wquant<<<dim3((48*64)/256,16),256,0,stream>>>(uw1, emb, Su1, Wu1, 384, 64, RS1);
  k_bias<<<(N_*128)/256,256,0,stream>>>(gb0, emb, Bg0, 128);
  k_bias<<<(N_*64)/256,256,0,stream>>>(ub0, emb, Bu0, 64);
  k_bias<<<(N_*128)/256,256,0,stream>>>(gb1, emb, Bg1, 128);
  k_bias<<<(N_*64)/256,256,0,stream>>>(ub1, emb, Bu1, 64);

  k_fill0<<<2048,256,0,stream>>>(hA, (size_t)N_*B_*H_);
  k_fill0<<<2048,256,0,stream>>>(hB, (size_t)N_*B_*H_);

  for (int t=0; t<T_; ++t){
    // ---- layer 0 (CIN=65) ----
    k_btr<<<dim3(8,32,1),256,0,stream>>>(hA, hA, XH, XL, 65, 1, 1, src, t, 1);
    k_apply<<<dim3(17,8,3),256,0,stream>>>(XH, XL, Abf, A2bf, ADh, P, R, Q);
    k_gate<65><<<N_,256,0,stream>>>(src, t, hA, hA, P, R, Q, dvec, lam,
                                    Wg0, fSg0, Bg0, hA, cand, rbuf);
    k_btr<<<dim3(8,32,1),256,0,stream>>>(cand, cand, XH, XL, 65, 1, 1, nullptr, 0, 0);
    k_apply<<<dim3(17,8,3),256,0,stream>>>(XH, XL, Abf, A2bf, ADh, P, R, Q);
    k_update<65><<<N_,256,0,stream>>>(src, t, hA, cand, P, R, Q, dvec, lam,
                                      Wu0, fSu0, Bu0, rbuf, hA);
    // ---- layer 1 (CIN=128) ----
    k_btr<<<dim3(8,32,2),256,0,stream>>>(hA, hB, XH, XL, 128, 0, 64, nullptr, 0, 0);
    k_apply<<<dim3(32,8,3),256,0,stream>>>(XH, XL, Abf, A2bf, ADh, P, R, Q);
    k_gate<128><<<N_,256,0,stream>>>(nullptr, 0, hA, hB, P, R, Q, dvec, lam,
                                     Wg1, fSg1, Bg1, hB, cand, rbuf);
    k_btr<<<dim3(8,32,1),256,0,stream>>>(cand, cand, XH, XL, 128, 64, 64, nullptr, 0, 0);
    k_apply<<<dim3(32,8,3),256,0,stream>>>(XH, XL, Abf, A2bf, ADh, P, R, Q);
    k_update<128><<<N_,256,0,stream>>>(nullptr, 0, hA, cand, P, R, Q, dvec, lam,
                                       Wu1, fSu1, Bu1, rbuf, hB);
  }

  k_readout<<<(B_*HOR_*N_)/256,256,0,stream>>>(hB, cw, cb, out);
}

// Round 11
// 2887.736 us; speedup vs baseline: 1.8039x; 1.0144x over previous
//
#include <hip/hip_runtime.h>
#include <math.h>

#define N_    512
#define B_    32
#define T_    12
#define H_    64
#define ED_   10
#define HOR_  12
#define OUTS_ 4096

typedef unsigned short ushort_t;
typedef __attribute__((ext_vector_type(4))) float f32x4;
typedef __attribute__((ext_vector_type(8))) __bf16 bf16x8;
typedef __attribute__((ext_vector_type(8))) short short8;

__device__ __forceinline__ float sigmoidf_(float x){ return 1.f/(1.f+expf(-x)); }
__device__ __forceinline__ float b2f(ushort_t u){ return __uint_as_float(((unsigned)u)<<16); }
__device__ __forceinline__ ushort_t f2b(float f){
  unsigned x = __float_as_uint(f);
  unsigned r = x + 0x7FFFu + ((x>>16)&1u);
  return (ushort_t)(r>>16);
}
__device__ __forceinline__ void stage16(const void* g, void* l){
  __builtin_amdgcn_global_load_lds(
    (const __attribute__((address_space(1))) unsigned int*)g,
    (__attribute__((address_space(3))) unsigned int*)l, 16, 0, 0);
}

// ---------- graph structure ----------
__global__ __launch_bounds__(512) void k_norm(const float* __restrict__ emb, float* __restrict__ nrm){
  int n = threadIdx.x;
  if (n < N_){
    float s = 0.f;
    #pragma unroll
    for (int d=0; d<ED_; ++d){ float v = emb[n*ED_+d]; s += v*v; }
    nrm[n] = sqrtf(s);
  }
}

__global__ __launch_bounds__(256) void k_adj(const float* __restrict__ emb, const float* __restrict__ nrm,
                      const float* __restrict__ gn, ushort_t* __restrict__ Abf, float* __restrict__ dvec){
  __shared__ float ei[ED_];
  __shared__ float red[256];
  int i = blockIdx.x;
  if (threadIdx.x < ED_) ei[threadIdx.x] = emb[i*ED_+threadIdx.x];
  __syncthreads();
  float ni = nrm[i];
  float part = 0.f;
  for (int j = threadIdx.x; j < N_; j += 256){
    float dot = 0.f;
    #pragma unroll
    for (int d=0; d<ED_; ++d) dot += ei[d]*emb[j*ED_+d];
    float lg = (dot/(ni*nrm[j]) + 1.f)*0.5f;
    size_t gi = ((size_t)i*N_ + j)*2;
    float y0 = lg + gn[gi];
    float y1 = (1.f - lg) + gn[gi+1];
    bool a = (j != i && y0 >= y1);
    Abf[(size_t)i*N_ + j] = a ? (ushort_t)0x3F80 : (ushort_t)0;
    part += a ? 1.f : 0.f;
  }
  red[threadIdx.x] = part;
  __syncthreads();
  for (int s=128; s>0; s>>=1){
    if (threadIdx.x < s) red[threadIdx.x] += red[threadIdx.x+s];
    __syncthreads();
  }
  if (threadIdx.x==0) dvec[i] = red[0];
}

__global__ __launch_bounds__(512) void k_lam(const float* __restrict__ dvec, float* __restrict__ lam){
  __shared__ float red[512];
  red[threadIdx.x] = dvec[threadIdx.x];
  __syncthreads();
  for (int s=256; s>0; s>>=1){
    if (threadIdx.x < s) red[threadIdx.x] = fmaxf(red[threadIdx.x], red[threadIdx.x+s]);
    __syncthreads();
  }
  if (threadIdx.x==0){
    float maxd = red[0];
    lam[0] = maxd + (maxd > 0.f ? 1.f : 0.f);
  }
}

__global__ __launch_bounds__(256) void k_a2(const ushort_t* __restrict__ Abf, ushort_t* __restrict__ A2bf){
  __shared__ float ar[N_];
  int n = blockIdx.x;
  for (int p = threadIdx.x; p < N_; p += 256) ar[p] = b2f(Abf[(size_t)n*N_ + p]);
  __syncthreads();
  int m0 = threadIdx.x, m1 = threadIdx.x + 256;
  float a0 = 0.f, a1 = 0.f;
  for (int p=0; p<N_; ++p){
    float ap = ar[p];
    a0 += ap * b2f(Abf[(size_t)p*N_ + m0]);
    a1 += ap * b2f(Abf[(size_t)p*N_ + m1]);
  }
  A2bf[(size_t)n*N_ + m0] = f2b(a0);
  A2bf[(size_t)n*N_ + m1] = f2b(a1);
}

__global__ __launch_bounds__(256) void k_admats(const ushort_t* __restrict__ Abf, const float* __restrict__ dvec,
                        const float* __restrict__ lam, ushort_t* __restrict__ ADh){
  int idx = blockIdx.x*256 + threadIdx.x;
  int m = idx & (N_-1);
  float dm = 2.f*dvec[m]/lam[0] - 1.f;
  ADh[idx] = Abf[idx] ? f2b(dm) : (ushort_t)0;
}

// ---------- fused MFMA apply: 64 cols x 64 n, ALL 3 matrices per block ----------
// LDS: XH(8K) XL(8K) A(8K) A2(8K) AD(8K) = 40KB. Per-output MFMA order: kk, kh, hi, lo
// (identical fragments/sequence to prior version -> bit-exact).
__global__ __launch_bounds__(256) void k_apply(
    const ushort_t* __restrict__ XH, const ushort_t* __restrict__ XL,
    const ushort_t* __restrict__ Abf, const ushort_t* __restrict__ A2bf, const ushort_t* __restrict__ ADh,
    float* __restrict__ P, float* __restrict__ Rm, float* __restrict__ Qm)
{
  __shared__ ushort_t lds[5*4096];
  const int cBase = blockIdx.x<<6, nBase = blockIdx.y<<6;
  const int tid = threadIdx.x, lane = tid&63, w = tid>>6;
  const int lrow = lane>>3, lslot = lane&7;
  const int srck = lslot ^ (lrow&7);
  f32x4 acc[3][4];
  #pragma unroll
  for (int i=0;i<3;++i)
    #pragma unroll
    for (int j=0;j<4;++j) acc[i][j] = f32x4{0.f,0.f,0.f,0.f};
  const int fl = lane&15, kq = lane>>4;

  for (int kk=0; kk<512; kk+=64){
    #pragma unroll
    for (int s=0; s<10; ++s){
      int instId = w + s*4;        // 0..39
      int tile = instId>>3;        // 0..4
      int inst = instId&7;         // 0..7
      const char* g = (tile==0)? (const char*)XH : (tile==1)? (const char*)XL :
                      (tile==2)? (const char*)Abf : (tile==3)? (const char*)A2bf : (const char*)ADh;
      int rb = (tile<2? cBase : nBase) + inst*8 + lrow;
      stage16(g + (size_t)rb*(N_*2) + kk*2 + srck*16,
              (char*)lds + tile*8192 + inst*1024);
    }
    __syncthreads();
    #pragma unroll
    for (int kh=0; kh<2; ++kh){
      int rowA = (w<<4) + fl;
      int offA = (rowA<<6) + (((kq + (kh<<2)) ^ (rowA&7))<<3);
      bf16x8 ah  = *(const bf16x8*)&lds[offA];
      bf16x8 alo = *(const bf16x8*)&lds[4096 + offA];
      bf16x8 bA[4], b2[4], bD[4];
      #pragma unroll
      for (int fj=0; fj<4; ++fj){
        int rowB = (fj<<4) + fl;
        int offB = (rowB<<6) + (((kq + (kh<<2)) ^ (rowB&7))<<3);
        bA[fj] = *(const bf16x8*)&lds[2*4096 + offB];
        b2[fj] = *(const bf16x8*)&lds[3*4096 + offB];
        bD[fj] = *(const bf16x8*)&lds[4*4096 + offB];
      }
      #pragma unroll
      for (int fj=0; fj<4; ++fj){
        acc[0][fj] = __builtin_amdgcn_mfma_f32_16x16x32_bf16(ah,  bA[fj], acc[0][fj], 0,0,0);
        acc[0][fj] = __builtin_amdgcn_mfma_f32_16x16x32_bf16(alo, bA[fj], acc[0][fj], 0,0,0);
        acc[1][fj] = __builtin_amdgcn_mfma_f32_16x16x32_bf16(ah,  b2[fj], acc[1][fj], 0,0,0);
        acc[1][fj] = __builtin_amdgcn_mfma_f32_16x16x32_bf16(alo, b2[fj], acc[1][fj], 0,0,0);
        acc[2][fj] = __builtin_amdgcn_mfma_f32_16x16x32_bf16(ah,  bD[fj], acc[2][fj], 0,0,0);
        acc[2][fj] = __builtin_amdgcn_mfma_f32_16x16x32_bf16(alo, bD[fj], acc[2][fj], 0,0,0);
      }
    }
    __syncthreads();
  }
  int cg = cBase + (w<<4) + (kq<<2);
  #pragma unroll
  for (int fj=0; fj<4; ++fj){
    int ng = nBase + (fj<<4) + fl;
    *(float4*)&P [(size_t)ng*OUTS_ + cg] = make_float4(acc[0][fj][0],acc[0][fj][1],acc[0][fj][2],acc[0][fj][3]);
    *(float4*)&Rm[(size_t)ng*OUTS_ + cg] = make_float4(acc[1][fj][0],acc[1][fj][1],acc[1][fj][2],acc[1][fj][3]);
    *(float4*)&Qm[(size_t)ng*OUTS_ + cg] = make_float4(acc[2][fj][0],acc[2][fj][1],acc[2][fj][2],acc[2][fj][3]);
  }
}

// ---------- weight prep: two-stage per-o max (no atomics), int16 packed [n][kc][o][8] ----------
// stage 1: grid (ceil(KIO/256), 2); partial max over 256 n's -> scratch[block][o]
__global__ __launch_bounds__(256) void k_wmax(const float* __restrict__ wp, const float* __restrict__ emb,
                       float* __restrict__ scratch, int KIO, int O){
  __shared__ float es[N_*ED_];
  __shared__ float sm[256];
  for (int e = threadIdx.x; e < N_*ED_; e += 256) es[e] = emb[e];
  __syncthreads();
  int e = blockIdx.x*256 + threadIdx.x;
  float m = 0.f;
  if (e < KIO){
    float wv[ED_];
    #pragma unroll
    for (int d=0; d<ED_; ++d) wv[d] = wp[(size_t)d*KIO + e];
    int n0 = blockIdx.y*256;
    for (int n=n0; n<n0+256; ++n){
      float a = 0.f;
      #pragma unroll
      for (int d=0; d<ED_; ++d) a += es[n*ED_+d]*wv[d];
      m = fmaxf(m, fabsf(a));
    }
  }
  sm[threadIdx.x] = m;
  __syncthreads();
  for (int s=128; s>=O; s>>=1){
    if (threadIdx.x < s) sm[threadIdx.x] = fmaxf(sm[threadIdx.x], sm[threadIdx.x+s]);
    __syncthreads();
  }
  // o = (bx*256+tid)%O = tid for tid<O (256%O==0)
  if (threadIdx.x < O)
    scratch[(size_t)(blockIdx.x*gridDim.y + blockIdx.y)*O + threadIdx.x] = sm[threadIdx.x];
}

// stage 2: reduce nb partials per o -> sb (plain f32)
__global__ __launch_bounds__(128) void k_wred(const float* __restrict__ scratch,
                       float* __restrict__ sb, int nb, int O){
  int o = threadIdx.x;
  if (o >= O) return;
  float m = 0.f;
  for (int b=0; b<nb; ++b) m = fmaxf(m, scratch[(size_t)b*O + o]);
  sb[o] = m;
}

__global__ __launch_bounds__(256) void k_wquant(const float* __restrict__ wp, const float* __restrict__ emb,
                         const float* __restrict__ sb, short* __restrict__ W,
                         int KI, int O, int RS){
  __shared__ float es[N_*ED_];
  for (int e = threadIdx.x; e < N_*ED_; e += 256) es[e] = emb[e];
  __syncthreads();
  int KC = RS/8;
  int e = blockIdx.x*256 + threadIdx.x;
  if (e >= KC*O) return;
  int o = e % O, kc = e / O;
  int KIO = KI*O;
  float M = sb[o];
  float inv = (M > 0.f) ? 32767.f/M : 0.f;
  float wv[8][ED_];
  #pragma unroll
  for (int km=0; km<8; ++km){
    int ki = kc*8 + km;
    #pragma unroll
    for (int d=0; d<ED_; ++d)
      wv[km][d] = (ki < KI) ? wp[(size_t)d*KIO + (size_t)ki*O + o] : 0.f;
  }
  int n0 = blockIdx.y*32;
  for (int n=n0; n<n0+32; ++n){
    short8 q;
    #pragma unroll
    for (int km=0; km<8; ++km){
      float a = 0.f;
      #pragma unroll
      for (int d=0; d<ED_; ++d) a += es[n*ED_+d]*wv[km][d];
      q[km] = (short)__float2int_rn(a*inv);
    }
    *(short8*)&W[(((size_t)n*KC + kc)*O + o)*8] = q;
  }
}

__global__ __launch_bounds__(256) void k_bias(const float* __restrict__ bp, const float* __restrict__ emb,
                       float* __restrict__ Bo, int O){
  int idx = blockIdx.x*256 + threadIdx.x;
  int o = idx % O, n = idx / O;
  float a = 0.f;
  #pragma unroll
  for (int d=0; d<ED_; ++d) a += emb[n*ED_+d]*bp[d*O+o];
  Bo[idx] = a;
}

__global__ void k_fill0(float* __restrict__ p, size_t n){
  size_t i = (size_t)blockIdx.x*blockDim.x + threadIdx.x;
  size_t stride = (size_t)gridDim.x*blockDim.x;
  for (; i<n; i+=stride) p[i] = 0.f;
}

// ---------- plane builders ----------
__global__ __launch_bounds__(256) void k_btr(const float* __restrict__ S0, const float* __restrict__ S1,
        ushort_t* __restrict__ XH, ushort_t* __restrict__ XL, int CIN, int coff0, int coff1,
        const float* __restrict__ src, int t, int doSrc){
  __shared__ float Tt[64][65];
  const float* S = blockIdx.z ? S1 : S0;
  int coff = blockIdx.z ? coff1 : coff0;
  int mt = blockIdx.x, b = blockIdx.y;
  int r = threadIdx.x >> 6;
  int j = threadIdx.x & 63;
  #pragma unroll
  for (int rr=0; rr<16; ++rr){
    int m = mt*64 + rr*4 + r;
    Tt[rr*4+r][j] = S[((size_t)m*B_ + b)*H_ + j];
  }
  if (doSrc && blockIdx.z==0 && threadIdx.x < 64){
    int m = mt*64 + threadIdx.x;
    float x = src[((size_t)(b*T_+t))*N_ + m];
    size_t o = ((size_t)(b*CIN))*N_ + m;
    ushort_t xh = f2b(x);
    XH[o] = xh; XL[o] = f2b(x - b2f(xh));
  }
  __syncthreads();
  int mr = threadIdx.x & 63;
  int jq = threadIdx.x >> 6;
  #pragma unroll
  for (int jj=0; jj<16; ++jj){
    int jcol = jj*4 + jq;
    float x = Tt[mr][jcol];
    size_t idx = ((size_t)(b*CIN + coff + jcol))*N_ + mt*64 + mr;
    ushort_t xh = f2b(x);
    XH[idx] = xh;
    XL[idx] = f2b(x - b2f(xh));
  }
}

// ---------- int16 contraction core (prefetch-2), sum order ki ascending ----------
template<int KC, int NBJ, int OSTR, int AS>
__device__ __forceinline__ void contract_i16(const short* __restrict__ Wb,
                                             const float* __restrict__ A0,
                                             float acc[4][NBJ]){
  short8 w0,w1,w2,w3, p0,p1,p2,p3, q0,q1,q2,q3;
  {
    const short8* wp8 = (const short8*)(Wb);
    w0=wp8[0]; w1=wp8[1]; w2=wp8[2]; w3=wp8[3];
    const short8* pp8 = (const short8*)(Wb + OSTR);
    p0=pp8[0]; p1=pp8[1]; p2=pp8[2]; p3=pp8[3];
    q0=p0; q1=p1; q2=p2; q3=p3;
  }
  for (int kc=0; kc<KC; ++kc){
    if (kc+2 < KC){
      const short8* np8 = (const short8*)(Wb + (size_t)(kc+2)*OSTR);
      q0=np8[0]; q1=np8[1]; q2=np8[2]; q3=np8[3];
    }
    #pragma unroll
    for (int kh=0; kh<2; ++kh){
      f32x4 av[NBJ];
      #pragma unroll
      for (int bj=0; bj<NBJ; ++bj) av[bj] = *(const f32x4*)&A0[bj*AS + kc*8 + kh*4];
      #pragma unroll
      for (int u=0; u<4; ++u){
        float f0=(float)w0[kh*4+u], f1=(float)w1[kh*4+u];
        float f2v=(float)w2[kh*4+u], f3=(float)w3[kh*4+u];
        #pragma unroll
        for (int bj=0; bj<NBJ; ++bj){
          acc[0][bj] += av[bj][u]*f0;
          acc[1][bj] += av[bj][u]*f1;
          acc[2][bj] += av[bj][u]*f2v;
          acc[3][bj] += av[bj][u]*f3;
        }
      }
    }
    w0=p0; w1=p1; w2=p2; w3=p3;
    p0=q0; p1=q1; p2=q2; p3=q3;
  }
}

// ---------- per-node gate (O=128): 32ow x 8bq, 4o x 4b per thread ----------
template<int CIN>
__global__ __launch_bounds__(256) void k_gate(
    const float* __restrict__ src, int t,
    const float* __restrict__ hx, const float* __restrict__ hy,
    const float* __restrict__ P, const float* __restrict__ Rm, const float* __restrict__ Qm,
    const float* __restrict__ dvec, const float* __restrict__ lam,
    const short* __restrict__ W, const float* __restrict__ Wsc, const float* __restrict__ Bb,
    const float* __restrict__ hstate,
    float* __restrict__ cand, float* __restrict__ rbuf)
{
  constexpr int O  = 128;
  constexpr int RS = (3*CIN + 7) & ~7;
  constexpr int KC = RS/8;
  constexpr int AS = RS + 4;
  __shared__ float A[B_*AS];
  int n = blockIdx.x;
  float lm = lam[0];
  float al = -2.f/lm;
  float dn = 2.f*dvec[n]/lm - 1.f;
  float c_r = 2.f*al*al, c_q = 2.f*al, c_p = 2.f*al*dn, c_x = 2.f*dn*dn - 1.f;
  for (int e = threadIdx.x; e < B_*CIN; e += 256){
    int b = e/CIN, c = e%CIN;
    float x;
    if (CIN==65) x = (c==0) ? src[((size_t)(b*T_+t))*N_ + n] : hx[(size_t)n*(B_*H_) + b*H_ + (c-1)];
    else         x = (c<H_) ? hx[(size_t)n*(B_*H_) + b*H_ + c] : hy[(size_t)n*(B_*H_) + b*H_ + (c-H_)];
    size_t pi = (size_t)n*OUTS_ + e;
    float pe = P[pi], re = Rm[pi], qe = Qm[pi];
    float* Ab = A + b*AS;
    Ab[c]         = x;
    Ab[CIN+c]     = al*pe + dn*x;
    Ab[2*CIN+c]   = c_r*re + c_q*qe + c_p*pe + c_x*x;
  }
  for (int e = threadIdx.x; e < B_*(AS-3*CIN); e += 256){
    int b = e/(AS-3*CIN), c = e%(AS-3*CIN);
    A[b*AS + 3*CIN + c] = 0.f;
  }
  __syncthreads();
  int ow = threadIdx.x & 31;
  int bq = threadIdx.x >> 5;
  int o0 = ow*4;
  float acc[4][4] = {};
  const short* Wb = W + ((size_t)n*KC*O + o0)*8;
  const float* A0 = A + (bq*4)*AS;
  contract_i16<KC,4,O*8,AS>(Wb, A0, acc);
  #pragma unroll
  for (int oj=0; oj<4; ++oj){
    int o = o0 + oj;
    float sc = Wsc[o]*(1.f/32767.f);
    float bias = Bb[n*O+o];
    if (o < H_){
      #pragma unroll
      for (int bj=0; bj<4; ++bj){
        int b = bq*4 + bj;
        float z = sigmoidf_(acc[oj][bj]*sc + bias);
        size_t hi = (size_t)n*(B_*H_) + b*H_ + o;
        cand[hi] = z*hstate[hi];
      }
    } else {
      int oo = o - H_;
      #pragma unroll
      for (int bj=0; bj<4; ++bj){
        int b = bq*4 + bj;
        rbuf[(size_t)n*(B_*H_) + b*H_ + oo] = sigmoidf_(acc[oj][bj]*sc + bias);
      }
    }
  }
}

// ---------- per-node update (O=64): 16ow x 16bq, 4o x 2b ----------
template<int CIN>
__global__ __launch_bounds__(256) void k_update(
    const float* __restrict__ src, int t,
    const float* __restrict__ hx, const float* __restrict__ cand,
    const float* __restrict__ P, const float* __restrict__ Rm, const float* __restrict__ Qm,
    const float* __restrict__ dvec, const float* __restrict__ lam,
    const short* __restrict__ W, const float* __restrict__ Wsc, const float* __restrict__ Bb,
    const float* __restrict__ rbuf, float* __restrict__ h)
{
  constexpr int O  = 64;
  constexpr int RS = (3*CIN + 7) & ~7;
  constexpr int KC = RS/8;
  constexpr int AS = RS + 4;
  __shared__ float A[B_*AS];
  int n = blockIdx.x;
  float lm = lam[0];
  float al = -2.f/lm;
  float dn = 2.f*dvec[n]/lm - 1.f;
  float c_r = 2.f*al*al, c_q = 2.f*al, c_p = 2.f*al*dn, c_x = 2.f*dn*dn - 1.f;
  for (int e = threadIdx.x; e < B_*CIN; e += 256){
    int b = e/CIN, c = e%CIN;
    float x;
    if (CIN==65) x = (c==0) ? src[((size_t)(b*T_+t))*N_ + n] : cand[(size_t)n*(B_*H_) + b*H_ + (c-1)];
    else         x = (c<H_) ? hx[(size_t)n*(B_*H_) + b*H_ + c] : cand[(size_t)n*(B_*H_) + b*H_ + (c-H_)];
    size_t pi = (size_t)n*OUTS_ + e;
    float pe = P[pi], re = Rm[pi], qe = Qm[pi];
    float* Ab = A + b*AS;
    Ab[c]         = x;
    Ab[CIN+c]     = al*pe + dn*x;
    Ab[2*CIN+c]   = c_r*re + c_q*qe + c_p*pe + c_x*x;
  }
  for (int e = threadIdx.x; e < B_*(AS-3*CIN); e += 256){
    int b = e/(AS-3*CIN), c = e%(AS-3*CIN);
    A[b*AS + 3*CIN + c] = 0.f;
  }
  __syncthreads();
  int ow = threadIdx.x & 15;
  int bq = threadIdx.x >> 4;
  int o0 = ow*4;
  float acc[4][2] = {};
  const short* Wb = W + ((size_t)n*KC*O + o0)*8;
  const float* A0 = A + (bq*2)*AS;
  contract_i16<KC,2,O*8,AS>(Wb, A0, acc);
  #pragma unroll
  for (int oj=0; oj<4; ++oj){
    int o = o0 + oj;
    float sc = Wsc[o]*(1.f/32767.f);
    float bias = Bb[n*O+o];
    #pragma unroll
    for (int bj=0; bj<2; ++bj){
      int b = bq*2 + bj;
      float hc = tanhf(acc[oj][bj]*sc + bias);
      size_t hidx = (size_t)n*(B_*H_) + b*H_ + o;
      float r = rbuf[hidx];
      h[hidx] = r*h[hidx] + (1.f-r)*hc;
    }
  }
}

// ---------- readout ----------
__global__ __launch_bounds__(256) void k_readout(const float* __restrict__ hB, const float* __restrict__ cw,
                          const float* __restrict__ cb, float* __restrict__ out){
  int idx = blockIdx.x*256 + threadIdx.x;
  int n = idx & (N_-1);
  int bo = idx >> 9;
  int o = bo % HOR_, b = bo / HOR_;
  float a = cb[o];
  #pragma unroll
  for (int j=0;j<H_;++j) a += hB[(size_t)n*(B_*H_) + b*H_ + j]*cw[o*H_+j];
  out[idx] = a;
}

extern "C" void kernel_launch(void* const* d_in, const int* in_sizes, int n_in,
                              void* d_out, int out_size, void* d_ws, size_t ws_size,
                              hipStream_t stream){
  (void)in_sizes; (void)n_in; (void)out_size; (void)ws_size;
  const float* src  = (const float*)d_in[0];
  const float* gn   = (const float*)d_in[2];
  const float* emb  = (const float*)d_in[3];
  const float* gw0  = (const float*)d_in[4];
  const float* gb0  = (const float*)d_in[5];
  const float* uw0  = (const float*)d_in[6];
  const float* ub0  = (const float*)d_in[7];
  const float* gw1  = (const float*)d_in[8];
  const float* gb1  = (const float*)d_in[9];
  const float* uw1  = (const float*)d_in[10];
  const float* ub1  = (const float*)d_in[11];
  const float* cw   = (const float*)d_in[12];
  const float* cb   = (const float*)d_in[13];
  float* out = (float*)d_out;

  const int RS0 = 200;  // (3*65+7)&~7
  const int RS1 = 384;  // 3*128

  char* ws = (char*)d_ws;
  size_t off = 0;
  auto alloc = [&](size_t bytes)->char*{
    char* p = ws + off; off = (off + bytes + 255) & ~(size_t)255; return p;
  };
  short* Wg0 = (short*)alloc((size_t)N_*128*RS0*2);
  short* Wu0 = (short*)alloc((size_t)N_*64*RS0*2);
  short* Wg1 = (short*)alloc((size_t)N_*128*RS1*2);
  short* Wu1 = (short*)alloc((size_t)N_*64*RS1*2);
  float* Sg0 = (float*)alloc(128*4);
  float* Su0 = (float*)alloc(64*4);
  float* Sg1 = (float*)alloc(128*4);
  float* Su1 = (float*)alloc(64*4);
  float* wscr = (float*)alloc((size_t)512*128*4);   // wmax partials (max 384x128)
  float* Bg0 = (float*)alloc((size_t)N_*128*4);
  float* Bu0 = (float*)alloc((size_t)N_*64*4);
  float* Bg1 = (float*)alloc((size_t)N_*128*4);
  float* Bu1 = (float*)alloc((size_t)N_*64*4);
  ushort_t* Abf  = (ushort_t*)alloc((size_t)N_*N_*2);
  ushort_t* A2bf = (ushort_t*)alloc((size_t)N_*N_*2);
  ushort_t* ADh  = (ushort_t*)alloc((size_t)N_*N_*2);
  float* dvec = (float*)alloc(N_*4);
  float* lam  = (float*)alloc(256);
  float* nrm  = (float*)alloc(N_*4);
  float* hA   = (float*)alloc((size_t)N_*B_*H_*4);
  float* hB   = (float*)alloc((size_t)N_*B_*H_*4);
  float* rbuf = (float*)alloc((size_t)N_*B_*H_*4);
  float* cand = (float*)alloc((size_t)N_*B_*H_*4);
  ushort_t* XH = (ushort_t*)alloc((size_t)4096*N_*2);
  ushort_t* XL = (ushort_t*)alloc((size_t)4096*N_*2);
  float* P  = (float*)alloc((size_t)N_*OUTS_*4);
  float* R  = (float*)alloc((size_t)N_*OUTS_*4);
  float* Q  = (float*)alloc((size_t)N_*OUTS_*4);

  // graph structure
  k_norm<<<1,512,0,stream>>>(emb, nrm);
  k_adj<<<N_,256,0,stream>>>(emb, nrm, gn, Abf, dvec);
  k_lam<<<1,512,0,stream>>>(dvec, lam);
  k_a2<<<N_,256,0,stream>>>(Abf, A2bf);
  k_admats<<<(N_*N_)/256,256,0,stream>>>(Abf, dvec, lam, ADh);

  // weights: two-stage per-o max -> scale, then quantize (packed [n][kc][o][8])
  k_wmax<<<dim3(98,2),256,0,stream>>>(gw0, emb, wscr, 195*128, 128);
  k_wred<<<1,128,0,stream>>>(wscr, Sg0, 196, 128);
  k_wmax<<<dim3(49,2),256,0,stream>>>(uw0, emb, wscr, 195*64, 64);
  k_wred<<<1,128,0,stream>>>(wscr, Su0, 98, 64);
  k_wmax<<<dim3(192,2),256,0,stream>>>(gw1, emb, wscr, 384*128, 128);
  k_wred<<<1,128,0,stream>>>(wscr, Sg1, 384, 128);
  k_wmax<<<dim3(96,2),256,0,stream>>>(uw1, emb, wscr, 384*64, 64);
  k_wred<<<1,128,0,stream>>>(wscr, Su1, 192, 64);
  k_wquant<<<dim3((25*128+255)/256,16),256,0,stream>>>(gw0, emb, Sg0, Wg0, 195, 128, RS0);
  k_wquant<<<dim3((25*64+255)/256,16),256,0,stream>>>(uw0, emb, Su0, Wu0, 195, 64, RS0);
  k_wquant<<<dim3((48*128)/256,16),256,0,stream>>>(gw1, emb, Sg1, Wg1, 384, 128, RS1);
  k_wquant<<<dim3((48*64)/256,16),256,0,stream>>>(uw1, emb, Su1, Wu1, 384, 64, RS1);
  k_bias<<<(N_*128)/256,256,0,stream>>>(gb0, emb, Bg0, 128);
  k_bias<<<(N_*64)/256,256,0,stream>>>(ub0, emb, Bu0, 64);
  k_bias<<<(N_*128)/256,256,0,stream>>>(gb1, emb, Bg1, 128);
  k_bias<<<(N_*64)/256,256,0,stream>>>(ub1, emb, Bu1, 64);

  k_fill0<<<2048,256,0,stream>>>(hA, (size_t)N_*B_*H_);
  k_fill0<<<2048,256,0,stream>>>(hB, (size_t)N_*B_*H_);

  for (int t=0; t<T_; ++t){
    // ---- layer 0 (CIN=65, cols padded to 2176 = 34*64) ----
    k_btr<<<dim3(8,32,1),256,0,stream>>>(hA, hA, XH, XL, 65, 1, 1, src, t, 1);
    k_apply<<<dim3(34,8),256,0,stream>>>(XH, XL, Abf, A2bf, ADh, P, R, Q);
    k_gate<65><<<N_,256,0,stream>>>(src, t, hA, hA, P, R, Q, dvec, lam,
                                    Wg0, Sg0, Bg0, hA, cand, rbuf);
    k_btr<<<dim3(8,32,1),256,0,stream>>>(cand, cand, XH, XL, 65, 1, 1, nullptr, 0, 0);
    k_apply<<<dim3(34,8),256,0,stream>>>(XH, XL, Abf, A2bf, ADh, P, R, Q);
    k_update<65><<<N_,256,0,stream>>>(src, t, hA, cand, P, R, Q, dvec, lam,
                                      Wu0, Su0, Bu0, rbuf, hA);
    // ---- layer 1 (CIN=128, cols = 4096 = 64*64) ----
    k_btr<<<dim3(8,32,2),256,0,stream>>>(hA, hB, XH, XL, 128, 0, 64, nullptr, 0, 0);
    k_apply<<<dim3(64,8),256,0,stream>>>(XH, XL, Abf, A2bf, ADh, P, R, Q);
    k_gate<128><<<N_,256,0,stream>>>(nullptr, 0, hA, hB, P, R, Q, dvec, lam,
                                     Wg1, Sg1, Bg1, hB, cand, rbuf);
    k_btr<<<dim3(8,32,1),256,0,stream>>>(cand, cand, XH, XL, 128, 64, 64, nullptr, 0, 0);
    k_apply<<<dim3(64,8),256,0,stream>>>(XH, XL, Abf, A2bf, ADh, P, R, Q);
    k_update<128><<<N_,256,0,stream>>>(nullptr, 0, hA, cand, P, R, Q, dvec, lam,
                                       Wu1, Su1, Bu1, rbuf, hB);
  }

  k_readout<<<(B_*HOR_*N_)/256,256,0,stream>>>(hB, cw, cb, out);
}

// Round 12
// 2693.744 us; speedup vs baseline: 1.9338x; 1.0720x over previous
//
#include <hip/hip_runtime.h>
#include <math.h>

#define N_    512
#define B_    32
#define T_    12
#define H_    64
#define ED_   10
#define HOR_  12
#define OUTS_ 4096

typedef unsigned short ushort_t;
typedef __attribute__((ext_vector_type(4))) float f32x4;
typedef __attribute__((ext_vector_type(8))) __bf16 bf16x8;
typedef __attribute__((ext_vector_type(8))) short short8;

__device__ __forceinline__ float sigmoidf_(float x){ return 1.f/(1.f+expf(-x)); }
__device__ __forceinline__ float b2f(ushort_t u){ return __uint_as_float(((unsigned)u)<<16); }
__device__ __forceinline__ ushort_t f2b(float f){
  unsigned x = __float_as_uint(f);
  unsigned r = x + 0x7FFFu + ((x>>16)&1u);
  return (ushort_t)(r>>16);
}
__device__ __forceinline__ void stage16(const void* g, void* l){
  __builtin_amdgcn_global_load_lds(
    (const __attribute__((address_space(1))) unsigned int*)g,
    (__attribute__((address_space(3))) unsigned int*)l, 16, 0, 0);
}

// ---------- graph structure ----------
__global__ __launch_bounds__(512) void k_norm(const float* __restrict__ emb, float* __restrict__ nrm){
  int n = threadIdx.x;
  if (n < N_){
    float s = 0.f;
    #pragma unroll
    for (int d=0; d<ED_; ++d){ float v = emb[n*ED_+d]; s += v*v; }
    nrm[n] = sqrtf(s);
  }
}

__global__ __launch_bounds__(256) void k_adj(const float* __restrict__ emb, const float* __restrict__ nrm,
                      const float* __restrict__ gn, ushort_t* __restrict__ Abf, float* __restrict__ dvec){
  __shared__ float ei[ED_];
  __shared__ float red[256];
  int i = blockIdx.x;
  if (threadIdx.x < ED_) ei[threadIdx.x] = emb[i*ED_+threadIdx.x];
  __syncthreads();
  float ni = nrm[i];
  float part = 0.f;
  for (int j = threadIdx.x; j < N_; j += 256){
    float dot = 0.f;
    #pragma unroll
    for (int d=0; d<ED_; ++d) dot += ei[d]*emb[j*ED_+d];
    float lg = (dot/(ni*nrm[j]) + 1.f)*0.5f;
    size_t gi = ((size_t)i*N_ + j)*2;
    float y0 = lg + gn[gi];
    float y1 = (1.f - lg) + gn[gi+1];
    bool a = (j != i && y0 >= y1);
    Abf[(size_t)i*N_ + j] = a ? (ushort_t)0x3F80 : (ushort_t)0;
    part += a ? 1.f : 0.f;
  }
  red[threadIdx.x] = part;
  __syncthreads();
  for (int s=128; s>0; s>>=1){
    if (threadIdx.x < s) red[threadIdx.x] += red[threadIdx.x+s];
    __syncthreads();
  }
  if (threadIdx.x==0) dvec[i] = red[0];
}

__global__ __launch_bounds__(512) void k_lam(const float* __restrict__ dvec, float* __restrict__ lam){
  __shared__ float red[512];
  red[threadIdx.x] = dvec[threadIdx.x];
  __syncthreads();
  for (int s=256; s>0; s>>=1){
    if (threadIdx.x < s) red[threadIdx.x] = fmaxf(red[threadIdx.x], red[threadIdx.x+s]);
    __syncthreads();
  }
  if (threadIdx.x==0){
    float maxd = red[0];
    lam[0] = maxd + (maxd > 0.f ? 1.f : 0.f);
  }
}

__global__ __launch_bounds__(256) void k_a2(const ushort_t* __restrict__ Abf, ushort_t* __restrict__ A2bf){
  __shared__ float ar[N_];
  int n = blockIdx.x;
  for (int p = threadIdx.x; p < N_; p += 256) ar[p] = b2f(Abf[(size_t)n*N_ + p]);
  __syncthreads();
  int m0 = threadIdx.x, m1 = threadIdx.x + 256;
  float a0 = 0.f, a1 = 0.f;
  for (int p=0; p<N_; ++p){
    float ap = ar[p];
    a0 += ap * b2f(Abf[(size_t)p*N_ + m0]);
    a1 += ap * b2f(Abf[(size_t)p*N_ + m1]);
  }
  A2bf[(size_t)n*N_ + m0] = f2b(a0);
  A2bf[(size_t)n*N_ + m1] = f2b(a1);
}

__global__ __launch_bounds__(256) void k_admats(const ushort_t* __restrict__ Abf, const float* __restrict__ dvec,
                        const float* __restrict__ lam, ushort_t* __restrict__ ADh){
  int idx = blockIdx.x*256 + threadIdx.x;
  int m = idx & (N_-1);
  float dm = 2.f*dvec[m]/lam[0] - 1.f;
  ADh[idx] = Abf[idx] ? f2b(dm) : (ushort_t)0;
}

// ---------- fused MFMA apply: 64 cols x 64 n, ALL 3 matrices per block ----------
__global__ __launch_bounds__(256) void k_apply(
    const ushort_t* __restrict__ XH, const ushort_t* __restrict__ XL,
    const ushort_t* __restrict__ Abf, const ushort_t* __restrict__ A2bf, const ushort_t* __restrict__ ADh,
    float* __restrict__ P, float* __restrict__ Rm, float* __restrict__ Qm)
{
  __shared__ ushort_t lds[5*4096];
  const int cBase = blockIdx.x<<6, nBase = blockIdx.y<<6;
  const int tid = threadIdx.x, lane = tid&63, w = tid>>6;
  const int lrow = lane>>3, lslot = lane&7;
  const int srck = lslot ^ (lrow&7);
  f32x4 acc[3][4];
  #pragma unroll
  for (int i=0;i<3;++i)
    #pragma unroll
    for (int j=0;j<4;++j) acc[i][j] = f32x4{0.f,0.f,0.f,0.f};
  const int fl = lane&15, kq = lane>>4;

  for (int kk=0; kk<512; kk+=64){
    #pragma unroll
    for (int s=0; s<10; ++s){
      int instId = w + s*4;        // 0..39
      int tile = instId>>3;        // 0..4
      int inst = instId&7;         // 0..7
      const char* g = (tile==0)? (const char*)XH : (tile==1)? (const char*)XL :
                      (tile==2)? (const char*)Abf : (tile==3)? (const char*)A2bf : (const char*)ADh;
      int rb = (tile<2? cBase : nBase) + inst*8 + lrow;
      stage16(g + (size_t)rb*(N_*2) + kk*2 + srck*16,
              (char*)lds + tile*8192 + inst*1024);
    }
    __syncthreads();
    #pragma unroll
    for (int kh=0; kh<2; ++kh){
      int rowA = (w<<4) + fl;
      int offA = (rowA<<6) + (((kq + (kh<<2)) ^ (rowA&7))<<3);
      bf16x8 ah  = *(const bf16x8*)&lds[offA];
      bf16x8 alo = *(const bf16x8*)&lds[4096 + offA];
      bf16x8 bA[4], b2[4], bD[4];
      #pragma unroll
      for (int fj=0; fj<4; ++fj){
        int rowB = (fj<<4) + fl;
        int offB = (rowB<<6) + (((kq + (kh<<2)) ^ (rowB&7))<<3);
        bA[fj] = *(const bf16x8*)&lds[2*4096 + offB];
        b2[fj] = *(const bf16x8*)&lds[3*4096 + offB];
        bD[fj] = *(const bf16x8*)&lds[4*4096 + offB];
      }
      #pragma unroll
      for (int fj=0; fj<4; ++fj){
        acc[0][fj] = __builtin_amdgcn_mfma_f32_16x16x32_bf16(ah,  bA[fj], acc[0][fj], 0,0,0);
        acc[0][fj] = __builtin_amdgcn_mfma_f32_16x16x32_bf16(alo, bA[fj], acc[0][fj], 0,0,0);
        acc[1][fj] = __builtin_amdgcn_mfma_f32_16x16x32_bf16(ah,  b2[fj], acc[1][fj], 0,0,0);
        acc[1][fj] = __builtin_amdgcn_mfma_f32_16x16x32_bf16(alo, b2[fj], acc[1][fj], 0,0,0);
        acc[2][fj] = __builtin_amdgcn_mfma_f32_16x16x32_bf16(ah,  bD[fj], acc[2][fj], 0,0,0);
        acc[2][fj] = __builtin_amdgcn_mfma_f32_16x16x32_bf16(alo, bD[fj], acc[2][fj], 0,0,0);
      }
    }
    __syncthreads();
  }
  int cg = cBase + (w<<4) + (kq<<2);
  #pragma unroll
  for (int fj=0; fj<4; ++fj){
    int ng = nBase + (fj<<4) + fl;
    *(float4*)&P [(size_t)ng*OUTS_ + cg] = make_float4(acc[0][fj][0],acc[0][fj][1],acc[0][fj][2],acc[0][fj][3]);
    *(float4*)&Rm[(size_t)ng*OUTS_ + cg] = make_float4(acc[1][fj][0],acc[1][fj][1],acc[1][fj][2],acc[1][fj][3]);
    *(float4*)&Qm[(size_t)ng*OUTS_ + cg] = make_float4(acc[2][fj][0],acc[2][fj][1],acc[2][fj][2],acc[2][fj][3]);
  }
}

// ---------- weight prep: two-stage per-o max (no atomics), int16 packed [n][kc][o][8] ----------
__global__ __launch_bounds__(256) void k_wmax(const float* __restrict__ wp, const float* __restrict__ emb,
                       float* __restrict__ scratch, int KIO, int O){
  __shared__ float es[N_*ED_];
  __shared__ float sm[256];
  for (int e = threadIdx.x; e < N_*ED_; e += 256) es[e] = emb[e];
  __syncthreads();
  int e = blockIdx.x*256 + threadIdx.x;
  float m = 0.f;
  if (e < KIO){
    float wv[ED_];
    #pragma unroll
    for (int d=0; d<ED_; ++d) wv[d] = wp[(size_t)d*KIO + e];
    int n0 = blockIdx.y*256;
    for (int n=n0; n<n0+256; ++n){
      float a = 0.f;
      #pragma unroll
      for (int d=0; d<ED_; ++d) a += es[n*ED_+d]*wv[d];
      m = fmaxf(m, fabsf(a));
    }
  }
  sm[threadIdx.x] = m;
  __syncthreads();
  for (int s=128; s>=O; s>>=1){
    if (threadIdx.x < s) sm[threadIdx.x] = fmaxf(sm[threadIdx.x], sm[threadIdx.x+s]);
    __syncthreads();
  }
  if (threadIdx.x < O)
    scratch[(size_t)(blockIdx.x*gridDim.y + blockIdx.y)*O + threadIdx.x] = sm[threadIdx.x];
}

// stage 2: PARALLEL reduce — one block per o, 256 threads stride over partials
__global__ __launch_bounds__(256) void k_wred(const float* __restrict__ scratch,
                       float* __restrict__ sb, int nb, int O){
  __shared__ float sm[256];
  int o = blockIdx.x;
  float m = 0.f;
  for (int b = threadIdx.x; b < nb; b += 256)
    m = fmaxf(m, scratch[(size_t)b*O + o]);
  sm[threadIdx.x] = m;
  __syncthreads();
  for (int s=128; s>0; s>>=1){
    if (threadIdx.x < s) sm[threadIdx.x] = fmaxf(sm[threadIdx.x], sm[threadIdx.x+s]);
    __syncthreads();
  }
  if (threadIdx.x==0) sb[o] = sm[0];
}

__global__ __launch_bounds__(256) void k_wquant(const float* __restrict__ wp, const float* __restrict__ emb,
                         const float* __restrict__ sb, short* __restrict__ W,
                         int KI, int O, int RS){
  __shared__ float es[N_*ED_];
  for (int e = threadIdx.x; e < N_*ED_; e += 256) es[e] = emb[e];
  __syncthreads();
  int KC = RS/8;
  int e = blockIdx.x*256 + threadIdx.x;
  if (e >= KC*O) return;
  int o = e % O, kc = e / O;
  int KIO = KI*O;
  float M = sb[o];
  float inv = (M > 0.f) ? 32767.f/M : 0.f;
  float wv[8][ED_];
  #pragma unroll
  for (int km=0; km<8; ++km){
    int ki = kc*8 + km;
    #pragma unroll
    for (int d=0; d<ED_; ++d)
      wv[km][d] = (ki < KI) ? wp[(size_t)d*KIO + (size_t)ki*O + o] : 0.f;
  }
  int n0 = blockIdx.y*32;
  for (int n=n0; n<n0+32; ++n){
    short8 q;
    #pragma unroll
    for (int km=0; km<8; ++km){
      float a = 0.f;
      #pragma unroll
      for (int d=0; d<ED_; ++d) a += es[n*ED_+d]*wv[km][d];
      q[km] = (short)__float2int_rn(a*inv);
    }
    *(short8*)&W[(((size_t)n*KC + kc)*O + o)*8] = q;
  }
}

__global__ __launch_bounds__(256) void k_bias(const float* __restrict__ bp, const float* __restrict__ emb,
                       float* __restrict__ Bo, int O){
  int idx = blockIdx.x*256 + threadIdx.x;
  int o = idx % O, n = idx / O;
  float a = 0.f;
  #pragma unroll
  for (int d=0; d<ED_; ++d) a += emb[n*ED_+d]*bp[d*O+o];
  Bo[idx] = a;
}

__global__ void k_fill0(float* __restrict__ p, size_t n){
  size_t i = (size_t)blockIdx.x*blockDim.x + threadIdx.x;
  size_t stride = (size_t)gridDim.x*blockDim.x;
  for (; i<n; i+=stride) p[i] = 0.f;
}

// ---------- plane builders ----------
__global__ __launch_bounds__(256) void k_btr(const float* __restrict__ S0, const float* __restrict__ S1,
        ushort_t* __restrict__ XH, ushort_t* __restrict__ XL, int CIN, int coff0, int coff1,
        const float* __restrict__ src, int t, int doSrc){
  __shared__ float Tt[64][65];
  const float* S = blockIdx.z ? S1 : S0;
  int coff = blockIdx.z ? coff1 : coff0;
  int mt = blockIdx.x, b = blockIdx.y;
  int r = threadIdx.x >> 6;
  int j = threadIdx.x & 63;
  #pragma unroll
  for (int rr=0; rr<16; ++rr){
    int m = mt*64 + rr*4 + r;
    Tt[rr*4+r][j] = S[((size_t)m*B_ + b)*H_ + j];
  }
  if (doSrc && blockIdx.z==0 && threadIdx.x < 64){
    int m = mt*64 + threadIdx.x;
    float x = src[((size_t)(b*T_+t))*N_ + m];
    size_t o = ((size_t)(b*CIN))*N_ + m;
    ushort_t xh = f2b(x);
    XH[o] = xh; XL[o] = f2b(x - b2f(xh));
  }
  __syncthreads();
  int mr = threadIdx.x & 63;
  int jq = threadIdx.x >> 6;
  #pragma unroll
  for (int jj=0; jj<16; ++jj){
    int jcol = jj*4 + jq;
    float x = Tt[mr][jcol];
    size_t idx = ((size_t)(b*CIN + coff + jcol))*N_ + mt*64 + mr;
    ushort_t xh = f2b(x);
    XH[idx] = xh;
    XL[idx] = f2b(x - b2f(xh));
  }
}

// ---------- int16 contraction core (prefetch-2), sum order ki ascending ----------
template<int KC, int NBJ, int OSTR, int AS>
__device__ __forceinline__ void contract_i16(const short* __restrict__ Wb,
                                             const float* __restrict__ A0,
                                             float acc[4][NBJ]){
  short8 w0,w1,w2,w3, p0,p1,p2,p3, q0,q1,q2,q3;
  {
    const short8* wp8 = (const short8*)(Wb);
    w0=wp8[0]; w1=wp8[1]; w2=wp8[2]; w3=wp8[3];
    const short8* pp8 = (const short8*)(Wb + OSTR);
    p0=pp8[0]; p1=pp8[1]; p2=pp8[2]; p3=pp8[3];
    q0=p0; q1=p1; q2=p2; q3=p3;
  }
  for (int kc=0; kc<KC; ++kc){
    if (kc+2 < KC){
      const short8* np8 = (const short8*)(Wb + (size_t)(kc+2)*OSTR);
      q0=np8[0]; q1=np8[1]; q2=np8[2]; q3=np8[3];
    }
    #pragma unroll
    for (int kh=0; kh<2; ++kh){
      f32x4 av[NBJ];
      #pragma unroll
      for (int bj=0; bj<NBJ; ++bj) av[bj] = *(const f32x4*)&A0[bj*AS + kc*8 + kh*4];
      #pragma unroll
      for (int u=0; u<4; ++u){
        float f0=(float)w0[kh*4+u], f1=(float)w1[kh*4+u];
        float f2v=(float)w2[kh*4+u], f3=(float)w3[kh*4+u];
        #pragma unroll
        for (int bj=0; bj<NBJ; ++bj){
          acc[0][bj] += av[bj][u]*f0;
          acc[1][bj] += av[bj][u]*f1;
          acc[2][bj] += av[bj][u]*f2v;
          acc[3][bj] += av[bj][u]*f3;
        }
      }
    }
    w0=p0; w1=p1; w2=p2; w3=p3;
    p0=q0; p1=q1; p2=q2; p3=q3;
  }
}

// ---------- per-node gate (O=128): 32ow x 8bq, 4o x 4b per thread ----------
template<int CIN>
__global__ __launch_bounds__(256) void k_gate(
    const float* __restrict__ src, int t,
    const float* __restrict__ hx, const float* __restrict__ hy,
    const float* __restrict__ P, const float* __restrict__ Rm, const float* __restrict__ Qm,
    const float* __restrict__ dvec, const float* __restrict__ lam,
    const short* __restrict__ W, const float* __restrict__ Wsc, const float* __restrict__ Bb,
    const float* __restrict__ hstate,
    float* __restrict__ cand, float* __restrict__ rbuf)
{
  constexpr int O  = 128;
  constexpr int RS = (3*CIN + 7) & ~7;
  constexpr int KC = RS/8;
  constexpr int AS = RS + 4;
  __shared__ float A[B_*AS];
  int n = blockIdx.x;
  float lm = lam[0];
  float al = -2.f/lm;
  float dn = 2.f*dvec[n]/lm - 1.f;
  float c_r = 2.f*al*al, c_q = 2.f*al, c_p = 2.f*al*dn, c_x = 2.f*dn*dn - 1.f;
  for (int e = threadIdx.x; e < B_*CIN; e += 256){
    int b = e/CIN, c = e%CIN;
    float x;
    if (CIN==65) x = (c==0) ? src[((size_t)(b*T_+t))*N_ + n] : hx[(size_t)n*(B_*H_) + b*H_ + (c-1)];
    else         x = (c<H_) ? hx[(size_t)n*(B_*H_) + b*H_ + c] : hy[(size_t)n*(B_*H_) + b*H_ + (c-H_)];
    size_t pi = (size_t)n*OUTS_ + e;
    float pe = P[pi], re = Rm[pi], qe = Qm[pi];
    float* Ab = A + b*AS;
    Ab[c]         = x;
    Ab[CIN+c]     = al*pe + dn*x;
    Ab[2*CIN+c]   = c_r*re + c_q*qe + c_p*pe + c_x*x;
  }
  for (int e = threadIdx.x; e < B_*(AS-3*CIN); e += 256){
    int b = e/(AS-3*CIN), c = e%(AS-3*CIN);
    A[b*AS + 3*CIN + c] = 0.f;
  }
  __syncthreads();
  int ow = threadIdx.x & 31;
  int bq = threadIdx.x >> 5;
  int o0 = ow*4;
  float acc[4][4] = {};
  const short* Wb = W + ((size_t)n*KC*O + o0)*8;
  const float* A0 = A + (bq*4)*AS;
  contract_i16<KC,4,O*8,AS>(Wb, A0, acc);
  #pragma unroll
  for (int oj=0; oj<4; ++oj){
    int o = o0 + oj;
    float sc = Wsc[o]*(1.f/32767.f);
    float bias = Bb[n*O+o];
    if (o < H_){
      #pragma unroll
      for (int bj=0; bj<4; ++bj){
        int b = bq*4 + bj;
        float z = sigmoidf_(acc[oj][bj]*sc + bias);
        size_t hi = (size_t)n*(B_*H_) + b*H_ + o;
        cand[hi] = z*hstate[hi];
      }
    } else {
      int oo = o - H_;
      #pragma unroll
      for (int bj=0; bj<4; ++bj){
        int b = bq*4 + bj;
        rbuf[(size_t)n*(B_*H_) + b*H_ + oo] = sigmoidf_(acc[oj][bj]*sc + bias);
      }
    }
  }
}

// ---------- per-node update (O=64): 16ow x 16bq, 4o x 2b ----------
template<int CIN>
__global__ __launch_bounds__(256) void k_update(
    const float* __restrict__ src, int t,
    const float* __restrict__ hx, const float* __restrict__ cand,
    const float* __restrict__ P, const float* __restrict__ Rm, const float* __restrict__ Qm,
    const float* __restrict__ dvec, const float* __restrict__ lam,
    const short* __restrict__ W, const float* __restrict__ Wsc, const float* __restrict__ Bb,
    const float* __restrict__ rbuf, float* __restrict__ h)
{
  constexpr int O  = 64;
  constexpr int RS = (3*CIN + 7) & ~7;
  constexpr int KC = RS/8;
  constexpr int AS = RS + 4;
  __shared__ float A[B_*AS];
  int n = blockIdx.x;
  float lm = lam[0];
  float al = -2.f/lm;
  float dn = 2.f*dvec[n]/lm - 1.f;
  float c_r = 2.f*al*al, c_q = 2.f*al, c_p = 2.f*al*dn, c_x = 2.f*dn*dn - 1.f;
  for (int e = threadIdx.x; e < B_*CIN; e += 256){
    int b = e/CIN, c = e%CIN;
    float x;
    if (CIN==65) x = (c==0) ? src[((size_t)(b*T_+t))*N_ + n] : cand[(size_t)n*(B_*H_) + b*H_ + (c-1)];
    else         x = (c<H_) ? hx[(size_t)n*(B_*H_) + b*H_ + c] : cand[(size_t)n*(B_*H_) + b*H_ + (c-H_)];
    size_t pi = (size_t)n*OUTS_ + e;
    float pe = P[pi], re = Rm[pi], qe = Qm[pi];
    float* Ab = A + b*AS;
    Ab[c]         = x;
    Ab[CIN+c]     = al*pe + dn*x;
    Ab[2*CIN+c]   = c_r*re + c_q*qe + c_p*pe + c_x*x;
  }
  for (int e = threadIdx.x; e < B_*(AS-3*CIN); e += 256){
    int b = e/(AS-3*CIN), c = e%(AS-3*CIN);
    A[b*AS + 3*CIN + c] = 0.f;
  }
  __syncthreads();
  int ow = threadIdx.x & 15;
  int bq = threadIdx.x >> 4;
  int o0 = ow*4;
  float acc[4][2] = {};
  const short* Wb = W + ((size_t)n*KC*O + o0)*8;
  const float* A0 = A + (bq*2)*AS;
  contract_i16<KC,2,O*8,AS>(Wb, A0, acc);
  #pragma unroll
  for (int oj=0; oj<4; ++oj){
    int o = o0 + oj;
    float sc = Wsc[o]*(1.f/32767.f);
    float bias = Bb[n*O+o];
    #pragma unroll
    for (int bj=0; bj<2; ++bj){
      int b = bq*2 + bj;
      float hc = tanhf(acc[oj][bj]*sc + bias);
      size_t hidx = (size_t)n*(B_*H_) + b*H_ + o;
      float r = rbuf[hidx];
      h[hidx] = r*h[hidx] + (1.f-r)*hc;
    }
  }
}

// ---------- readout ----------
__global__ __launch_bounds__(256) void k_readout(const float* __restrict__ hB, const float* __restrict__ cw,
                          const float* __restrict__ cb, float* __restrict__ out){
  int idx = blockIdx.x*256 + threadIdx.x;
  int n = idx & (N_-1);
  int bo = idx >> 9;
  int o = bo % HOR_, b = bo / HOR_;
  float a = cb[o];
  #pragma unroll
  for (int j=0;j<H_;++j) a += hB[(size_t)n*(B_*H_) + b*H_ + j]*cw[o*H_+j];
  out[idx] = a;
}

extern "C" void kernel_launch(void* const* d_in, const int* in_sizes, int n_in,
                              void* d_out, int out_size, void* d_ws, size_t ws_size,
                              hipStream_t stream){
  (void)in_sizes; (void)n_in; (void)out_size; (void)ws_size;
  const float* src  = (const float*)d_in[0];
  const float* gn   = (const float*)d_in[2];
  const float* emb  = (const float*)d_in[3];
  const float* gw0  = (const float*)d_in[4];
  const float* gb0  = (const float*)d_in[5];
  const float* uw0  = (const float*)d_in[6];
  const float* ub0  = (const float*)d_in[7];
  const float* gw1  = (const float*)d_in[8];
  const float* gb1  = (const float*)d_in[9];
  const float* uw1  = (const float*)d_in[10];
  const float* ub1  = (const float*)d_in[11];
  const float* cw   = (const float*)d_in[12];
  const float* cb   = (const float*)d_in[13];
  float* out = (float*)d_out;

  const int RS0 = 200;  // (3*65+7)&~7
  const int RS1 = 384;  // 3*128

  char* ws = (char*)d_ws;
  size_t off = 0;
  auto alloc = [&](size_t bytes)->char*{
    char* p = ws + off; off = (off + bytes + 255) & ~(size_t)255; return p;
  };
  short* Wg0 = (short*)alloc((size_t)N_*128*RS0*2);
  short* Wu0 = (short*)alloc((size_t)N_*64*RS0*2);
  short* Wg1 = (short*)alloc((size_t)N_*128*RS1*2);
  short* Wu1 = (short*)alloc((size_t)N_*64*RS1*2);
  float* Sg0 = (float*)alloc(128*4);
  float* Su0 = (float*)alloc(64*4);
  float* Sg1 = (float*)alloc(128*4);
  float* Su1 = (float*)alloc(64*4);
  float* wscr = (float*)alloc((size_t)512*128*4);   // wmax partials (max 384x128)
  float* Bg0 = (float*)alloc((size_t)N_*128*4);
  float* Bu0 = (float*)alloc((size_t)N_*64*4);
  float* Bg1 = (float*)alloc((size_t)N_*128*4);
  float* Bu1 = (float*)alloc((size_t)N_*64*4);
  ushort_t* Abf  = (ushort_t*)alloc((size_t)N_*N_*2);
  ushort_t* A2bf = (ushort_t*)alloc((size_t)N_*N_*2);
  ushort_t* ADh  = (ushort_t*)alloc((size_t)N_*N_*2);
  float* dvec = (float*)alloc(N_*4);
  float* lam  = (float*)alloc(256);
  float* nrm  = (float*)alloc(N_*4);
  float* hA   = (float*)alloc((size_t)N_*B_*H_*4);
  float* hB   = (float*)alloc((size_t)N_*B_*H_*4);
  float* rbuf = (float*)alloc((size_t)N_*B_*H_*4);
  float* cand = (float*)alloc((size_t)N_*B_*H_*4);
  ushort_t* XH = (ushort_t*)alloc((size_t)4096*N_*2);
  ushort_t* XL = (ushort_t*)alloc((size_t)4096*N_*2);
  float* P  = (float*)alloc((size_t)N_*OUTS_*4);
  float* R  = (float*)alloc((size_t)N_*OUTS_*4);
  float* Q  = (float*)alloc((size_t)N_*OUTS_*4);

  // graph structure
  k_norm<<<1,512,0,stream>>>(emb, nrm);
  k_adj<<<N_,256,0,stream>>>(emb, nrm, gn, Abf, dvec);
  k_lam<<<1,512,0,stream>>>(dvec, lam);
  k_a2<<<N_,256,0,stream>>>(Abf, A2bf);
  k_admats<<<(N_*N_)/256,256,0,stream>>>(Abf, dvec, lam, ADh);

  // weights: two-stage per-o max -> scale, then quantize (packed [n][kc][o][8])
  k_wmax<<<dim3(98,2),256,0,stream>>>(gw0, emb, wscr, 195*128, 128);
  k_wred<<<128,256,0,stream>>>(wscr, Sg0, 196, 128);
  k_wmax<<<dim3(49,2),256,0,stream>>>(uw0, emb, wscr, 195*64, 64);
  k_wred<<<64,256,0,stream>>>(wscr, Su0, 98, 64);
  k_wmax<<<dim3(192,2),256,0,stream>>>(gw1, emb, wscr, 384*128, 128);
  k_wred<<<128,256,0,stream>>>(wscr, Sg1, 384, 128);
  k_wmax<<<dim3(96,2),256,0,stream>>>(uw1, emb, wscr, 384*64, 64);
  k_wred<<<64,256,0,stream>>>(wscr, Su1, 192, 64);
  k_wquant<<<dim3((25*128+255)/256,16),256,0,stream>>>(gw0, emb, Sg0, Wg0, 195, 128, RS0);
  k_wquant<<<dim3((25*64+255)/256,16),256,0,stream>>>(uw0, emb, Su0, Wu0, 195, 64, RS0);
  k_wquant<<<dim3((48*128)/256,16),256,0,stream>>>(gw1, emb, Sg1, Wg1, 384, 128, RS1);
  k_wquant<<<dim3((48*64)/256,16),256,0,stream>>>(uw1, emb, Su1, Wu1, 384, 64, RS1);
  k_bias<<<(N_*128)/256,256,0,stream>>>(gb0, emb, Bg0, 128);
  k_bias<<<(N_*64)/256,256,0,stream>>>(ub0, emb, Bu0, 64);
  k_bias<<<(N_*128)/256,256,0,stream>>>(gb1, emb, Bg1, 128);
  k_bias<<<(N_*64)/256,256,0,stream>>>(ub1, emb, Bu1, 64);

  k_fill0<<<2048,256,0,stream>>>(hA, (size_t)N_*B_*H_);
  k_fill0<<<2048,256,0,stream>>>(hB, (size_t)N_*B_*H_);

  for (int t=0; t<T_; ++t){
    // ---- layer 0 (CIN=65, cols padded to 2176 = 34*64) ----
    k_btr<<<dim3(8,32,1),256,0,stream>>>(hA, hA, XH, XL, 65, 1, 1, src, t, 1);
    k_apply<<<dim3(34,8),256,0,stream>>>(XH, XL, Abf, A2bf, ADh, P, R, Q);
    k_gate<65><<<N_,256,0,stream>>>(src, t, hA, hA, P, R, Q, dvec, lam,
                                    Wg0, Sg0, Bg0, hA, cand, rbuf);
    k_btr<<<dim3(8,32,1),256,0,stream>>>(cand, cand, XH, XL, 65, 1, 1, nullptr, 0, 0);
    k_apply<<<dim3(34,8),256,0,stream>>>(XH, XL, Abf, A2bf, ADh, P, R, Q);
    k_update<65><<<N_,256,0,stream>>>(src, t, hA, cand, P, R, Q, dvec, lam,
                                      Wu0, Su0, Bu0, rbuf, hA);
    // ---- layer 1 (CIN=128, cols = 4096 = 64*64) ----
    k_btr<<<dim3(8,32,2),256,0,stream>>>(hA, hB, XH, XL, 128, 0, 64, nullptr, 0, 0);
    k_apply<<<dim3(64,8),256,0,stream>>>(XH, XL, Abf, A2bf, ADh, P, R, Q);
    k_gate<128><<<N_,256,0,stream>>>(nullptr, 0, hA, hB, P, R, Q, dvec, lam,
                                     Wg1, Sg1, Bg1, hB, cand, rbuf);
    k_btr<<<dim3(8,32,1),256,0,stream>>>(cand, cand, XH, XL, 128, 64, 64, nullptr, 0, 0);
    k_apply<<<dim3(64,8),256,0,stream>>>(XH, XL, Abf, A2bf, ADh, P, R, Q);
    k_update<128><<<N_,256,0,stream>>>(nullptr, 0, hA, cand, P, R, Q, dvec, lam,
                                       Wu1, Su1, Bu1, rbuf, hB);
  }

  k_readout<<<(B_*HOR_*N_)/256,256,0,stream>>>(hB, cw, cb, out);
}